// Round 2
// baseline (5618.345 us; speedup 1.0000x reference)
//
#include <hip/hip_runtime.h>

typedef unsigned short u16;
typedef unsigned int   u32;
typedef unsigned long long u64;
typedef __attribute__((ext_vector_type(8))) short s8v;   // 8 bf16 (4 VGPRs) MFMA operand
typedef __attribute__((ext_vector_type(4))) float f4v;   // MFMA accumulator

#define NN 20000
#define EE 320000
#define BB 128
#define HH 256

union BU { u64 d[2]; s8v v; };

__device__ __forceinline__ u16 f2bf(float f){
  u32 u = __float_as_uint(f);
  return (u16)((u + 0x7FFFu + ((u >> 16) & 1u)) >> 16);   // RNE
}
__device__ __forceinline__ u64 pack4bf(float a, float b, float c, float d){
  return (u64)f2bf(a) | ((u64)f2bf(b) << 16) | ((u64)f2bf(c) << 32) | ((u64)f2bf(d) << 48);
}
__device__ __forceinline__ float siluf(float v){ return v / (1.0f + __expf(-v)); }

// ---------------- weight packing: W [K][256] f32 -> A-fragment blob (W^T), bf16 ----------------
// frag layout: lane l holds A[m = mf*16 + (l&15)][k = kb*32 + (l>>4)*4 + j (j<4) | +16 (j>=4)]
// blob addr: ((kb*16 + mf)*64 + lane)*8 ushorts
__global__ void pack_kernel(const float* __restrict__ src, u16* __restrict__ dst, int K, int KB){
  int t = blockIdx.x * 256 + threadIdx.x;
  if (t >= KB * 1024) return;
  int lane = t & 63, mf = (t >> 6) & 15, kb = t >> 10;
  int g = lane >> 4, li = lane & 15;
  int m = mf * 16 + li;
  u16 o[8];
  #pragma unroll
  for (int j = 0; j < 8; ++j){
    int k = kb * 32 + ((j < 4) ? (g * 4 + j) : (16 + g * 4 + (j - 4)));
    o[j] = (k < K) ? f2bf(src[(size_t)k * 256 + m]) : (u16)0;
  }
  u16* d = dst + ((size_t)(kb * 16 + mf) * 64 + lane) * 8;
  *(u64*)(d)     = (u64)o[0] | ((u64)o[1] << 16) | ((u64)o[2] << 32) | ((u64)o[3] << 48);
  *(u64*)(d + 4) = (u64)o[4] | ((u64)o[5] << 16) | ((u64)o[6] << 32) | ((u64)o[7] << 48);
}

// ---------------- small utility kernels ----------------
__global__ void cnt_kernel(const int* __restrict__ ei, float* __restrict__ cnt){
  int t = blockIdx.x * 256 + threadIdx.x;
  if (t < EE) atomicAdd(&cnt[ei[t]], 1.0f);
}
__global__ void coord_init_kernel(const float* __restrict__ pos, float4* __restrict__ coord){
  int t = blockIdx.x * 256 + threadIdx.x;
  if (t < NN) coord[t] = make_float4(pos[3*t], pos[3*t+1], pos[3*t+2], 0.f);
}
__global__ void coord_upd_kernel(float4* __restrict__ coord, const float* __restrict__ cacc,
                                 const float* __restrict__ cnt){
  int t = blockIdx.x * 256 + threadIdx.x;
  if (t >= NN) return;
  float k = fmaxf(cnt[t], 1.0f);
  float4 c = coord[t];
  c.x += cacc[4*t+0] / k; c.y += cacc[4*t+1] / k; c.z += cacc[4*t+2] / k;
  coord[t] = c;
}
__global__ void pool_init_kernel(u32* __restrict__ pooled){
  int t = blockIdx.x * 256 + threadIdx.x;
  if (t < BB * HH){
    u32 u = __float_as_uint(-3.0e38f);
    pooled[t] = ~u;
  }
}
__global__ void build_z_kernel(const u32* __restrict__ pooled, const float* __restrict__ fragl,
                               const float* __restrict__ addf, float* __restrict__ z){
  int t = blockIdx.x * 256 + threadIdx.x;
  if (t >= BB * 272) return;
  int b = t / 272, j = t % 272;
  float v;
  if (j < 256){
    u32 u = pooled[b * 256 + j];
    v = (u & 0x80000000u) ? __uint_as_float(u & 0x7FFFFFFFu) : __uint_as_float(~u);
  } else if (j < 264) v = fragl[b * 8 + (j - 256)];
  else                v = addf[b * 8 + (j - 264)];
  z[t] = v;
}

// ---------------- emb_in: h = x @ emb_in_w + b   (transposed MFMA, K=128) ----------------
__global__ __launch_bounds__(256) void emb_in_kernel(
    const float* __restrict__ x, const u16* __restrict__ pw,
    const float* __restrict__ bias, float* __restrict__ h, u16* __restrict__ hb){
  const int tid = threadIdx.x;
  const int w = tid >> 6, l = tid & 63, g = l >> 4, li = l & 15;
  const int nb = blockIdx.x * 64;
  const float* xp[4];
  #pragma unroll
  for (int nf = 0; nf < 4; ++nf){
    int n = nb + nf * 16 + li; if (n >= NN) n = NN - 1;
    xp[nf] = x + (size_t)n * 128 + g * 4;
  }
  f4v acc[4][4];
  #pragma unroll
  for (int a = 0; a < 4; ++a)
    #pragma unroll
    for (int b = 0; b < 4; ++b) acc[a][b] = (f4v){0.f,0.f,0.f,0.f};
  const u16* pwb = pw + ((size_t)(w * 4) * 64 + l) * 8;
  #pragma unroll
  for (int kb = 0; kb < 4; ++kb){
    s8v A[4];
    #pragma unroll
    for (int mf = 0; mf < 4; ++mf) A[mf] = *(const s8v*)(pwb + (size_t)kb * 8192 + mf * 512);
    #pragma unroll
    for (int nf = 0; nf < 4; ++nf){
      float4 fa = *(const float4*)(xp[nf] + kb * 32);
      float4 fb = *(const float4*)(xp[nf] + kb * 32 + 16);
      BU bu;
      bu.d[0] = pack4bf(fa.x, fa.y, fa.z, fa.w);
      bu.d[1] = pack4bf(fb.x, fb.y, fb.z, fb.w);
      #pragma unroll
      for (int mf = 0; mf < 4; ++mf)
        acc[mf][nf] = __builtin_amdgcn_mfma_f32_16x16x32_bf16(A[mf], bu.v, acc[mf][nf], 0, 0, 0);
    }
  }
  #pragma unroll
  for (int mf = 0; mf < 4; ++mf){
    const int fb = w * 64 + mf * 16 + g * 4;
    float b0 = bias[fb], b1 = bias[fb+1], b2 = bias[fb+2], b3 = bias[fb+3];
    #pragma unroll
    for (int nf = 0; nf < 4; ++nf){
      int n = nb + nf * 16 + li;
      if (n < NN){
        float o0 = acc[mf][nf][0] + b0, o1 = acc[mf][nf][1] + b1;
        float o2 = acc[mf][nf][2] + b2, o3 = acc[mf][nf][3] + b3;
        *(float4*)(h + (size_t)n * HH + fb) = make_float4(o0, o1, o2, o3);
        *(u64*)(hb + (size_t)n * HH + fb) = pack4bf(o0, o1, o2, o3);
      }
    }
  }
}

// ---------------- edge kernel: 64 edges/block, 4 waves split 256 out-feats ----------------
// Latency-oriented restructure vs R1:
//  - LDS 39.4KB (tailb removed) -> 4 blocks/CU instead of 3
//  - 4-slot rotating register pipeline for W-fragments + h gathers (loads issued 4 steps ahead)
//  - all global atomics deferred past the last barrier (no vmcnt(0)-before-barrier stall)
__global__ __launch_bounds__(256) void edge_kernel(
    const u16* __restrict__ hb, const float4* __restrict__ coord,
    const int* __restrict__ ei, const float* __restrict__ eattr,
    const u16* __restrict__ pw1, const u16* __restrict__ pw2, const u16* __restrict__ pw3,
    const float* __restrict__ b1, const float* __restrict__ b2,
    const float* __restrict__ cb1, const float* __restrict__ cw2,
    float* __restrict__ agg, float* __restrict__ cacc){
  __shared__ u64 mt[4096];            // 32KB swizzled tile [64 edges][64 4-feat chunks]
  __shared__ float4 dif[64];          // diff.xyz, radial
  __shared__ int rows_s[64];
  __shared__ int cols_s[64];
  __shared__ float bias_s[1024];      // b1 | b2 | cb1 | cw2
  __shared__ float cpart[4][64];

  const int tid = threadIdx.x;
  const int w = tid >> 6, l = tid & 63, g = l >> 4, li = l & 15;
  const int eb = blockIdx.x * 64;

  if (tid < 64){
    int e = eb + tid;
    int r = ei[e], c = ei[EE + e];
    rows_s[tid] = r; cols_s[tid] = c;
    float4 ca = coord[r], cb = coord[c];
    float dx = ca.x - cb.x, dy = ca.y - cb.y, dz = ca.z - cb.z;
    float rad = dx*dx + dy*dy + dz*dz;
    dif[tid] = make_float4(dx, dy, dz, rad);
  }
  for (int i = tid; i < 1024; i += 256){
    float v;
    if      (i < 256) v = b1[i];
    else if (i < 512) v = b2[i - 256];
    else if (i < 768) v = cb1[i - 512];
    else              v = cw2[i - 768];
    bias_s[i] = v;
  }
  __syncthreads();

  const u16* rp[4]; const u16* cp[4];
  #pragma unroll
  for (int nf = 0; nf < 4; ++nf){
    int e = nf * 16 + li;
    rp[nf] = hb + (size_t)rows_s[e] * HH + g * 4;
    cp[nf] = hb + (size_t)cols_s[e] * HH + g * 4;
  }

  f4v acc[4][4];
  #pragma unroll
  for (int a = 0; a < 4; ++a)
    #pragma unroll
    for (int b = 0; b < 4; ++b) acc[a][b] = (f4v){0.f,0.f,0.f,0.f};

  const u16* pw1b = pw1 + ((size_t)(w * 4) * 64 + l) * 8;
  const u16* pw2b = pw2 + ((size_t)(w * 4) * 64 + l) * 8;
  const u16* pw3b = pw3 + ((size_t)(w * 4) * 64 + l) * 8;

  // ---- tail operand prefetch (k 512..543: radial | edge_attr | 0-pad), built in regs
  float tf[4][4];
  float rads[4];
  #pragma unroll
  for (int nf = 0; nf < 4; ++nf){
    int e = nf * 16 + li;
    const float* ep = eattr + (size_t)(eb + e) * 16;
    if (g == 0){ tf[nf][0] = ep[0]; tf[nf][1] = ep[1]; tf[nf][2] = ep[2]; tf[nf][3] = ep[15]; }
    else { int i0 = g * 4 - 1; tf[nf][0] = ep[i0]; tf[nf][1] = ep[i0+1]; tf[nf][2] = ep[i0+2]; tf[nf][3] = ep[i0+3]; }
    rads[nf] = dif[e].w;
  }
  s8v at[4];
  #pragma unroll
  for (int mf = 0; mf < 4; ++mf) at[mf] = *(const s8v*)(pw1b + (size_t)16 * 8192 + mf * 512);

  // ---- GEMM1 pipeline: 16 steps (8 row-k-blocks + 8 col-k-blocks), depth-4 prefetch
  s8v sa[4][4];       // [slot][mf] W fragments
  u64 sb[4][4][2];    // [slot][nf] gathered h operands
  #pragma unroll
  for (int s = 0; s < 4; ++s){
    #pragma unroll
    for (int mf = 0; mf < 4; ++mf) sa[s][mf] = *(const s8v*)(pw1b + (size_t)s * 8192 + mf * 512);
    #pragma unroll
    for (int nf = 0; nf < 4; ++nf){
      sb[s][nf][0] = *(const u64*)(rp[nf] + s * 32);
      sb[s][nf][1] = *(const u64*)(rp[nf] + s * 32 + 16);
    }
  }
  #pragma unroll
  for (int s = 0; s < 16; ++s){
    const int sl = s & 3;
    #pragma unroll
    for (int nf = 0; nf < 4; ++nf){
      BU bu; bu.d[0] = sb[sl][nf][0]; bu.d[1] = sb[sl][nf][1];
      #pragma unroll
      for (int mf = 0; mf < 4; ++mf)
        acc[mf][nf] = __builtin_amdgcn_mfma_f32_16x16x32_bf16(sa[sl][mf], bu.v, acc[mf][nf], 0, 0, 0);
    }
    if (s + 4 < 16){
      const int nx = s + 4;
      #pragma unroll
      for (int mf = 0; mf < 4; ++mf)
        sa[sl][mf] = *(const s8v*)(pw1b + (size_t)nx * 8192 + mf * 512);
      #pragma unroll
      for (int nf = 0; nf < 4; ++nf){
        const u16* bp = (nx < 8) ? rp[nf] : cp[nf];
        const int ko = (nx & 7) * 32;
        sb[sl][nf][0] = *(const u64*)(bp + ko);
        sb[sl][nf][1] = *(const u64*)(bp + ko + 16);
      }
    }
  }
  // tail k-block
  #pragma unroll
  for (int nf = 0; nf < 4; ++nf){
    BU bu;
    if (g == 0){ bu.d[0] = pack4bf(rads[nf], tf[nf][0], tf[nf][1], tf[nf][2]); bu.d[1] = (u64)f2bf(tf[nf][3]); }
    else       { bu.d[0] = pack4bf(tf[nf][0], tf[nf][1], tf[nf][2], tf[nf][3]); bu.d[1] = 0; }
    #pragma unroll
    for (int mf = 0; mf < 4; ++mf)
      acc[mf][nf] = __builtin_amdgcn_mfma_f32_16x16x32_bf16(at[mf], bu.v, acc[mf][nf], 0, 0, 0);
  }

  // bias + silu -> m1 tile (swizzled LDS)
  #pragma unroll
  for (int mf = 0; mf < 4; ++mf){
    const int fb = w * 64 + mf * 16 + g * 4;
    const int fc = fb >> 2;
    #pragma unroll
    for (int nf = 0; nf < 4; ++nf){
      int e = nf * 16 + li;
      float v0 = siluf(acc[mf][nf][0] + bias_s[fb+0]);
      float v1 = siluf(acc[mf][nf][1] + bias_s[fb+1]);
      float v2 = siluf(acc[mf][nf][2] + bias_s[fb+2]);
      float v3 = siluf(acc[mf][nf][3] + bias_s[fb+3]);
      mt[e * 64 + (fc ^ (e & 7))] = pack4bf(v0, v1, v2, v3);
    }
  }
  __syncthreads();

  // ---- GEMM2: m2 = silu(m1 @ W2 + b2), K=256 (A pipelined, B from LDS)
  #pragma unroll
  for (int a = 0; a < 4; ++a)
    #pragma unroll
    for (int b = 0; b < 4; ++b) acc[a][b] = (f4v){0.f,0.f,0.f,0.f};
  #pragma unroll
  for (int s = 0; s < 4; ++s)
    #pragma unroll
    for (int mf = 0; mf < 4; ++mf) sa[s][mf] = *(const s8v*)(pw2b + (size_t)s * 8192 + mf * 512);
  #pragma unroll
  for (int s = 0; s < 8; ++s){
    const int sl = s & 3;
    #pragma unroll
    for (int nf = 0; nf < 4; ++nf){
      int e = nf * 16 + li;
      BU bu;
      bu.d[0] = mt[e * 64 + ((s * 8 + g)     ^ (e & 7))];
      bu.d[1] = mt[e * 64 + ((s * 8 + 4 + g) ^ (e & 7))];
      #pragma unroll
      for (int mf = 0; mf < 4; ++mf)
        acc[mf][nf] = __builtin_amdgcn_mfma_f32_16x16x32_bf16(sa[sl][mf], bu.v, acc[mf][nf], 0, 0, 0);
    }
    if (s + 4 < 8){
      #pragma unroll
      for (int mf = 0; mf < 4; ++mf)
        sa[sl][mf] = *(const s8v*)(pw2b + (size_t)(s + 4) * 8192 + mf * 512);
    }
  }
  f4v m2s[4][4];                              // keep exact fp32 m2 for deferred agg atomics
  #pragma unroll
  for (int mf = 0; mf < 4; ++mf){
    const int fb = w * 64 + mf * 16 + g * 4;
    #pragma unroll
    for (int nf = 0; nf < 4; ++nf){
      #pragma unroll
      for (int r = 0; r < 4; ++r)
        m2s[mf][nf][r] = siluf(acc[mf][nf][r] + bias_s[256 + fb + r]);
    }
  }
  __syncthreads();                       // all waves done reading m1
  #pragma unroll
  for (int mf = 0; mf < 4; ++mf){
    const int fb = w * 64 + mf * 16 + g * 4;
    const int fc = fb >> 2;
    #pragma unroll
    for (int nf = 0; nf < 4; ++nf){
      int e = nf * 16 + li;
      mt[e * 64 + (fc ^ (e & 7))] = pack4bf(m2s[mf][nf][0], m2s[mf][nf][1], m2s[mf][nf][2], m2s[mf][nf][3]);
    }
  }
  __syncthreads();

  // ---- GEMM3: q = silu(m2 @ CW1 + cb1); c = q . cw2
  #pragma unroll
  for (int a = 0; a < 4; ++a)
    #pragma unroll
    for (int b = 0; b < 4; ++b) acc[a][b] = (f4v){0.f,0.f,0.f,0.f};
  #pragma unroll
  for (int s = 0; s < 4; ++s)
    #pragma unroll
    for (int mf = 0; mf < 4; ++mf) sa[s][mf] = *(const s8v*)(pw3b + (size_t)s * 8192 + mf * 512);
  #pragma unroll
  for (int s = 0; s < 8; ++s){
    const int sl = s & 3;
    #pragma unroll
    for (int nf = 0; nf < 4; ++nf){
      int e = nf * 16 + li;
      BU bu;
      bu.d[0] = mt[e * 64 + ((s * 8 + g)     ^ (e & 7))];
      bu.d[1] = mt[e * 64 + ((s * 8 + 4 + g) ^ (e & 7))];
      #pragma unroll
      for (int mf = 0; mf < 4; ++mf)
        acc[mf][nf] = __builtin_amdgcn_mfma_f32_16x16x32_bf16(sa[sl][mf], bu.v, acc[mf][nf], 0, 0, 0);
    }
    if (s + 4 < 8){
      #pragma unroll
      for (int mf = 0; mf < 4; ++mf)
        sa[sl][mf] = *(const s8v*)(pw3b + (size_t)(s + 4) * 8192 + mf * 512);
    }
  }
  float cp4[4] = {0.f, 0.f, 0.f, 0.f};
  #pragma unroll
  for (int mf = 0; mf < 4; ++mf){
    const int fb = w * 64 + mf * 16 + g * 4;
    #pragma unroll
    for (int nf = 0; nf < 4; ++nf){
      #pragma unroll
      for (int r = 0; r < 4; ++r){
        float q = siluf(acc[mf][nf][r] + bias_s[512 + fb + r]);
        cp4[nf] += q * bias_s[768 + fb + r];
      }
    }
  }
  #pragma unroll
  for (int nf = 0; nf < 4; ++nf){
    float v = cp4[nf];
    v += __shfl_xor(v, 16, 64);
    v += __shfl_xor(v, 32, 64);
    if (g == 0) cpart[w][nf * 16 + li] = v;
  }
  __syncthreads();

  // ---- deferred atomics: no barrier follows, so no vmcnt drain stalls the block
  if (tid < 64){
    float c = cpart[0][tid] + cpart[1][tid] + cpart[2][tid] + cpart[3][tid];
    float4 d = dif[tid];
    int r = rows_s[tid];
    atomicAdd(cacc + (size_t)r * 4 + 0, d.x * c);
    atomicAdd(cacc + (size_t)r * 4 + 1, d.y * c);
    atomicAdd(cacc + (size_t)r * 4 + 2, d.z * c);
  }
  #pragma unroll
  for (int mf = 0; mf < 4; ++mf){
    const int fb = w * 64 + mf * 16 + g * 4;
    #pragma unroll
    for (int nf = 0; nf < 4; ++nf){
      int e = nf * 16 + li;
      float* ag = agg + (size_t)rows_s[e] * HH + fb;
      atomicAdd(ag + 0, m2s[mf][nf][0]);
      atomicAdd(ag + 1, m2s[mf][nf][1]);
      atomicAdd(ag + 2, m2s[mf][nf][2]);
      atomicAdd(ag + 3, m2s[mf][nf][3]);
    }
  }
}

// ---------------- node kernel: h += MLP([h, agg]) ----------------
__global__ __launch_bounds__(256) void node_kernel(
    float* __restrict__ h, u16* __restrict__ hb, const float* __restrict__ agg,
    const u16* __restrict__ pw1, const u16* __restrict__ pw2,
    const float* __restrict__ b1, const float* __restrict__ b2){
  __shared__ u64 mt[4096];
  __shared__ float bias_s[512];
  const int tid = threadIdx.x;
  const int w = tid >> 6, l = tid & 63, g = l >> 4, li = l & 15;
  const int nb = blockIdx.x * 64;
  for (int i = tid; i < 512; i += 256) bias_s[i] = (i < 256) ? b1[i] : b2[i - 256];
  __syncthreads();

  const u16* hp[4]; const float* ap[4];
  #pragma unroll
  for (int nf = 0; nf < 4; ++nf){
    int n = nb + nf * 16 + li; if (n >= NN) n = NN - 1;
    hp[nf] = hb  + (size_t)n * HH + g * 4;
    ap[nf] = agg + (size_t)n * HH + g * 4;
  }
  f4v acc[4][4];
  #pragma unroll
  for (int a = 0; a < 4; ++a)
    #pragma unroll
    for (int b = 0; b < 4; ++b) acc[a][b] = (f4v){0.f,0.f,0.f,0.f};

  const u16* pw1b = pw1 + ((size_t)(w * 4) * 64 + l) * 8;
  #pragma unroll 4
  for (int kb = 0; kb < 8; ++kb){                       // k 0..255 from h (bf16)
    s8v A[4];
    #pragma unroll
    for (int mf = 0; mf < 4; ++mf) A[mf] = *(const s8v*)(pw1b + (size_t)kb * 8192 + mf * 512);
    #pragma unroll
    for (int nf = 0; nf < 4; ++nf){
      BU bu;
      bu.d[0] = *(const u64*)(hp[nf] + kb * 32);
      bu.d[1] = *(const u64*)(hp[nf] + kb * 32 + 16);
      #pragma unroll
      for (int mf = 0; mf < 4; ++mf)
        acc[mf][nf] = __builtin_amdgcn_mfma_f32_16x16x32_bf16(A[mf], bu.v, acc[mf][nf], 0, 0, 0);
    }
  }
  #pragma unroll 4
  for (int kb = 8; kb < 16; ++kb){                      // k 256..511 from agg (f32 -> bf16)
    s8v A[4];
    #pragma unroll
    for (int mf = 0; mf < 4; ++mf) A[mf] = *(const s8v*)(pw1b + (size_t)kb * 8192 + mf * 512);
    #pragma unroll
    for (int nf = 0; nf < 4; ++nf){
      float4 fa = *(const float4*)(ap[nf] + (kb - 8) * 32);
      float4 fb = *(const float4*)(ap[nf] + (kb - 8) * 32 + 16);
      BU bu;
      bu.d[0] = pack4bf(fa.x, fa.y, fa.z, fa.w);
      bu.d[1] = pack4bf(fb.x, fb.y, fb.z, fb.w);
      #pragma unroll
      for (int mf = 0; mf < 4; ++mf)
        acc[mf][nf] = __builtin_amdgcn_mfma_f32_16x16x32_bf16(A[mf], bu.v, acc[mf][nf], 0, 0, 0);
    }
  }
  #pragma unroll
  for (int mf = 0; mf < 4; ++mf){
    const int fb = w * 64 + mf * 16 + g * 4;
    const int fc = fb >> 2;
    #pragma unroll
    for (int nf = 0; nf < 4; ++nf){
      int e = nf * 16 + li;
      float v0 = siluf(acc[mf][nf][0] + bias_s[fb+0]);
      float v1 = siluf(acc[mf][nf][1] + bias_s[fb+1]);
      float v2 = siluf(acc[mf][nf][2] + bias_s[fb+2]);
      float v3 = siluf(acc[mf][nf][3] + bias_s[fb+3]);
      mt[e * 64 + (fc ^ (e & 7))] = pack4bf(v0, v1, v2, v3);
    }
  }
  __syncthreads();

  #pragma unroll
  for (int a = 0; a < 4; ++a)
    #pragma unroll
    for (int b = 0; b < 4; ++b) acc[a][b] = (f4v){0.f,0.f,0.f,0.f};
  const u16* pw2b = pw2 + ((size_t)(w * 4) * 64 + l) * 8;
  #pragma unroll 4
  for (int kb = 0; kb < 8; ++kb){
    s8v A[4];
    #pragma unroll
    for (int mf = 0; mf < 4; ++mf) A[mf] = *(const s8v*)(pw2b + (size_t)kb * 8192 + mf * 512);
    #pragma unroll
    for (int nf = 0; nf < 4; ++nf){
      int e = nf * 16 + li;
      BU bu;
      bu.d[0] = mt[e * 64 + ((kb * 8 + g)     ^ (e & 7))];
      bu.d[1] = mt[e * 64 + ((kb * 8 + 4 + g) ^ (e & 7))];
      #pragma unroll
      for (int mf = 0; mf < 4; ++mf)
        acc[mf][nf] = __builtin_amdgcn_mfma_f32_16x16x32_bf16(A[mf], bu.v, acc[mf][nf], 0, 0, 0);
    }
  }
  #pragma unroll
  for (int mf = 0; mf < 4; ++mf){
    const int fb = w * 64 + mf * 16 + g * 4;
    #pragma unroll
    for (int nf = 0; nf < 4; ++nf){
      int n = nb + nf * 16 + li;
      if (n < NN){
        float4 hv = *(float4*)(h + (size_t)n * HH + fb);
        float o0 = hv.x + acc[mf][nf][0] + bias_s[256+fb+0];
        float o1 = hv.y + acc[mf][nf][1] + bias_s[256+fb+1];
        float o2 = hv.z + acc[mf][nf][2] + bias_s[256+fb+2];
        float o3 = hv.w + acc[mf][nf][3] + bias_s[256+fb+3];
        *(float4*)(h + (size_t)n * HH + fb) = make_float4(o0, o1, o2, o3);
        *(u64*)(hb + (size_t)n * HH + fb) = pack4bf(o0, o1, o2, o3);
      }
    }
  }
}

// ---------------- emb_out + max-pool ----------------
__global__ __launch_bounds__(256) void emb_out_pool_kernel(
    const u16* __restrict__ hb, const u16* __restrict__ pw,
    const float* __restrict__ bias, const int* __restrict__ batch, u32* __restrict__ pooled){
  const int tid = threadIdx.x;
  const int w = tid >> 6, l = tid & 63, g = l >> 4, li = l & 15;
  const int nb = blockIdx.x * 64;
  const u16* hp[4]; int bs[4];
  #pragma unroll
  for (int nf = 0; nf < 4; ++nf){
    int n = nb + nf * 16 + li; int nc = (n >= NN) ? NN - 1 : n;
    hp[nf] = hb + (size_t)nc * HH + g * 4;
    bs[nf] = batch[nc];
  }
  f4v acc[4][4];
  #pragma unroll
  for (int a = 0; a < 4; ++a)
    #pragma unroll
    for (int b = 0; b < 4; ++b) acc[a][b] = (f4v){0.f,0.f,0.f,0.f};
  const u16* pwb = pw + ((size_t)(w * 4) * 64 + l) * 8;
  #pragma unroll 4
  for (int kb = 0; kb < 8; ++kb){
    s8v A[4];
    #pragma unroll
    for (int mf = 0; mf < 4; ++mf) A[mf] = *(const s8v*)(pwb + (size_t)kb * 8192 + mf * 512);
    #pragma unroll
    for (int nf = 0; nf < 4; ++nf){
      BU bu;
      bu.d[0] = *(const u64*)(hp[nf] + kb * 32);
      bu.d[1] = *(const u64*)(hp[nf] + kb * 32 + 16);
      #pragma unroll
      for (int mf = 0; mf < 4; ++mf)
        acc[mf][nf] = __builtin_amdgcn_mfma_f32_16x16x32_bf16(A[mf], bu.v, acc[mf][nf], 0, 0, 0);
    }
  }
  #pragma unroll
  for (int mf = 0; mf < 4; ++mf){
    const int fb = w * 64 + mf * 16 + g * 4;
    float b0 = bias[fb], b1 = bias[fb+1], b2 = bias[fb+2], b3 = bias[fb+3];
    #pragma unroll
    for (int nf = 0; nf < 4; ++nf){
      int n = nb + nf * 16 + li;
      if (n < NN){
        float vv[4] = {acc[mf][nf][0] + b0, acc[mf][nf][1] + b1, acc[mf][nf][2] + b2, acc[mf][nf][3] + b3};
        #pragma unroll
        for (int r = 0; r < 4; ++r){
          u32 u = __float_as_uint(vv[r]);
          u = (u & 0x80000000u) ? ~u : (u | 0x80000000u);
          atomicMax(&pooled[(size_t)bs[nf] * HH + fb + r], u);
        }
      }
    }
  }
}

// ---------------- resblock + head (tiny: 128 graphs) ----------------
__global__ __launch_bounds__(256) void final_kernel(
    const float* __restrict__ z, const float* __restrict__ rw1, const float* __restrict__ rb1,
    const float* __restrict__ rw2, const float* __restrict__ rb2,
    const float* __restrict__ hw, const float* __restrict__ hbs, float* __restrict__ out){
  __shared__ float zr[272], t1[256], t2[272];
  const int b = blockIdx.x, tid = threadIdx.x;
  for (int i = tid; i < 272; i += 256) zr[i] = z[(size_t)b * 272 + i];
  __syncthreads();
  {
    float a = rb1[tid];
    for (int k = 0; k < 272; ++k) a += zr[k] * rw1[(size_t)k * 256 + tid];
    t1[tid] = siluf(a);
  }
  __syncthreads();
  for (int i = tid; i < 272; i += 256){
    float a = rb2[i] + zr[i];
    for (int k = 0; k < 256; ++k) a += t1[k] * rw2[(size_t)k * 272 + i];
    t2[i] = a;
  }
  __syncthreads();
  for (int p = tid; p < 2000; p += 256){
    float a = hbs[p];
    for (int k = 0; k < 272; ++k) a += t2[k] * hw[(size_t)k * 2000 + p];
    out[(size_t)b * 2000 + p] = a;
  }
}

extern "C" void kernel_launch(void* const* d_in, const int* in_sizes, int n_in,
                              void* d_out, int out_size, void* d_ws, size_t ws_size,
                              hipStream_t stream){
  const float* x        = (const float*)d_in[0];
  const float* pos      = (const float*)d_in[1];
  const float* eattr    = (const float*)d_in[2];
  const float* fragl    = (const float*)d_in[3];
  const float* addf     = (const float*)d_in[4];
  const int*   ei       = (const int*)d_in[5];
  const int*   batch    = (const int*)d_in[6];
  const float* emb_in_w = (const float*)d_in[7];
  const float* emb_in_b = (const float*)d_in[8];
  const float* edge_w1  = (const float*)d_in[9];
  const float* edge_b1  = (const float*)d_in[10];
  const float* edge_w2  = (const float*)d_in[11];
  const float* edge_b2  = (const float*)d_in[12];
  const float* node_w1  = (const float*)d_in[13];
  const float* node_b1  = (const float*)d_in[14];
  const float* node_w2  = (const float*)d_in[15];
  const float* node_b2  = (const float*)d_in[16];
  const float* coord_w1 = (const float*)d_in[17];
  const float* coord_b1 = (const float*)d_in[18];
  const float* coord_w2 = (const float*)d_in[19];
  const float* emb_out_w= (const float*)d_in[20];
  const float* emb_out_b= (const float*)d_in[21];
  const float* res_w1   = (const float*)d_in[22];
  const float* res_b1   = (const float*)d_in[23];
  const float* res_w2   = (const float*)d_in[24];
  const float* res_b2   = (const float*)d_in[25];
  const float* head_w   = (const float*)d_in[26];
  const float* head_b   = (const float*)d_in[27];

  char* ws = (char*)d_ws;
  size_t off = 0;
  auto alloc = [&](size_t bytes) -> void* {
    void* p = ws + off;
    off += (bytes + 255) & ~(size_t)255;
    return p;
  };
  float*  h      = (float*)alloc((size_t)NN * HH * 4);
  float*  agg    = (float*)alloc((size_t)NN * HH * 4);
  u16*    hb     = (u16*)  alloc((size_t)NN * HH * 2);
  float4* coordb = (float4*)alloc((size_t)NN * 16);
  float*  cacc   = (float*)alloc((size_t)NN * 16);
  float*  cnt    = (float*)alloc((size_t)NN * 4);
  u32*    pooled = (u32*)  alloc((size_t)BB * HH * 4);
  float*  z      = (float*)alloc((size_t)BB * 272 * 4);
  u16*    packed = (u16*)  alloc((size_t)7680 * 256 * 2);
  if (off > ws_size) return;

  u16* pk_embin  = packed;
  u16* pk_embout = packed + 32768 + (size_t)4 * 466944;
  auto pk_ew1 = [&](int l){ return packed + 32768 + (size_t)l * 466944; };
  auto pk_ew2 = [&](int l){ return pk_ew1(l) + 139264; };
  auto pk_cw1 = [&](int l){ return pk_ew1(l) + 204800; };
  auto pk_nw1 = [&](int l){ return pk_ew1(l) + 270336; };
  auto pk_nw2 = [&](int l){ return pk_ew1(l) + 401408; };

  pack_kernel<<<16, 256, 0, stream>>>(emb_in_w, pk_embin, 128, 4);
  for (int l = 0; l < 4; ++l){
    pack_kernel<<<68, 256, 0, stream>>>(edge_w1 + (size_t)l * 529 * 256, pk_ew1(l), 529, 17);
    pack_kernel<<<32, 256, 0, stream>>>(edge_w2 + (size_t)l * 65536,     pk_ew2(l), 256, 8);
    pack_kernel<<<32, 256, 0, stream>>>(coord_w1 + (size_t)l * 65536,    pk_cw1(l), 256, 8);
    pack_kernel<<<64, 256, 0, stream>>>(node_w1 + (size_t)l * 131072,    pk_nw1(l), 512, 16);
    pack_kernel<<<32, 256, 0, stream>>>(node_w2 + (size_t)l * 65536,     pk_nw2(l), 256, 8);
  }
  pack_kernel<<<32, 256, 0, stream>>>(emb_out_w, pk_embout, 256, 8);

  hipMemsetAsync(cnt, 0, (size_t)NN * 4, stream);
  cnt_kernel<<<1250, 256, 0, stream>>>(ei, cnt);
  coord_init_kernel<<<79, 256, 0, stream>>>(pos, coordb);
  emb_in_kernel<<<313, 256, 0, stream>>>(x, pk_embin, emb_in_b, h, hb);

  for (int l = 0; l < 4; ++l){
    hipMemsetAsync(agg,  0, (size_t)NN * HH * 4, stream);
    hipMemsetAsync(cacc, 0, (size_t)NN * 16, stream);
    edge_kernel<<<5000, 256, 0, stream>>>(hb, coordb, ei, eattr,
        pk_ew1(l), pk_ew2(l), pk_cw1(l),
        edge_b1 + l * 256, edge_b2 + l * 256, coord_b1 + l * 256, coord_w2 + l * 256,
        agg, cacc);
    coord_upd_kernel<<<79, 256, 0, stream>>>(coordb, cacc, cnt);
    node_kernel<<<313, 256, 0, stream>>>(h, hb, agg, pk_nw1(l), pk_nw2(l),
        node_b1 + l * 256, node_b2 + l * 256);
  }

  pool_init_kernel<<<128, 256, 0, stream>>>(pooled);
  emb_out_pool_kernel<<<313, 256, 0, stream>>>(hb, pk_embout, emb_out_b, batch, pooled);
  build_z_kernel<<<136, 256, 0, stream>>>(pooled, fragl, addf, z);
  final_kernel<<<128, 256, 0, stream>>>(z, res_w1, res_b1, res_w2, res_b2, head_w, head_b,
                                        (float*)d_out);
}

// Round 3
// 2558.965 us; speedup vs baseline: 2.1956x; 2.1956x over previous
//
#include <hip/hip_runtime.h>

typedef unsigned short u16;
typedef unsigned int   u32;
typedef unsigned long long u64;
typedef __attribute__((ext_vector_type(8))) short s8v;   // 8 bf16 (4 VGPRs) MFMA operand
typedef __attribute__((ext_vector_type(4))) float f4v;   // MFMA accumulator

#define NN 20000
#define EE 320000
#define BB 128
#define HH 256

union BU { u64 d[2]; s8v v; };

__device__ __forceinline__ u16 f2bf(float f){
  u32 u = __float_as_uint(f);
  return (u16)((u + 0x7FFFu + ((u >> 16) & 1u)) >> 16);   // RNE
}
__device__ __forceinline__ u64 pack4bf(float a, float b, float c, float d){
  return (u64)f2bf(a) | ((u64)f2bf(b) << 16) | ((u64)f2bf(c) << 32) | ((u64)f2bf(d) << 48);
}
__device__ __forceinline__ float siluf(float v){ return v / (1.0f + __expf(-v)); }

// ---------------- weight packing: W [K][256] f32 -> A-fragment blob (W^T), bf16 ----------------
__global__ void pack_kernel(const float* __restrict__ src, u16* __restrict__ dst, int K, int KB){
  int t = blockIdx.x * 256 + threadIdx.x;
  if (t >= KB * 1024) return;
  int lane = t & 63, mf = (t >> 6) & 15, kb = t >> 10;
  int g = lane >> 4, li = lane & 15;
  int m = mf * 16 + li;
  u16 o[8];
  #pragma unroll
  for (int j = 0; j < 8; ++j){
    int k = kb * 32 + ((j < 4) ? (g * 4 + j) : (16 + g * 4 + (j - 4)));
    o[j] = (k < K) ? f2bf(src[(size_t)k * 256 + m]) : (u16)0;
  }
  u16* d = dst + ((size_t)(kb * 16 + mf) * 64 + lane) * 8;
  *(u64*)(d)     = (u64)o[0] | ((u64)o[1] << 16) | ((u64)o[2] << 32) | ((u64)o[3] << 48);
  *(u64*)(d + 4) = (u64)o[4] | ((u64)o[5] << 16) | ((u64)o[6] << 32) | ((u64)o[7] << 48);
}

// ---------------- edge sort by destination row (one-time per launch) ----------------
__global__ void icnt_kernel(const int* __restrict__ ei, int* __restrict__ icnt){
  int t = blockIdx.x * 256 + threadIdx.x;
  if (t < EE) atomicAdd(&icnt[ei[t]], 1);
}
__global__ void iscan_block(const int* __restrict__ icnt, int* __restrict__ iscan, int* __restrict__ bsum){
  __shared__ int s[256];
  int i = blockIdx.x * 256 + threadIdx.x;
  int v = (i < NN) ? icnt[i] : 0;
  s[threadIdx.x] = v; __syncthreads();
  #pragma unroll
  for (int d = 1; d < 256; d <<= 1){
    int t = (threadIdx.x >= d) ? s[threadIdx.x - d] : 0;
    __syncthreads();
    s[threadIdx.x] += t;
    __syncthreads();
  }
  if (i < NN) iscan[i] = s[threadIdx.x];
  if (threadIdx.x == 255) bsum[blockIdx.x] = s[255];
}
__global__ void iscan_top(int* __restrict__ bsum, int nb){
  if (blockIdx.x == 0 && threadIdx.x == 0){
    int acc = 0;
    for (int i = 0; i < nb; ++i){ int t = bsum[i]; bsum[i] = acc; acc += t; }
  }
}
__global__ void iscan_fix(const int* __restrict__ icnt, const int* __restrict__ iscan,
                          const int* __restrict__ bsum, int* __restrict__ rstart){
  int i = blockIdx.x * 256 + threadIdx.x;
  if (i < NN) rstart[i] = bsum[blockIdx.x] + iscan[i] - icnt[i];
}
__global__ void scatter_kernel(const int* __restrict__ ei, const int* __restrict__ rstart,
                               int* __restrict__ cursor, int* __restrict__ seid,
                               int* __restrict__ srow, int* __restrict__ scol){
  int e = blockIdx.x * 256 + threadIdx.x;
  if (e < EE){
    int r = ei[e];
    int p = rstart[r] + atomicAdd(&cursor[r], 1);
    seid[p] = e; srow[p] = r; scol[p] = ei[EE + e];
  }
}

// ---------------- small utility kernels ----------------
__global__ void coord_init_kernel(const float* __restrict__ pos, float4* __restrict__ coord){
  int t = blockIdx.x * 256 + threadIdx.x;
  if (t < NN) coord[t] = make_float4(pos[3*t], pos[3*t+1], pos[3*t+2], 0.f);
}
__global__ void coord_upd_kernel(float4* __restrict__ coord, const float* __restrict__ cacc,
                                 const int* __restrict__ icnt){
  int t = blockIdx.x * 256 + threadIdx.x;
  if (t >= NN) return;
  float k = fmaxf((float)icnt[t], 1.0f);
  float4 c = coord[t];
  c.x += cacc[4*t+0] / k; c.y += cacc[4*t+1] / k; c.z += cacc[4*t+2] / k;
  coord[t] = c;
}
__global__ void pool_init_kernel(u32* __restrict__ pooled){
  int t = blockIdx.x * 256 + threadIdx.x;
  if (t < BB * HH){
    u32 u = __float_as_uint(-3.0e38f);
    pooled[t] = ~u;
  }
}
__global__ void build_z_kernel(const u32* __restrict__ pooled, const float* __restrict__ fragl,
                               const float* __restrict__ addf, float* __restrict__ z){
  int t = blockIdx.x * 256 + threadIdx.x;
  if (t >= BB * 272) return;
  int b = t / 272, j = t % 272;
  float v;
  if (j < 256){
    u32 u = pooled[b * 256 + j];
    v = (u & 0x80000000u) ? __uint_as_float(u & 0x7FFFFFFFu) : __uint_as_float(~u);
  } else if (j < 264) v = fragl[b * 8 + (j - 256)];
  else                v = addf[b * 8 + (j - 264)];
  z[t] = v;
}

// ---------------- emb_in: h = x @ emb_in_w + b ----------------
__global__ __launch_bounds__(256) void emb_in_kernel(
    const float* __restrict__ x, const u16* __restrict__ pw,
    const float* __restrict__ bias, float* __restrict__ h, u16* __restrict__ hb){
  const int tid = threadIdx.x;
  const int w = tid >> 6, l = tid & 63, g = l >> 4, li = l & 15;
  const int nb = blockIdx.x * 64;
  const float* xp[4];
  #pragma unroll
  for (int nf = 0; nf < 4; ++nf){
    int n = nb + nf * 16 + li; if (n >= NN) n = NN - 1;
    xp[nf] = x + (size_t)n * 128 + g * 4;
  }
  f4v acc[4][4];
  #pragma unroll
  for (int a = 0; a < 4; ++a)
    #pragma unroll
    for (int b = 0; b < 4; ++b) acc[a][b] = (f4v){0.f,0.f,0.f,0.f};
  const u16* pwb = pw + ((size_t)(w * 4) * 64 + l) * 8;
  #pragma unroll
  for (int kb = 0; kb < 4; ++kb){
    s8v A[4];
    #pragma unroll
    for (int mf = 0; mf < 4; ++mf) A[mf] = *(const s8v*)(pwb + (size_t)kb * 8192 + mf * 512);
    #pragma unroll
    for (int nf = 0; nf < 4; ++nf){
      float4 fa = *(const float4*)(xp[nf] + kb * 32);
      float4 fb = *(const float4*)(xp[nf] + kb * 32 + 16);
      BU bu;
      bu.d[0] = pack4bf(fa.x, fa.y, fa.z, fa.w);
      bu.d[1] = pack4bf(fb.x, fb.y, fb.z, fb.w);
      #pragma unroll
      for (int mf = 0; mf < 4; ++mf)
        acc[mf][nf] = __builtin_amdgcn_mfma_f32_16x16x32_bf16(A[mf], bu.v, acc[mf][nf], 0, 0, 0);
    }
  }
  #pragma unroll
  for (int mf = 0; mf < 4; ++mf){
    const int fb = w * 64 + mf * 16 + g * 4;
    float b0 = bias[fb], b1 = bias[fb+1], b2 = bias[fb+2], b3 = bias[fb+3];
    #pragma unroll
    for (int nf = 0; nf < 4; ++nf){
      int n = nb + nf * 16 + li;
      if (n < NN){
        float o0 = acc[mf][nf][0] + b0, o1 = acc[mf][nf][1] + b1;
        float o2 = acc[mf][nf][2] + b2, o3 = acc[mf][nf][3] + b3;
        *(float4*)(h + (size_t)n * HH + fb) = make_float4(o0, o1, o2, o3);
        *(u64*)(hb + (size_t)n * HH + fb) = pack4bf(o0, o1, o2, o3);
      }
    }
  }
}

// ---------------- edge kernel: 64 SORTED edges/block ----------------
// Edges sorted by row => gathers are cache-local, and agg atomics are collapsed
// via segmented suffix-reduction (shfl within 16-lane windows) to ~1 atomic per
// distinct row per window instead of 1 per edge.
__global__ __launch_bounds__(256) void edge_kernel(
    const u16* __restrict__ hb, const float4* __restrict__ coord,
    const int* __restrict__ srow, const int* __restrict__ scol, const int* __restrict__ seid,
    const float* __restrict__ eattr,
    const u16* __restrict__ pw1, const u16* __restrict__ pw2, const u16* __restrict__ pw3,
    const float* __restrict__ b1, const float* __restrict__ b2,
    const float* __restrict__ cb1, const float* __restrict__ cw2,
    float* __restrict__ agg, float* __restrict__ cacc){
  __shared__ u64 mt[4096];            // 32KB swizzled tile [64 edges][64 4-feat chunks]
  __shared__ float4 dif[64];          // diff.xyz, radial
  __shared__ int rows_s[64];
  __shared__ int cols_s[64];
  __shared__ int seid_s[64];
  __shared__ float bias_s[1024];      // b1 | b2 | cb1 | cw2
  __shared__ float cpart[4][64];

  const int tid = threadIdx.x;
  const int w = tid >> 6, l = tid & 63, g = l >> 4, li = l & 15;
  const int eb = blockIdx.x * 64;

  if (tid < 64){
    int sp = eb + tid;
    int r = srow[sp], c = scol[sp];
    rows_s[tid] = r; cols_s[tid] = c; seid_s[tid] = seid[sp];
    float4 ca = coord[r], cb = coord[c];
    float dx = ca.x - cb.x, dy = ca.y - cb.y, dz = ca.z - cb.z;
    float rad = dx*dx + dy*dy + dz*dz;
    dif[tid] = make_float4(dx, dy, dz, rad);
  }
  for (int i = tid; i < 1024; i += 256){
    float v;
    if      (i < 256) v = b1[i];
    else if (i < 512) v = b2[i - 256];
    else if (i < 768) v = cb1[i - 512];
    else              v = cw2[i - 768];
    bias_s[i] = v;
  }
  __syncthreads();

  const u16* rp[4]; const u16* cp[4];
  #pragma unroll
  for (int nf = 0; nf < 4; ++nf){
    int e = nf * 16 + li;
    rp[nf] = hb + (size_t)rows_s[e] * HH + g * 4;
    cp[nf] = hb + (size_t)cols_s[e] * HH + g * 4;
  }

  f4v acc[4][4];
  #pragma unroll
  for (int a = 0; a < 4; ++a)
    #pragma unroll
    for (int b = 0; b < 4; ++b) acc[a][b] = (f4v){0.f,0.f,0.f,0.f};

  const u16* pw1b = pw1 + ((size_t)(w * 4) * 64 + l) * 8;
  const u16* pw2b = pw2 + ((size_t)(w * 4) * 64 + l) * 8;
  const u16* pw3b = pw3 + ((size_t)(w * 4) * 64 + l) * 8;

  // ---- tail operand prefetch (k 512..543: radial | edge_attr | 0-pad), built in regs
  float tf[4][4];
  float rads[4];
  #pragma unroll
  for (int nf = 0; nf < 4; ++nf){
    int e = nf * 16 + li;
    const float* ep = eattr + (size_t)seid_s[e] * 16;
    if (g == 0){ tf[nf][0] = ep[0]; tf[nf][1] = ep[1]; tf[nf][2] = ep[2]; tf[nf][3] = ep[15]; }
    else { int i0 = g * 4 - 1; tf[nf][0] = ep[i0]; tf[nf][1] = ep[i0+1]; tf[nf][2] = ep[i0+2]; tf[nf][3] = ep[i0+3]; }
    rads[nf] = dif[e].w;
  }
  s8v at[4];
  #pragma unroll
  for (int mf = 0; mf < 4; ++mf) at[mf] = *(const s8v*)(pw1b + (size_t)16 * 8192 + mf * 512);

  // ---- GEMM1: 16 k-block steps (8 row + 8 col), depth-4 register pipeline
  s8v sa[4][4];
  u64 sb[4][4][2];
  #pragma unroll
  for (int s = 0; s < 4; ++s){
    #pragma unroll
    for (int mf = 0; mf < 4; ++mf) sa[s][mf] = *(const s8v*)(pw1b + (size_t)s * 8192 + mf * 512);
    #pragma unroll
    for (int nf = 0; nf < 4; ++nf){
      sb[s][nf][0] = *(const u64*)(rp[nf] + s * 32);
      sb[s][nf][1] = *(const u64*)(rp[nf] + s * 32 + 16);
    }
  }
  #pragma unroll
  for (int s = 0; s < 16; ++s){
    const int sl = s & 3;
    #pragma unroll
    for (int nf = 0; nf < 4; ++nf){
      BU bu; bu.d[0] = sb[sl][nf][0]; bu.d[1] = sb[sl][nf][1];
      #pragma unroll
      for (int mf = 0; mf < 4; ++mf)
        acc[mf][nf] = __builtin_amdgcn_mfma_f32_16x16x32_bf16(sa[sl][mf], bu.v, acc[mf][nf], 0, 0, 0);
    }
    if (s + 4 < 16){
      const int nx = s + 4;
      #pragma unroll
      for (int mf = 0; mf < 4; ++mf)
        sa[sl][mf] = *(const s8v*)(pw1b + (size_t)nx * 8192 + mf * 512);
      #pragma unroll
      for (int nf = 0; nf < 4; ++nf){
        const u16* bp = (nx < 8) ? rp[nf] : cp[nf];
        const int ko = (nx & 7) * 32;
        sb[sl][nf][0] = *(const u64*)(bp + ko);
        sb[sl][nf][1] = *(const u64*)(bp + ko + 16);
      }
    }
  }
  // tail k-block
  #pragma unroll
  for (int nf = 0; nf < 4; ++nf){
    BU bu;
    if (g == 0){ bu.d[0] = pack4bf(rads[nf], tf[nf][0], tf[nf][1], tf[nf][2]); bu.d[1] = (u64)f2bf(tf[nf][3]); }
    else       { bu.d[0] = pack4bf(tf[nf][0], tf[nf][1], tf[nf][2], tf[nf][3]); bu.d[1] = 0; }
    #pragma unroll
    for (int mf = 0; mf < 4; ++mf)
      acc[mf][nf] = __builtin_amdgcn_mfma_f32_16x16x32_bf16(at[mf], bu.v, acc[mf][nf], 0, 0, 0);
  }

  // bias + silu -> m1 tile (swizzled LDS)
  #pragma unroll
  for (int mf = 0; mf < 4; ++mf){
    const int fb = w * 64 + mf * 16 + g * 4;
    const int fc = fb >> 2;
    #pragma unroll
    for (int nf = 0; nf < 4; ++nf){
      int e = nf * 16 + li;
      float v0 = siluf(acc[mf][nf][0] + bias_s[fb+0]);
      float v1 = siluf(acc[mf][nf][1] + bias_s[fb+1]);
      float v2 = siluf(acc[mf][nf][2] + bias_s[fb+2]);
      float v3 = siluf(acc[mf][nf][3] + bias_s[fb+3]);
      mt[e * 64 + (fc ^ (e & 7))] = pack4bf(v0, v1, v2, v3);
    }
  }
  __syncthreads();

  // ---- GEMM2: m2 = silu(m1 @ W2 + b2)
  #pragma unroll
  for (int a = 0; a < 4; ++a)
    #pragma unroll
    for (int b = 0; b < 4; ++b) acc[a][b] = (f4v){0.f,0.f,0.f,0.f};
  #pragma unroll
  for (int s = 0; s < 4; ++s)
    #pragma unroll
    for (int mf = 0; mf < 4; ++mf) sa[s][mf] = *(const s8v*)(pw2b + (size_t)s * 8192 + mf * 512);
  #pragma unroll
  for (int s = 0; s < 8; ++s){
    const int sl = s & 3;
    #pragma unroll
    for (int nf = 0; nf < 4; ++nf){
      int e = nf * 16 + li;
      BU bu;
      bu.d[0] = mt[e * 64 + ((s * 8 + g)     ^ (e & 7))];
      bu.d[1] = mt[e * 64 + ((s * 8 + 4 + g) ^ (e & 7))];
      #pragma unroll
      for (int mf = 0; mf < 4; ++mf)
        acc[mf][nf] = __builtin_amdgcn_mfma_f32_16x16x32_bf16(sa[sl][mf], bu.v, acc[mf][nf], 0, 0, 0);
    }
    if (s + 4 < 8){
      #pragma unroll
      for (int mf = 0; mf < 4; ++mf)
        sa[sl][mf] = *(const s8v*)(pw2b + (size_t)(s + 4) * 8192 + mf * 512);
    }
  }
  f4v m2s[4][4];                              // exact fp32 m2 kept for deferred agg
  #pragma unroll
  for (int mf = 0; mf < 4; ++mf){
    const int fb = w * 64 + mf * 16 + g * 4;
    #pragma unroll
    for (int nf = 0; nf < 4; ++nf){
      #pragma unroll
      for (int r = 0; r < 4; ++r)
        m2s[mf][nf][r] = siluf(acc[mf][nf][r] + bias_s[256 + fb + r]);
    }
  }
  __syncthreads();
  #pragma unroll
  for (int mf = 0; mf < 4; ++mf){
    const int fb = w * 64 + mf * 16 + g * 4;
    const int fc = fb >> 2;
    #pragma unroll
    for (int nf = 0; nf < 4; ++nf){
      int e = nf * 16 + li;
      mt[e * 64 + (fc ^ (e & 7))] = pack4bf(m2s[mf][nf][0], m2s[mf][nf][1], m2s[mf][nf][2], m2s[mf][nf][3]);
    }
  }
  __syncthreads();

  // ---- GEMM3: q = silu(m2 @ CW1 + cb1); c = q . cw2
  #pragma unroll
  for (int a = 0; a < 4; ++a)
    #pragma unroll
    for (int b = 0; b < 4; ++b) acc[a][b] = (f4v){0.f,0.f,0.f,0.f};
  #pragma unroll
  for (int s = 0; s < 4; ++s)
    #pragma unroll
    for (int mf = 0; mf < 4; ++mf) sa[s][mf] = *(const s8v*)(pw3b + (size_t)s * 8192 + mf * 512);
  #pragma unroll
  for (int s = 0; s < 8; ++s){
    const int sl = s & 3;
    #pragma unroll
    for (int nf = 0; nf < 4; ++nf){
      int e = nf * 16 + li;
      BU bu;
      bu.d[0] = mt[e * 64 + ((s * 8 + g)     ^ (e & 7))];
      bu.d[1] = mt[e * 64 + ((s * 8 + 4 + g) ^ (e & 7))];
      #pragma unroll
      for (int mf = 0; mf < 4; ++mf)
        acc[mf][nf] = __builtin_amdgcn_mfma_f32_16x16x32_bf16(sa[sl][mf], bu.v, acc[mf][nf], 0, 0, 0);
    }
    if (s + 4 < 8){
      #pragma unroll
      for (int mf = 0; mf < 4; ++mf)
        sa[sl][mf] = *(const s8v*)(pw3b + (size_t)(s + 4) * 8192 + mf * 512);
    }
  }
  float cp4[4] = {0.f, 0.f, 0.f, 0.f};
  #pragma unroll
  for (int mf = 0; mf < 4; ++mf){
    const int fb = w * 64 + mf * 16 + g * 4;
    #pragma unroll
    for (int nf = 0; nf < 4; ++nf){
      #pragma unroll
      for (int r = 0; r < 4; ++r){
        float q = siluf(acc[mf][nf][r] + bias_s[512 + fb + r]);
        cp4[nf] += q * bias_s[768 + fb + r];
      }
    }
  }
  #pragma unroll
  for (int nf = 0; nf < 4; ++nf){
    float v = cp4[nf];
    v += __shfl_xor(v, 16, 64);
    v += __shfl_xor(v, 32, 64);
    if (g == 0) cpart[w][nf * 16 + li] = v;
  }
  __syncthreads();

  // ---- cacc: segmented suffix-reduce across the 64 sorted edges, head lanes atomic
  if (tid < 64){
    float c = cpart[0][tid] + cpart[1][tid] + cpart[2][tid] + cpart[3][tid];
    float4 d = dif[tid];
    const int myrow = rows_s[tid];
    float vx = d.x * c, vy = d.y * c, vz = d.z * c;
    #pragma unroll
    for (int dd = 1; dd < 64; dd <<= 1){
      const int rr = __shfl_down(myrow, dd, 64);
      const bool ok = ((tid + dd) < 64) && (rr == myrow);
      float tx = __shfl_down(vx, dd, 64);
      float ty = __shfl_down(vy, dd, 64);
      float tz = __shfl_down(vz, dd, 64);
      if (ok){ vx += tx; vy += ty; vz += tz; }
    }
    if (tid == 0 || rows_s[tid - 1] != myrow){
      atomicAdd(cacc + (size_t)myrow * 4 + 0, vx);
      atomicAdd(cacc + (size_t)myrow * 4 + 1, vy);
      atomicAdd(cacc + (size_t)myrow * 4 + 2, vz);
    }
  }

  // ---- agg: segmented suffix-reduce within each 16-lane edge window (rows sorted),
  //      then ONE atomicAdd per run-head instead of one per edge (~8x fewer)
  #pragma unroll
  for (int nf = 0; nf < 4; ++nf){
    const int myrow = rows_s[nf * 16 + li];
    const bool head = (li == 0) || (rows_s[nf * 16 + li - 1] != myrow);
    float v[16];
    #pragma unroll
    for (int mf = 0; mf < 4; ++mf)
      #pragma unroll
      for (int r = 0; r < 4; ++r) v[mf * 4 + r] = m2s[mf][nf][r];
    #pragma unroll
    for (int d = 1; d < 16; d <<= 1){
      const int rr = __shfl_down(myrow, d, 16);
      const bool ok = ((li + d) < 16) && (rr == myrow);
      #pragma unroll
      for (int j = 0; j < 16; ++j){
        const float vv = __shfl_down(v[j], d, 16);
        if (ok) v[j] += vv;
      }
    }
    if (head){
      #pragma unroll
      for (int mf = 0; mf < 4; ++mf){
        float* ag = agg + (size_t)myrow * HH + w * 64 + mf * 16 + g * 4;
        atomicAdd(ag + 0, v[mf * 4 + 0]);
        atomicAdd(ag + 1, v[mf * 4 + 1]);
        atomicAdd(ag + 2, v[mf * 4 + 2]);
        atomicAdd(ag + 3, v[mf * 4 + 3]);
      }
    }
  }
}

// ---------------- node kernel: h += MLP([h, agg]) ----------------
__global__ __launch_bounds__(256) void node_kernel(
    float* __restrict__ h, u16* __restrict__ hb, const float* __restrict__ agg,
    const u16* __restrict__ pw1, const u16* __restrict__ pw2,
    const float* __restrict__ b1, const float* __restrict__ b2){
  __shared__ u64 mt[4096];
  __shared__ float bias_s[512];
  const int tid = threadIdx.x;
  const int w = tid >> 6, l = tid & 63, g = l >> 4, li = l & 15;
  const int nb = blockIdx.x * 64;
  for (int i = tid; i < 512; i += 256) bias_s[i] = (i < 256) ? b1[i] : b2[i - 256];
  __syncthreads();

  const u16* hp[4]; const float* ap[4];
  #pragma unroll
  for (int nf = 0; nf < 4; ++nf){
    int n = nb + nf * 16 + li; if (n >= NN) n = NN - 1;
    hp[nf] = hb  + (size_t)n * HH + g * 4;
    ap[nf] = agg + (size_t)n * HH + g * 4;
  }
  f4v acc[4][4];
  #pragma unroll
  for (int a = 0; a < 4; ++a)
    #pragma unroll
    for (int b = 0; b < 4; ++b) acc[a][b] = (f4v){0.f,0.f,0.f,0.f};

  const u16* pw1b = pw1 + ((size_t)(w * 4) * 64 + l) * 8;
  #pragma unroll 4
  for (int kb = 0; kb < 8; ++kb){
    s8v A[4];
    #pragma unroll
    for (int mf = 0; mf < 4; ++mf) A[mf] = *(const s8v*)(pw1b + (size_t)kb * 8192 + mf * 512);
    #pragma unroll
    for (int nf = 0; nf < 4; ++nf){
      BU bu;
      bu.d[0] = *(const u64*)(hp[nf] + kb * 32);
      bu.d[1] = *(const u64*)(hp[nf] + kb * 32 + 16);
      #pragma unroll
      for (int mf = 0; mf < 4; ++mf)
        acc[mf][nf] = __builtin_amdgcn_mfma_f32_16x16x32_bf16(A[mf], bu.v, acc[mf][nf], 0, 0, 0);
    }
  }
  #pragma unroll 4
  for (int kb = 8; kb < 16; ++kb){
    s8v A[4];
    #pragma unroll
    for (int mf = 0; mf < 4; ++mf) A[mf] = *(const s8v*)(pw1b + (size_t)kb * 8192 + mf * 512);
    #pragma unroll
    for (int nf = 0; nf < 4; ++nf){
      float4 fa = *(const float4*)(ap[nf] + (kb - 8) * 32);
      float4 fb = *(const float4*)(ap[nf] + (kb - 8) * 32 + 16);
      BU bu;
      bu.d[0] = pack4bf(fa.x, fa.y, fa.z, fa.w);
      bu.d[1] = pack4bf(fb.x, fb.y, fb.z, fb.w);
      #pragma unroll
      for (int mf = 0; mf < 4; ++mf)
        acc[mf][nf] = __builtin_amdgcn_mfma_f32_16x16x32_bf16(A[mf], bu.v, acc[mf][nf], 0, 0, 0);
    }
  }
  #pragma unroll
  for (int mf = 0; mf < 4; ++mf){
    const int fb = w * 64 + mf * 16 + g * 4;
    const int fc = fb >> 2;
    #pragma unroll
    for (int nf = 0; nf < 4; ++nf){
      int e = nf * 16 + li;
      float v0 = siluf(acc[mf][nf][0] + bias_s[fb+0]);
      float v1 = siluf(acc[mf][nf][1] + bias_s[fb+1]);
      float v2 = siluf(acc[mf][nf][2] + bias_s[fb+2]);
      float v3 = siluf(acc[mf][nf][3] + bias_s[fb+3]);
      mt[e * 64 + (fc ^ (e & 7))] = pack4bf(v0, v1, v2, v3);
    }
  }
  __syncthreads();

  #pragma unroll
  for (int a = 0; a < 4; ++a)
    #pragma unroll
    for (int b = 0; b < 4; ++b) acc[a][b] = (f4v){0.f,0.f,0.f,0.f};
  const u16* pw2b = pw2 + ((size_t)(w * 4) * 64 + l) * 8;
  #pragma unroll 4
  for (int kb = 0; kb < 8; ++kb){
    s8v A[4];
    #pragma unroll
    for (int mf = 0; mf < 4; ++mf) A[mf] = *(const s8v*)(pw2b + (size_t)kb * 8192 + mf * 512);
    #pragma unroll
    for (int nf = 0; nf < 4; ++nf){
      int e = nf * 16 + li;
      BU bu;
      bu.d[0] = mt[e * 64 + ((kb * 8 + g)     ^ (e & 7))];
      bu.d[1] = mt[e * 64 + ((kb * 8 + 4 + g) ^ (e & 7))];
      #pragma unroll
      for (int mf = 0; mf < 4; ++mf)
        acc[mf][nf] = __builtin_amdgcn_mfma_f32_16x16x32_bf16(A[mf], bu.v, acc[mf][nf], 0, 0, 0);
    }
  }
  #pragma unroll
  for (int mf = 0; mf < 4; ++mf){
    const int fb = w * 64 + mf * 16 + g * 4;
    #pragma unroll
    for (int nf = 0; nf < 4; ++nf){
      int n = nb + nf * 16 + li;
      if (n < NN){
        float4 hv = *(float4*)(h + (size_t)n * HH + fb);
        float o0 = hv.x + acc[mf][nf][0] + bias_s[256+fb+0];
        float o1 = hv.y + acc[mf][nf][1] + bias_s[256+fb+1];
        float o2 = hv.z + acc[mf][nf][2] + bias_s[256+fb+2];
        float o3 = hv.w + acc[mf][nf][3] + bias_s[256+fb+3];
        *(float4*)(h + (size_t)n * HH + fb) = make_float4(o0, o1, o2, o3);
        *(u64*)(hb + (size_t)n * HH + fb) = pack4bf(o0, o1, o2, o3);
      }
    }
  }
}

// ---------------- emb_out + max-pool ----------------
__global__ __launch_bounds__(256) void emb_out_pool_kernel(
    const u16* __restrict__ hb, const u16* __restrict__ pw,
    const float* __restrict__ bias, const int* __restrict__ batch, u32* __restrict__ pooled){
  const int tid = threadIdx.x;
  const int w = tid >> 6, l = tid & 63, g = l >> 4, li = l & 15;
  const int nb = blockIdx.x * 64;
  const u16* hp[4]; int bs[4];
  #pragma unroll
  for (int nf = 0; nf < 4; ++nf){
    int n = nb + nf * 16 + li; int nc = (n >= NN) ? NN - 1 : n;
    hp[nf] = hb + (size_t)nc * HH + g * 4;
    bs[nf] = batch[nc];
  }
  f4v acc[4][4];
  #pragma unroll
  for (int a = 0; a < 4; ++a)
    #pragma unroll
    for (int b = 0; b < 4; ++b) acc[a][b] = (f4v){0.f,0.f,0.f,0.f};
  const u16* pwb = pw + ((size_t)(w * 4) * 64 + l) * 8;
  #pragma unroll 4
  for (int kb = 0; kb < 8; ++kb){
    s8v A[4];
    #pragma unroll
    for (int mf = 0; mf < 4; ++mf) A[mf] = *(const s8v*)(pwb + (size_t)kb * 8192 + mf * 512);
    #pragma unroll
    for (int nf = 0; nf < 4; ++nf){
      BU bu;
      bu.d[0] = *(const u64*)(hp[nf] + kb * 32);
      bu.d[1] = *(const u64*)(hp[nf] + kb * 32 + 16);
      #pragma unroll
      for (int mf = 0; mf < 4; ++mf)
        acc[mf][nf] = __builtin_amdgcn_mfma_f32_16x16x32_bf16(A[mf], bu.v, acc[mf][nf], 0, 0, 0);
    }
  }
  #pragma unroll
  for (int mf = 0; mf < 4; ++mf){
    const int fb = w * 64 + mf * 16 + g * 4;
    float b0 = bias[fb], b1 = bias[fb+1], b2 = bias[fb+2], b3 = bias[fb+3];
    #pragma unroll
    for (int nf = 0; nf < 4; ++nf){
      int n = nb + nf * 16 + li;
      if (n < NN){
        float vv[4] = {acc[mf][nf][0] + b0, acc[mf][nf][1] + b1, acc[mf][nf][2] + b2, acc[mf][nf][3] + b3};
        #pragma unroll
        for (int r = 0; r < 4; ++r){
          u32 u = __float_as_uint(vv[r]);
          u = (u & 0x80000000u) ? ~u : (u | 0x80000000u);
          atomicMax(&pooled[(size_t)bs[nf] * HH + fb + r], u);
        }
      }
    }
  }
}

// ---------------- resblock + head ----------------
__global__ __launch_bounds__(256) void final_kernel(
    const float* __restrict__ z, const float* __restrict__ rw1, const float* __restrict__ rb1,
    const float* __restrict__ rw2, const float* __restrict__ rb2,
    const float* __restrict__ hw, const float* __restrict__ hbs, float* __restrict__ out){
  __shared__ float zr[272], t1[256], t2[272];
  const int b = blockIdx.x, tid = threadIdx.x;
  for (int i = tid; i < 272; i += 256) zr[i] = z[(size_t)b * 272 + i];
  __syncthreads();
  {
    float a = rb1[tid];
    for (int k = 0; k < 272; ++k) a += zr[k] * rw1[(size_t)k * 256 + tid];
    t1[tid] = siluf(a);
  }
  __syncthreads();
  for (int i = tid; i < 272; i += 256){
    float a = rb2[i] + zr[i];
    for (int k = 0; k < 256; ++k) a += t1[k] * rw2[(size_t)k * 272 + i];
    t2[i] = a;
  }
  __syncthreads();
  for (int p = tid; p < 2000; p += 256){
    float a = hbs[p];
    for (int k = 0; k < 272; ++k) a += t2[k] * hw[(size_t)k * 2000 + p];
    out[(size_t)b * 2000 + p] = a;
  }
}

extern "C" void kernel_launch(void* const* d_in, const int* in_sizes, int n_in,
                              void* d_out, int out_size, void* d_ws, size_t ws_size,
                              hipStream_t stream){
  const float* x        = (const float*)d_in[0];
  const float* pos      = (const float*)d_in[1];
  const float* eattr    = (const float*)d_in[2];
  const float* fragl    = (const float*)d_in[3];
  const float* addf     = (const float*)d_in[4];
  const int*   ei       = (const int*)d_in[5];
  const int*   batch    = (const int*)d_in[6];
  const float* emb_in_w = (const float*)d_in[7];
  const float* emb_in_b = (const float*)d_in[8];
  const float* edge_w1  = (const float*)d_in[9];
  const float* edge_b1  = (const float*)d_in[10];
  const float* edge_w2  = (const float*)d_in[11];
  const float* edge_b2  = (const float*)d_in[12];
  const float* node_w1  = (const float*)d_in[13];
  const float* node_b1  = (const float*)d_in[14];
  const float* node_w2  = (const float*)d_in[15];
  const float* node_b2  = (const float*)d_in[16];
  const float* coord_w1 = (const float*)d_in[17];
  const float* coord_b1 = (const float*)d_in[18];
  const float* coord_w2 = (const float*)d_in[19];
  const float* emb_out_w= (const float*)d_in[20];
  const float* emb_out_b= (const float*)d_in[21];
  const float* res_w1   = (const float*)d_in[22];
  const float* res_b1   = (const float*)d_in[23];
  const float* res_w2   = (const float*)d_in[24];
  const float* res_b2   = (const float*)d_in[25];
  const float* head_w   = (const float*)d_in[26];
  const float* head_b   = (const float*)d_in[27];

  char* ws = (char*)d_ws;
  size_t off = 0;
  auto alloc = [&](size_t bytes) -> void* {
    void* p = ws + off;
    off += (bytes + 255) & ~(size_t)255;
    return p;
  };
  float*  h      = (float*)alloc((size_t)NN * HH * 4);
  float*  agg    = (float*)alloc((size_t)NN * HH * 4);
  u16*    hb     = (u16*)  alloc((size_t)NN * HH * 2);
  float4* coordb = (float4*)alloc((size_t)NN * 16);
  float*  cacc   = (float*)alloc((size_t)NN * 16);
  u32*    pooled = (u32*)  alloc((size_t)BB * HH * 4);
  float*  z      = (float*)alloc((size_t)BB * 272 * 4);
  u16*    packed = (u16*)  alloc((size_t)7680 * 256 * 2);
  int*    icnt   = (int*)  alloc((size_t)NN * 4);
  int*    iscan  = (int*)  alloc((size_t)NN * 4);
  int*    rstart = (int*)  alloc((size_t)NN * 4);
  int*    cursor = (int*)  alloc((size_t)NN * 4);
  int*    bsum   = (int*)  alloc((size_t)128 * 4);
  int*    seid   = (int*)  alloc((size_t)EE * 4);
  int*    srow   = (int*)  alloc((size_t)EE * 4);
  int*    scol   = (int*)  alloc((size_t)EE * 4);
  if (off > ws_size) return;

  u16* pk_embin  = packed;
  u16* pk_embout = packed + 32768 + (size_t)4 * 466944;
  auto pk_ew1 = [&](int l){ return packed + 32768 + (size_t)l * 466944; };
  auto pk_ew2 = [&](int l){ return pk_ew1(l) + 139264; };
  auto pk_cw1 = [&](int l){ return pk_ew1(l) + 204800; };
  auto pk_nw1 = [&](int l){ return pk_ew1(l) + 270336; };
  auto pk_nw2 = [&](int l){ return pk_ew1(l) + 401408; };

  pack_kernel<<<16, 256, 0, stream>>>(emb_in_w, pk_embin, 128, 4);
  for (int l = 0; l < 4; ++l){
    pack_kernel<<<68, 256, 0, stream>>>(edge_w1 + (size_t)l * 529 * 256, pk_ew1(l), 529, 17);
    pack_kernel<<<32, 256, 0, stream>>>(edge_w2 + (size_t)l * 65536,     pk_ew2(l), 256, 8);
    pack_kernel<<<32, 256, 0, stream>>>(coord_w1 + (size_t)l * 65536,    pk_cw1(l), 256, 8);
    pack_kernel<<<64, 256, 0, stream>>>(node_w1 + (size_t)l * 131072,    pk_nw1(l), 512, 16);
    pack_kernel<<<32, 256, 0, stream>>>(node_w2 + (size_t)l * 65536,     pk_nw2(l), 256, 8);
  }
  pack_kernel<<<32, 256, 0, stream>>>(emb_out_w, pk_embout, 256, 8);

  // ---- one-time edge sort by row
  const int NB = (NN + 255) / 256;   // 79
  hipMemsetAsync(icnt,   0, (size_t)NN * 4, stream);
  hipMemsetAsync(cursor, 0, (size_t)NN * 4, stream);
  icnt_kernel<<<(EE + 255) / 256, 256, 0, stream>>>(ei, icnt);
  iscan_block<<<NB, 256, 0, stream>>>(icnt, iscan, bsum);
  iscan_top<<<1, 64, 0, stream>>>(bsum, NB);
  iscan_fix<<<NB, 256, 0, stream>>>(icnt, iscan, bsum, rstart);
  scatter_kernel<<<(EE + 255) / 256, 256, 0, stream>>>(ei, rstart, cursor, seid, srow, scol);

  coord_init_kernel<<<79, 256, 0, stream>>>(pos, coordb);
  emb_in_kernel<<<313, 256, 0, stream>>>(x, pk_embin, emb_in_b, h, hb);

  for (int l = 0; l < 4; ++l){
    hipMemsetAsync(agg,  0, (size_t)NN * HH * 4, stream);
    hipMemsetAsync(cacc, 0, (size_t)NN * 16, stream);
    edge_kernel<<<5000, 256, 0, stream>>>(hb, coordb, srow, scol, seid, eattr,
        pk_ew1(l), pk_ew2(l), pk_cw1(l),
        edge_b1 + l * 256, edge_b2 + l * 256, coord_b1 + l * 256, coord_w2 + l * 256,
        agg, cacc);
    coord_upd_kernel<<<79, 256, 0, stream>>>(coordb, cacc, icnt);
    node_kernel<<<313, 256, 0, stream>>>(h, hb, agg, pk_nw1(l), pk_nw2(l),
        node_b1 + l * 256, node_b2 + l * 256);
  }

  pool_init_kernel<<<128, 256, 0, stream>>>(pooled);
  emb_out_pool_kernel<<<313, 256, 0, stream>>>(hb, pk_embout, emb_out_b, batch, pooled);
  build_z_kernel<<<136, 256, 0, stream>>>(pooled, fragl, addf, z);
  final_kernel<<<128, 256, 0, stream>>>(z, res_w1, res_b1, res_w2, res_b2, head_w, head_b,
                                        (float*)d_out);
}

// Round 4
// 2404.212 us; speedup vs baseline: 2.3369x; 1.0644x over previous
//
#include <hip/hip_runtime.h>

typedef unsigned short u16;
typedef unsigned int   u32;
typedef unsigned long long u64;
typedef __attribute__((ext_vector_type(8))) short s8v;   // 8 bf16 (4 VGPRs) MFMA operand
typedef __attribute__((ext_vector_type(4))) float f4v;   // MFMA accumulator

#define NN 20000
#define EE 320000
#define BB 128
#define HH 256

union BU { u64 d[2]; s8v v; };

__device__ __forceinline__ u16 f2bf(float f){
  u32 u = __float_as_uint(f);
  return (u16)((u + 0x7FFFu + ((u >> 16) & 1u)) >> 16);   // RNE
}
__device__ __forceinline__ float bf2f(u16 u){ return __uint_as_float((u32)u << 16); }
// hardware packed f32->bf16 (RNE), low16 = a, high16 = b
__device__ __forceinline__ u32 cvt2(float a, float b){
  u32 r; asm("v_cvt_pk_bf16_f32 %0, %1, %2" : "=v"(r) : "v"(a), "v"(b)); return r;
}
__device__ __forceinline__ u64 pack4bf(float a, float b, float c, float d){
  return (u64)cvt2(a, b) | ((u64)cvt2(c, d) << 32);
}
__device__ __forceinline__ float siluf(float v){ return v / (1.0f + __expf(-v)); }

// ---------------- weight packing: W [K][256] f32 -> A-fragment blob (W^T), bf16 ----------------
__global__ void pack_kernel(const float* __restrict__ src, u16* __restrict__ dst, int K, int KB){
  int t = blockIdx.x * 256 + threadIdx.x;
  if (t >= KB * 1024) return;
  int lane = t & 63, mf = (t >> 6) & 15, kb = t >> 10;
  int g = lane >> 4, li = lane & 15;
  int m = mf * 16 + li;
  u16 o[8];
  #pragma unroll
  for (int j = 0; j < 8; ++j){
    int k = kb * 32 + ((j < 4) ? (g * 4 + j) : (16 + g * 4 + (j - 4)));
    o[j] = (k < K) ? f2bf(src[(size_t)k * 256 + m]) : (u16)0;
  }
  u16* d = dst + ((size_t)(kb * 16 + mf) * 64 + lane) * 8;
  *(u64*)(d)     = (u64)o[0] | ((u64)o[1] << 16) | ((u64)o[2] << 32) | ((u64)o[3] << 48);
  *(u64*)(d + 4) = (u64)o[4] | ((u64)o[5] << 16) | ((u64)o[6] << 32) | ((u64)o[7] << 48);
}

// ---------------- edge sort by destination row (one-time per launch) ----------------
__global__ void icnt_kernel(const int* __restrict__ ei, int* __restrict__ icnt){
  int t = blockIdx.x * 256 + threadIdx.x;
  if (t < EE) atomicAdd(&icnt[ei[t]], 1);
}
__global__ void iscan_block(const int* __restrict__ icnt, int* __restrict__ iscan, int* __restrict__ bsum){
  __shared__ int s[256];
  int i = blockIdx.x * 256 + threadIdx.x;
  int v = (i < NN) ? icnt[i] : 0;
  s[threadIdx.x] = v; __syncthreads();
  #pragma unroll
  for (int d = 1; d < 256; d <<= 1){
    int t = (threadIdx.x >= d) ? s[threadIdx.x - d] : 0;
    __syncthreads();
    s[threadIdx.x] += t;
    __syncthreads();
  }
  if (i < NN) iscan[i] = s[threadIdx.x];
  if (threadIdx.x == 255) bsum[blockIdx.x] = s[255];
}
__global__ void iscan_top(int* __restrict__ bsum, int nb){
  if (blockIdx.x == 0 && threadIdx.x == 0){
    int acc = 0;
    for (int i = 0; i < nb; ++i){ int t = bsum[i]; bsum[i] = acc; acc += t; }
  }
}
__global__ void iscan_fix(const int* __restrict__ icnt, const int* __restrict__ iscan,
                          const int* __restrict__ bsum, int* __restrict__ rstart){
  int i = blockIdx.x * 256 + threadIdx.x;
  if (i < NN) rstart[i] = bsum[blockIdx.x] + iscan[i] - icnt[i];
}
__global__ void scatter_kernel(const int* __restrict__ ei, const int* __restrict__ rstart,
                               int* __restrict__ cursor, int* __restrict__ seid,
                               int* __restrict__ srow, int* __restrict__ scol){
  int e = blockIdx.x * 256 + threadIdx.x;
  if (e < EE){
    int r = ei[e];
    int p = rstart[r] + atomicAdd(&cursor[r], 1);
    seid[p] = e; srow[p] = r; scol[p] = ei[EE + e];
  }
}

// ---------------- small utility kernels ----------------
__global__ void coord_init_kernel(const float* __restrict__ pos, float4* __restrict__ coord){
  int t = blockIdx.x * 256 + threadIdx.x;
  if (t < NN) coord[t] = make_float4(pos[3*t], pos[3*t+1], pos[3*t+2], 0.f);
}
__global__ void coord_upd_kernel(float4* __restrict__ coord, const float* __restrict__ cacc,
                                 const int* __restrict__ icnt){
  int t = blockIdx.x * 256 + threadIdx.x;
  if (t >= NN) return;
  float k = fmaxf((float)icnt[t], 1.0f);
  float4 c = coord[t];
  c.x += cacc[4*t+0] / k; c.y += cacc[4*t+1] / k; c.z += cacc[4*t+2] / k;
  coord[t] = c;
}
__global__ void pool_init_kernel(u32* __restrict__ pooled){
  int t = blockIdx.x * 256 + threadIdx.x;
  if (t < BB * HH){
    u32 u = __float_as_uint(-3.0e38f);
    pooled[t] = ~u;
  }
}
__global__ void build_z_kernel(const u32* __restrict__ pooled, const float* __restrict__ fragl,
                               const float* __restrict__ addf, float* __restrict__ z){
  int t = blockIdx.x * 256 + threadIdx.x;
  if (t >= BB * 272) return;
  int b = t / 272, j = t % 272;
  float v;
  if (j < 256){
    u32 u = pooled[b * 256 + j];
    v = (u & 0x80000000u) ? __uint_as_float(u & 0x7FFFFFFFu) : __uint_as_float(~u);
  } else if (j < 264) v = fragl[b * 8 + (j - 256)];
  else                v = addf[b * 8 + (j - 264)];
  z[t] = v;
}

// ---------------- CSR segment-sum: agg_bf[n][f] = bf16( sum_e m2[e][f] ) ----------------
__global__ __launch_bounds__(256) void agg_csr_kernel(
    const u16* __restrict__ m2b, const int* __restrict__ rstart,
    const int* __restrict__ icnt, u16* __restrict__ agg_bf){
  const int n = blockIdx.x, f = threadIdx.x;
  const int s = rstart[n], d = icnt[n];
  const u16* p = m2b + (size_t)s * 256 + f;
  float a0 = 0.f, a1 = 0.f;
  int i = 0;
  for (; i + 1 < d; i += 2){ a0 += bf2f(p[(size_t)i * 256]); a1 += bf2f(p[(size_t)(i + 1) * 256]); }
  if (i < d) a0 += bf2f(p[(size_t)i * 256]);
  agg_bf[(size_t)n * 256 + f] = f2bf(a0 + a1);
}
// fallback path: convert f32 agg -> bf16
__global__ void agg_conv_kernel(const float* __restrict__ agg, u16* __restrict__ agg_bf){
  int t = blockIdx.x * 256 + threadIdx.x;
  if (t < NN * HH) agg_bf[t] = f2bf(agg[t]);
}

// ---------------- emb_in: h = x @ emb_in_w + b ----------------
__global__ __launch_bounds__(256) void emb_in_kernel(
    const float* __restrict__ x, const u16* __restrict__ pw,
    const float* __restrict__ bias, float* __restrict__ h, u16* __restrict__ hb){
  const int tid = threadIdx.x;
  const int w = tid >> 6, l = tid & 63, g = l >> 4, li = l & 15;
  const int nb = blockIdx.x * 64;
  const float* xp[4];
  #pragma unroll
  for (int nf = 0; nf < 4; ++nf){
    int n = nb + nf * 16 + li; if (n >= NN) n = NN - 1;
    xp[nf] = x + (size_t)n * 128 + g * 4;
  }
  f4v acc[4][4];
  #pragma unroll
  for (int a = 0; a < 4; ++a)
    #pragma unroll
    for (int b = 0; b < 4; ++b) acc[a][b] = (f4v){0.f,0.f,0.f,0.f};
  const u16* pwb = pw + ((size_t)(w * 4) * 64 + l) * 8;
  #pragma unroll
  for (int kb = 0; kb < 4; ++kb){
    s8v A[4];
    #pragma unroll
    for (int mf = 0; mf < 4; ++mf) A[mf] = *(const s8v*)(pwb + (size_t)kb * 8192 + mf * 512);
    #pragma unroll
    for (int nf = 0; nf < 4; ++nf){
      float4 fa = *(const float4*)(xp[nf] + kb * 32);
      float4 fb = *(const float4*)(xp[nf] + kb * 32 + 16);
      BU bu;
      bu.d[0] = pack4bf(fa.x, fa.y, fa.z, fa.w);
      bu.d[1] = pack4bf(fb.x, fb.y, fb.z, fb.w);
      #pragma unroll
      for (int mf = 0; mf < 4; ++mf)
        acc[mf][nf] = __builtin_amdgcn_mfma_f32_16x16x32_bf16(A[mf], bu.v, acc[mf][nf], 0, 0, 0);
    }
  }
  #pragma unroll
  for (int mf = 0; mf < 4; ++mf){
    const int fb = w * 64 + mf * 16 + g * 4;
    float b0 = bias[fb], b1 = bias[fb+1], b2 = bias[fb+2], b3 = bias[fb+3];
    #pragma unroll
    for (int nf = 0; nf < 4; ++nf){
      int n = nb + nf * 16 + li;
      if (n < NN){
        float o0 = acc[mf][nf][0] + b0, o1 = acc[mf][nf][1] + b1;
        float o2 = acc[mf][nf][2] + b2, o3 = acc[mf][nf][3] + b3;
        *(float4*)(h + (size_t)n * HH + fb) = make_float4(o0, o1, o2, o3);
        *(u64*)(hb + (size_t)n * HH + fb) = pack4bf(o0, o1, o2, o3);
      }
    }
  }
}

// ---------------- edge kernel: 64 SORTED edges/block ----------------
// STREAM=1: m2 streamed (coalesced bf16) to global; aggregation done by agg_csr_kernel.
// STREAM=0: R3 fallback (segmented shuffle reduce + atomics) when workspace is small.
template<bool STREAM>
__global__ __launch_bounds__(256) void edge_kernel(
    const u16* __restrict__ hb, const float4* __restrict__ coord,
    const int* __restrict__ srow, const int* __restrict__ scol, const int* __restrict__ seid,
    const float* __restrict__ eattr,
    const u16* __restrict__ pw1, const u16* __restrict__ pw2, const u16* __restrict__ pw3,
    const float* __restrict__ b1, const float* __restrict__ b2,
    const float* __restrict__ cb1, const float* __restrict__ cw2,
    float* __restrict__ agg, float* __restrict__ cacc, u64* __restrict__ m2g){
  __shared__ u64 mt[4096];            // 32KB swizzled tile [64 edges][64 4-feat chunks]
  __shared__ float4 dif[64];          // diff.xyz, radial
  __shared__ int rows_s[64];
  __shared__ int cols_s[64];
  __shared__ int seid_s[64];
  __shared__ float bias_s[1024];      // b1 | b2 | cb1 | cw2
  __shared__ float cpart[4][64];

  const int tid = threadIdx.x;
  const int w = tid >> 6, l = tid & 63, g = l >> 4, li = l & 15;
  const int eb = blockIdx.x * 64;

  if (tid < 64){
    int sp = eb + tid;
    int r = srow[sp], c = scol[sp];
    rows_s[tid] = r; cols_s[tid] = c; seid_s[tid] = seid[sp];
    float4 ca = coord[r], cb = coord[c];
    float dx = ca.x - cb.x, dy = ca.y - cb.y, dz = ca.z - cb.z;
    float rad = dx*dx + dy*dy + dz*dz;
    dif[tid] = make_float4(dx, dy, dz, rad);
  }
  for (int i = tid; i < 1024; i += 256){
    float v;
    if      (i < 256) v = b1[i];
    else if (i < 512) v = b2[i - 256];
    else if (i < 768) v = cb1[i - 512];
    else              v = cw2[i - 768];
    bias_s[i] = v;
  }
  __syncthreads();

  const u16* rp[4]; const u16* cp[4];
  #pragma unroll
  for (int nf = 0; nf < 4; ++nf){
    int e = nf * 16 + li;
    rp[nf] = hb + (size_t)rows_s[e] * HH + g * 4;
    cp[nf] = hb + (size_t)cols_s[e] * HH + g * 4;
  }

  f4v acc[4][4];
  #pragma unroll
  for (int a = 0; a < 4; ++a)
    #pragma unroll
    for (int b = 0; b < 4; ++b) acc[a][b] = (f4v){0.f,0.f,0.f,0.f};

  const u16* pw1b = pw1 + ((size_t)(w * 4) * 64 + l) * 8;
  const u16* pw2b = pw2 + ((size_t)(w * 4) * 64 + l) * 8;
  const u16* pw3b = pw3 + ((size_t)(w * 4) * 64 + l) * 8;

  // ---- tail operand prefetch (k 512..543: radial | edge_attr | 0-pad), built in regs
  float tf[4][4];
  float rads[4];
  #pragma unroll
  for (int nf = 0; nf < 4; ++nf){
    int e = nf * 16 + li;
    const float* ep = eattr + (size_t)seid_s[e] * 16;
    if (g == 0){ tf[nf][0] = ep[0]; tf[nf][1] = ep[1]; tf[nf][2] = ep[2]; tf[nf][3] = ep[15]; }
    else { int i0 = g * 4 - 1; tf[nf][0] = ep[i0]; tf[nf][1] = ep[i0+1]; tf[nf][2] = ep[i0+2]; tf[nf][3] = ep[i0+3]; }
    rads[nf] = dif[e].w;
  }
  s8v at[4];
  #pragma unroll
  for (int mf = 0; mf < 4; ++mf) at[mf] = *(const s8v*)(pw1b + (size_t)16 * 8192 + mf * 512);

  // ---- GEMM1: 16 k-block steps (8 row + 8 col), depth-4 register pipeline
  s8v sa[4][4];
  u64 sb[4][4][2];
  #pragma unroll
  for (int s = 0; s < 4; ++s){
    #pragma unroll
    for (int mf = 0; mf < 4; ++mf) sa[s][mf] = *(const s8v*)(pw1b + (size_t)s * 8192 + mf * 512);
    #pragma unroll
    for (int nf = 0; nf < 4; ++nf){
      sb[s][nf][0] = *(const u64*)(rp[nf] + s * 32);
      sb[s][nf][1] = *(const u64*)(rp[nf] + s * 32 + 16);
    }
  }
  #pragma unroll
  for (int s = 0; s < 16; ++s){
    const int sl = s & 3;
    #pragma unroll
    for (int nf = 0; nf < 4; ++nf){
      BU bu; bu.d[0] = sb[sl][nf][0]; bu.d[1] = sb[sl][nf][1];
      #pragma unroll
      for (int mf = 0; mf < 4; ++mf)
        acc[mf][nf] = __builtin_amdgcn_mfma_f32_16x16x32_bf16(sa[sl][mf], bu.v, acc[mf][nf], 0, 0, 0);
    }
    if (s + 4 < 16){
      const int nx = s + 4;
      #pragma unroll
      for (int mf = 0; mf < 4; ++mf)
        sa[sl][mf] = *(const s8v*)(pw1b + (size_t)nx * 8192 + mf * 512);
      #pragma unroll
      for (int nf = 0; nf < 4; ++nf){
        const u16* bp = (nx < 8) ? rp[nf] : cp[nf];
        const int ko = (nx & 7) * 32;
        sb[sl][nf][0] = *(const u64*)(bp + ko);
        sb[sl][nf][1] = *(const u64*)(bp + ko + 16);
      }
    }
  }
  // tail k-block
  #pragma unroll
  for (int nf = 0; nf < 4; ++nf){
    BU bu;
    if (g == 0){ bu.d[0] = pack4bf(rads[nf], tf[nf][0], tf[nf][1], tf[nf][2]); bu.d[1] = (u64)(cvt2(tf[nf][3], 0.f) & 0xffffu); }
    else       { bu.d[0] = pack4bf(tf[nf][0], tf[nf][1], tf[nf][2], tf[nf][3]); bu.d[1] = 0; }
    #pragma unroll
    for (int mf = 0; mf < 4; ++mf)
      acc[mf][nf] = __builtin_amdgcn_mfma_f32_16x16x32_bf16(at[mf], bu.v, acc[mf][nf], 0, 0, 0);
  }

  // bias + silu -> m1 tile (swizzled LDS)
  #pragma unroll
  for (int mf = 0; mf < 4; ++mf){
    const int fb = w * 64 + mf * 16 + g * 4;
    const int fc = fb >> 2;
    #pragma unroll
    for (int nf = 0; nf < 4; ++nf){
      int e = nf * 16 + li;
      float v0 = siluf(acc[mf][nf][0] + bias_s[fb+0]);
      float v1 = siluf(acc[mf][nf][1] + bias_s[fb+1]);
      float v2 = siluf(acc[mf][nf][2] + bias_s[fb+2]);
      float v3 = siluf(acc[mf][nf][3] + bias_s[fb+3]);
      mt[e * 64 + (fc ^ (e & 7))] = pack4bf(v0, v1, v2, v3);
    }
  }
  __syncthreads();

  // ---- GEMM2: m2 = silu(m1 @ W2 + b2)
  #pragma unroll
  for (int a = 0; a < 4; ++a)
    #pragma unroll
    for (int b = 0; b < 4; ++b) acc[a][b] = (f4v){0.f,0.f,0.f,0.f};
  #pragma unroll
  for (int s = 0; s < 4; ++s)
    #pragma unroll
    for (int mf = 0; mf < 4; ++mf) sa[s][mf] = *(const s8v*)(pw2b + (size_t)s * 8192 + mf * 512);
  #pragma unroll
  for (int s = 0; s < 8; ++s){
    const int sl = s & 3;
    #pragma unroll
    for (int nf = 0; nf < 4; ++nf){
      int e = nf * 16 + li;
      BU bu;
      bu.d[0] = mt[e * 64 + ((s * 8 + g)     ^ (e & 7))];
      bu.d[1] = mt[e * 64 + ((s * 8 + 4 + g) ^ (e & 7))];
      #pragma unroll
      for (int mf = 0; mf < 4; ++mf)
        acc[mf][nf] = __builtin_amdgcn_mfma_f32_16x16x32_bf16(sa[sl][mf], bu.v, acc[mf][nf], 0, 0, 0);
    }
    if (s + 4 < 8){
      #pragma unroll
      for (int mf = 0; mf < 4; ++mf)
        sa[sl][mf] = *(const s8v*)(pw2b + (size_t)(s + 4) * 8192 + mf * 512);
    }
  }
  f4v m2s[4][4];
  #pragma unroll
  for (int mf = 0; mf < 4; ++mf){
    const int fb = w * 64 + mf * 16 + g * 4;
    #pragma unroll
    for (int nf = 0; nf < 4; ++nf){
      #pragma unroll
      for (int r = 0; r < 4; ++r)
        m2s[mf][nf][r] = siluf(acc[mf][nf][r] + bias_s[256 + fb + r]);
    }
  }
  __syncthreads();
  #pragma unroll
  for (int mf = 0; mf < 4; ++mf){
    const int fb = w * 64 + mf * 16 + g * 4;
    const int fc = fb >> 2;
    #pragma unroll
    for (int nf = 0; nf < 4; ++nf){
      int e = nf * 16 + li;
      mt[e * 64 + (fc ^ (e & 7))] = pack4bf(m2s[mf][nf][0], m2s[mf][nf][1], m2s[mf][nf][2], m2s[mf][nf][3]);
    }
  }
  __syncthreads();

  // ---- STREAM: coalesced write-out of m2 tile (overlaps GEMM3's MFMAs)
  if (STREAM){
    u64* dst = m2g + (size_t)eb * 64;
    #pragma unroll
    for (int j = 0; j < 16; ++j){
      int q = j * 256 + tid;
      int e = q >> 6, fc = q & 63;
      dst[(size_t)e * 64 + fc] = mt[e * 64 + (fc ^ (e & 7))];
    }
  }

  // ---- GEMM3: q = silu(m2 @ CW1 + cb1); c = q . cw2
  #pragma unroll
  for (int a = 0; a < 4; ++a)
    #pragma unroll
    for (int b = 0; b < 4; ++b) acc[a][b] = (f4v){0.f,0.f,0.f,0.f};
  #pragma unroll
  for (int s = 0; s < 4; ++s)
    #pragma unroll
    for (int mf = 0; mf < 4; ++mf) sa[s][mf] = *(const s8v*)(pw3b + (size_t)s * 8192 + mf * 512);
  #pragma unroll
  for (int s = 0; s < 8; ++s){
    const int sl = s & 3;
    #pragma unroll
    for (int nf = 0; nf < 4; ++nf){
      int e = nf * 16 + li;
      BU bu;
      bu.d[0] = mt[e * 64 + ((s * 8 + g)     ^ (e & 7))];
      bu.d[1] = mt[e * 64 + ((s * 8 + 4 + g) ^ (e & 7))];
      #pragma unroll
      for (int mf = 0; mf < 4; ++mf)
        acc[mf][nf] = __builtin_amdgcn_mfma_f32_16x16x32_bf16(sa[sl][mf], bu.v, acc[mf][nf], 0, 0, 0);
    }
    if (s + 4 < 8){
      #pragma unroll
      for (int mf = 0; mf < 4; ++mf)
        sa[sl][mf] = *(const s8v*)(pw3b + (size_t)(s + 4) * 8192 + mf * 512);
    }
  }
  float cp4[4] = {0.f, 0.f, 0.f, 0.f};
  #pragma unroll
  for (int mf = 0; mf < 4; ++mf){
    const int fb = w * 64 + mf * 16 + g * 4;
    #pragma unroll
    for (int nf = 0; nf < 4; ++nf){
      #pragma unroll
      for (int r = 0; r < 4; ++r){
        float q = siluf(acc[mf][nf][r] + bias_s[512 + fb + r]);
        cp4[nf] += q * bias_s[768 + fb + r];
      }
    }
  }
  #pragma unroll
  for (int nf = 0; nf < 4; ++nf){
    float v = cp4[nf];
    v += __shfl_xor(v, 16, 64);
    v += __shfl_xor(v, 32, 64);
    if (g == 0) cpart[w][nf * 16 + li] = v;
  }
  __syncthreads();

  // ---- cacc: segmented suffix-reduce across the 64 sorted edges, head lanes atomic
  if (tid < 64){
    float c = cpart[0][tid] + cpart[1][tid] + cpart[2][tid] + cpart[3][tid];
    float4 d = dif[tid];
    const int myrow = rows_s[tid];
    float vx = d.x * c, vy = d.y * c, vz = d.z * c;
    #pragma unroll
    for (int dd = 1; dd < 64; dd <<= 1){
      const int rr = __shfl_down(myrow, dd, 64);
      const bool ok = ((tid + dd) < 64) && (rr == myrow);
      float tx = __shfl_down(vx, dd, 64);
      float ty = __shfl_down(vy, dd, 64);
      float tz = __shfl_down(vz, dd, 64);
      if (ok){ vx += tx; vy += ty; vz += tz; }
    }
    if (tid == 0 || rows_s[tid - 1] != myrow){
      atomicAdd(cacc + (size_t)myrow * 4 + 0, vx);
      atomicAdd(cacc + (size_t)myrow * 4 + 1, vy);
      atomicAdd(cacc + (size_t)myrow * 4 + 2, vz);
    }
  }

  // ---- fallback path only: agg via segmented suffix-reduce + atomics
  if (!STREAM){
    #pragma unroll
    for (int nf = 0; nf < 4; ++nf){
      const int myrow = rows_s[nf * 16 + li];
      const bool head = (li == 0) || (rows_s[nf * 16 + li - 1] != myrow);
      float v[16];
      #pragma unroll
      for (int mf = 0; mf < 4; ++mf)
        #pragma unroll
        for (int r = 0; r < 4; ++r) v[mf * 4 + r] = m2s[mf][nf][r];
      #pragma unroll
      for (int d = 1; d < 16; d <<= 1){
        const int rr = __shfl_down(myrow, d, 16);
        const bool ok = ((li + d) < 16) && (rr == myrow);
        #pragma unroll
        for (int j = 0; j < 16; ++j){
          const float vv = __shfl_down(v[j], d, 16);
          if (ok) v[j] += vv;
        }
      }
      if (head){
        #pragma unroll
        for (int mf = 0; mf < 4; ++mf){
          float* ag = agg + (size_t)myrow * HH + w * 64 + mf * 16 + g * 4;
          atomicAdd(ag + 0, v[mf * 4 + 0]);
          atomicAdd(ag + 1, v[mf * 4 + 1]);
          atomicAdd(ag + 2, v[mf * 4 + 2]);
          atomicAdd(ag + 3, v[mf * 4 + 3]);
        }
      }
    }
  }
}

// ---------------- node kernel: h += MLP([h, agg]) ; agg read as bf16 ----------------
__global__ __launch_bounds__(256) void node_kernel(
    float* __restrict__ h, u16* __restrict__ hb, const u16* __restrict__ agg_bf,
    const u16* __restrict__ pw1, const u16* __restrict__ pw2,
    const float* __restrict__ b1, const float* __restrict__ b2){
  __shared__ u64 mt[4096];
  __shared__ float bias_s[512];
  const int tid = threadIdx.x;
  const int w = tid >> 6, l = tid & 63, g = l >> 4, li = l & 15;
  const int nb = blockIdx.x * 64;
  for (int i = tid; i < 512; i += 256) bias_s[i] = (i < 256) ? b1[i] : b2[i - 256];
  __syncthreads();

  const u16* hp[4]; const u16* ap[4];
  #pragma unroll
  for (int nf = 0; nf < 4; ++nf){
    int n = nb + nf * 16 + li; if (n >= NN) n = NN - 1;
    hp[nf] = hb     + (size_t)n * HH + g * 4;
    ap[nf] = agg_bf + (size_t)n * HH + g * 4;
  }
  f4v acc[4][4];
  #pragma unroll
  for (int a = 0; a < 4; ++a)
    #pragma unroll
    for (int b = 0; b < 4; ++b) acc[a][b] = (f4v){0.f,0.f,0.f,0.f};

  const u16* pw1b = pw1 + ((size_t)(w * 4) * 64 + l) * 8;
  #pragma unroll 4
  for (int kb = 0; kb < 8; ++kb){
    s8v A[4];
    #pragma unroll
    for (int mf = 0; mf < 4; ++mf) A[mf] = *(const s8v*)(pw1b + (size_t)kb * 8192 + mf * 512);
    #pragma unroll
    for (int nf = 0; nf < 4; ++nf){
      BU bu;
      bu.d[0] = *(const u64*)(hp[nf] + kb * 32);
      bu.d[1] = *(const u64*)(hp[nf] + kb * 32 + 16);
      #pragma unroll
      for (int mf = 0; mf < 4; ++mf)
        acc[mf][nf] = __builtin_amdgcn_mfma_f32_16x16x32_bf16(A[mf], bu.v, acc[mf][nf], 0, 0, 0);
    }
  }
  #pragma unroll 4
  for (int kb = 8; kb < 16; ++kb){
    s8v A[4];
    #pragma unroll
    for (int mf = 0; mf < 4; ++mf) A[mf] = *(const s8v*)(pw1b + (size_t)kb * 8192 + mf * 512);
    #pragma unroll
    for (int nf = 0; nf < 4; ++nf){
      BU bu;
      bu.d[0] = *(const u64*)(ap[nf] + (kb - 8) * 32);
      bu.d[1] = *(const u64*)(ap[nf] + (kb - 8) * 32 + 16);
      #pragma unroll
      for (int mf = 0; mf < 4; ++mf)
        acc[mf][nf] = __builtin_amdgcn_mfma_f32_16x16x32_bf16(A[mf], bu.v, acc[mf][nf], 0, 0, 0);
    }
  }
  #pragma unroll
  for (int mf = 0; mf < 4; ++mf){
    const int fb = w * 64 + mf * 16 + g * 4;
    const int fc = fb >> 2;
    #pragma unroll
    for (int nf = 0; nf < 4; ++nf){
      int e = nf * 16 + li;
      float v0 = siluf(acc[mf][nf][0] + bias_s[fb+0]);
      float v1 = siluf(acc[mf][nf][1] + bias_s[fb+1]);
      float v2 = siluf(acc[mf][nf][2] + bias_s[fb+2]);
      float v3 = siluf(acc[mf][nf][3] + bias_s[fb+3]);
      mt[e * 64 + (fc ^ (e & 7))] = pack4bf(v0, v1, v2, v3);
    }
  }
  __syncthreads();

  #pragma unroll
  for (int a = 0; a < 4; ++a)
    #pragma unroll
    for (int b = 0; b < 4; ++b) acc[a][b] = (f4v){0.f,0.f,0.f,0.f};
  const u16* pw2b = pw2 + ((size_t)(w * 4) * 64 + l) * 8;
  #pragma unroll 4
  for (int kb = 0; kb < 8; ++kb){
    s8v A[4];
    #pragma unroll
    for (int mf = 0; mf < 4; ++mf) A[mf] = *(const s8v*)(pw2b + (size_t)kb * 8192 + mf * 512);
    #pragma unroll
    for (int nf = 0; nf < 4; ++nf){
      int e = nf * 16 + li;
      BU bu;
      bu.d[0] = mt[e * 64 + ((kb * 8 + g)     ^ (e & 7))];
      bu.d[1] = mt[e * 64 + ((kb * 8 + 4 + g) ^ (e & 7))];
      #pragma unroll
      for (int mf = 0; mf < 4; ++mf)
        acc[mf][nf] = __builtin_amdgcn_mfma_f32_16x16x32_bf16(A[mf], bu.v, acc[mf][nf], 0, 0, 0);
    }
  }
  #pragma unroll
  for (int mf = 0; mf < 4; ++mf){
    const int fb = w * 64 + mf * 16 + g * 4;
    #pragma unroll
    for (int nf = 0; nf < 4; ++nf){
      int n = nb + nf * 16 + li;
      if (n < NN){
        float4 hv = *(float4*)(h + (size_t)n * HH + fb);
        float o0 = hv.x + acc[mf][nf][0] + bias_s[256+fb+0];
        float o1 = hv.y + acc[mf][nf][1] + bias_s[256+fb+1];
        float o2 = hv.z + acc[mf][nf][2] + bias_s[256+fb+2];
        float o3 = hv.w + acc[mf][nf][3] + bias_s[256+fb+3];
        *(float4*)(h + (size_t)n * HH + fb) = make_float4(o0, o1, o2, o3);
        *(u64*)(hb + (size_t)n * HH + fb) = pack4bf(o0, o1, o2, o3);
      }
    }
  }
}

// ---------------- emb_out + max-pool ----------------
__global__ __launch_bounds__(256) void emb_out_pool_kernel(
    const u16* __restrict__ hb, const u16* __restrict__ pw,
    const float* __restrict__ bias, const int* __restrict__ batch, u32* __restrict__ pooled){
  const int tid = threadIdx.x;
  const int w = tid >> 6, l = tid & 63, g = l >> 4, li = l & 15;
  const int nb = blockIdx.x * 64;
  const u16* hp[4]; int bs[4];
  #pragma unroll
  for (int nf = 0; nf < 4; ++nf){
    int n = nb + nf * 16 + li; int nc = (n >= NN) ? NN - 1 : n;
    hp[nf] = hb + (size_t)nc * HH + g * 4;
    bs[nf] = batch[nc];
  }
  f4v acc[4][4];
  #pragma unroll
  for (int a = 0; a < 4; ++a)
    #pragma unroll
    for (int b = 0; b < 4; ++b) acc[a][b] = (f4v){0.f,0.f,0.f,0.f};
  const u16* pwb = pw + ((size_t)(w * 4) * 64 + l) * 8;
  #pragma unroll 4
  for (int kb = 0; kb < 8; ++kb){
    s8v A[4];
    #pragma unroll
    for (int mf = 0; mf < 4; ++mf) A[mf] = *(const s8v*)(pwb + (size_t)kb * 8192 + mf * 512);
    #pragma unroll
    for (int nf = 0; nf < 4; ++nf){
      BU bu;
      bu.d[0] = *(const u64*)(hp[nf] + kb * 32);
      bu.d[1] = *(const u64*)(hp[nf] + kb * 32 + 16);
      #pragma unroll
      for (int mf = 0; mf < 4; ++mf)
        acc[mf][nf] = __builtin_amdgcn_mfma_f32_16x16x32_bf16(A[mf], bu.v, acc[mf][nf], 0, 0, 0);
    }
  }
  #pragma unroll
  for (int mf = 0; mf < 4; ++mf){
    const int fb = w * 64 + mf * 16 + g * 4;
    float b0 = bias[fb], b1 = bias[fb+1], b2 = bias[fb+2], b3 = bias[fb+3];
    #pragma unroll
    for (int nf = 0; nf < 4; ++nf){
      int n = nb + nf * 16 + li;
      if (n < NN){
        float vv[4] = {acc[mf][nf][0] + b0, acc[mf][nf][1] + b1, acc[mf][nf][2] + b2, acc[mf][nf][3] + b3};
        #pragma unroll
        for (int r = 0; r < 4; ++r){
          u32 u = __float_as_uint(vv[r]);
          u = (u & 0x80000000u) ? ~u : (u | 0x80000000u);
          atomicMax(&pooled[(size_t)bs[nf] * HH + fb + r], u);
        }
      }
    }
  }
}

// ---------------- resblock + head ----------------
__global__ __launch_bounds__(256) void final_kernel(
    const float* __restrict__ z, const float* __restrict__ rw1, const float* __restrict__ rb1,
    const float* __restrict__ rw2, const float* __restrict__ rb2,
    const float* __restrict__ hw, const float* __restrict__ hbs, float* __restrict__ out){
  __shared__ float zr[272], t1[256], t2[272];
  const int b = blockIdx.x, tid = threadIdx.x;
  for (int i = tid; i < 272; i += 256) zr[i] = z[(size_t)b * 272 + i];
  __syncthreads();
  {
    float a = rb1[tid];
    for (int k = 0; k < 272; ++k) a += zr[k] * rw1[(size_t)k * 256 + tid];
    t1[tid] = siluf(a);
  }
  __syncthreads();
  for (int i = tid; i < 272; i += 256){
    float a = rb2[i] + zr[i];
    for (int k = 0; k < 256; ++k) a += t1[k] * rw2[(size_t)k * 272 + i];
    t2[i] = a;
  }
  __syncthreads();
  for (int p = tid; p < 2000; p += 256){
    float a = hbs[p];
    for (int k = 0; k < 272; ++k) a += t2[k] * hw[(size_t)k * 2000 + p];
    out[(size_t)b * 2000 + p] = a;
  }
}

extern "C" void kernel_launch(void* const* d_in, const int* in_sizes, int n_in,
                              void* d_out, int out_size, void* d_ws, size_t ws_size,
                              hipStream_t stream){
  const float* x        = (const float*)d_in[0];
  const float* pos      = (const float*)d_in[1];
  const float* eattr    = (const float*)d_in[2];
  const float* fragl    = (const float*)d_in[3];
  const float* addf     = (const float*)d_in[4];
  const int*   ei       = (const int*)d_in[5];
  const int*   batch    = (const int*)d_in[6];
  const float* emb_in_w = (const float*)d_in[7];
  const float* emb_in_b = (const float*)d_in[8];
  const float* edge_w1  = (const float*)d_in[9];
  const float* edge_b1  = (const float*)d_in[10];
  const float* edge_w2  = (const float*)d_in[11];
  const float* edge_b2  = (const float*)d_in[12];
  const float* node_w1  = (const float*)d_in[13];
  const float* node_b1  = (const float*)d_in[14];
  const float* node_w2  = (const float*)d_in[15];
  const float* node_b2  = (const float*)d_in[16];
  const float* coord_w1 = (const float*)d_in[17];
  const float* coord_b1 = (const float*)d_in[18];
  const float* coord_w2 = (const float*)d_in[19];
  const float* emb_out_w= (const float*)d_in[20];
  const float* emb_out_b= (const float*)d_in[21];
  const float* res_w1   = (const float*)d_in[22];
  const float* res_b1   = (const float*)d_in[23];
  const float* res_w2   = (const float*)d_in[24];
  const float* res_b2   = (const float*)d_in[25];
  const float* head_w   = (const float*)d_in[26];
  const float* head_b   = (const float*)d_in[27];

  char* ws = (char*)d_ws;
  size_t off = 0;
  auto alloc = [&](size_t bytes) -> void* {
    void* p = ws + off;
    off += (bytes + 255) & ~(size_t)255;
    return p;
  };
  float*  h      = (float*)alloc((size_t)NN * HH * 4);
  float*  agg    = (float*)alloc((size_t)NN * HH * 4);
  u16*    agg_bf = (u16*)  alloc((size_t)NN * HH * 2);
  u16*    hb     = (u16*)  alloc((size_t)NN * HH * 2);
  float4* coordb = (float4*)alloc((size_t)NN * 16);
  float*  cacc   = (float*)alloc((size_t)NN * 16);
  u32*    pooled = (u32*)  alloc((size_t)BB * HH * 4);
  float*  z      = (float*)alloc((size_t)BB * 272 * 4);
  u16*    packed = (u16*)  alloc((size_t)7680 * 256 * 2);
  int*    icnt   = (int*)  alloc((size_t)NN * 4);
  int*    iscan  = (int*)  alloc((size_t)NN * 4);
  int*    rstart = (int*)  alloc((size_t)NN * 4);
  int*    cursor = (int*)  alloc((size_t)NN * 4);
  int*    bsum   = (int*)  alloc((size_t)128 * 4);
  int*    seid   = (int*)  alloc((size_t)EE * 4);
  int*    srow   = (int*)  alloc((size_t)EE * 4);
  int*    scol   = (int*)  alloc((size_t)EE * 4);
  const size_t base_off = off;
  u64*    m2g    = (u64*)  alloc((size_t)EE * HH * 2);   // 164 MB m2 stream buffer
  const bool use_stream = (off <= ws_size);
  if (base_off > ws_size) return;   // even base allocs don't fit -> fail loudly

  u16* pk_embin  = packed;
  u16* pk_embout = packed + 32768 + (size_t)4 * 466944;
  auto pk_ew1 = [&](int l){ return packed + 32768 + (size_t)l * 466944; };
  auto pk_ew2 = [&](int l){ return pk_ew1(l) + 139264; };
  auto pk_cw1 = [&](int l){ return pk_ew1(l) + 204800; };
  auto pk_nw1 = [&](int l){ return pk_ew1(l) + 270336; };
  auto pk_nw2 = [&](int l){ return pk_ew1(l) + 401408; };

  pack_kernel<<<16, 256, 0, stream>>>(emb_in_w, pk_embin, 128, 4);
  for (int l = 0; l < 4; ++l){
    pack_kernel<<<68, 256, 0, stream>>>(edge_w1 + (size_t)l * 529 * 256, pk_ew1(l), 529, 17);
    pack_kernel<<<32, 256, 0, stream>>>(edge_w2 + (size_t)l * 65536,     pk_ew2(l), 256, 8);
    pack_kernel<<<32, 256, 0, stream>>>(coord_w1 + (size_t)l * 65536,    pk_cw1(l), 256, 8);
    pack_kernel<<<64, 256, 0, stream>>>(node_w1 + (size_t)l * 131072,    pk_nw1(l), 512, 16);
    pack_kernel<<<32, 256, 0, stream>>>(node_w2 + (size_t)l * 65536,     pk_nw2(l), 256, 8);
  }
  pack_kernel<<<32, 256, 0, stream>>>(emb_out_w, pk_embout, 256, 8);

  // ---- one-time edge sort by row
  const int NB = (NN + 255) / 256;   // 79
  hipMemsetAsync(icnt,   0, (size_t)NN * 4, stream);
  hipMemsetAsync(cursor, 0, (size_t)NN * 4, stream);
  icnt_kernel<<<(EE + 255) / 256, 256, 0, stream>>>(ei, icnt);
  iscan_block<<<NB, 256, 0, stream>>>(icnt, iscan, bsum);
  iscan_top<<<1, 64, 0, stream>>>(bsum, NB);
  iscan_fix<<<NB, 256, 0, stream>>>(icnt, iscan, bsum, rstart);
  scatter_kernel<<<(EE + 255) / 256, 256, 0, stream>>>(ei, rstart, cursor, seid, srow, scol);

  coord_init_kernel<<<79, 256, 0, stream>>>(pos, coordb);
  emb_in_kernel<<<313, 256, 0, stream>>>(x, pk_embin, emb_in_b, h, hb);

  for (int l = 0; l < 4; ++l){
    hipMemsetAsync(cacc, 0, (size_t)NN * 16, stream);
    if (use_stream){
      edge_kernel<true><<<5000, 256, 0, stream>>>(hb, coordb, srow, scol, seid, eattr,
          pk_ew1(l), pk_ew2(l), pk_cw1(l),
          edge_b1 + l * 256, edge_b2 + l * 256, coord_b1 + l * 256, coord_w2 + l * 256,
          agg, cacc, m2g);
      agg_csr_kernel<<<NN, 256, 0, stream>>>((const u16*)m2g, rstart, icnt, agg_bf);
    } else {
      hipMemsetAsync(agg, 0, (size_t)NN * HH * 4, stream);
      edge_kernel<false><<<5000, 256, 0, stream>>>(hb, coordb, srow, scol, seid, eattr,
          pk_ew1(l), pk_ew2(l), pk_cw1(l),
          edge_b1 + l * 256, edge_b2 + l * 256, coord_b1 + l * 256, coord_w2 + l * 256,
          agg, cacc, m2g);
      agg_conv_kernel<<<(NN * HH + 255) / 256, 256, 0, stream>>>(agg, agg_bf);
    }
    coord_upd_kernel<<<79, 256, 0, stream>>>(coordb, cacc, icnt);
    node_kernel<<<313, 256, 0, stream>>>(h, hb, agg_bf, pk_nw1(l), pk_nw2(l),
        node_b1 + l * 256, node_b2 + l * 256);
  }

  pool_init_kernel<<<128, 256, 0, stream>>>(pooled);
  emb_out_pool_kernel<<<313, 256, 0, stream>>>(hb, pk_embout, emb_out_b, batch, pooled);
  build_z_kernel<<<136, 256, 0, stream>>>(pooled, fragl, addf, z);
  final_kernel<<<128, 256, 0, stream>>>(z, res_w1, res_b1, res_w2, res_b2, head_w, head_b,
                                        (float*)d_out);
}

// Round 5
// 2264.330 us; speedup vs baseline: 2.4812x; 1.0618x over previous
//
#include <hip/hip_runtime.h>

typedef unsigned short u16;
typedef unsigned int   u32;
typedef unsigned long long u64;
typedef __attribute__((ext_vector_type(8))) short s8v;   // 8 bf16 (4 VGPRs) MFMA operand
typedef __attribute__((ext_vector_type(4))) float f4v;   // MFMA accumulator

#define NN 20000
#define EE 320000
#define BB 128
#define HH 256

union BU { u64 d[2]; s8v v; };

__device__ __forceinline__ u16 f2bf(float f){
  u32 u = __float_as_uint(f);
  return (u16)((u + 0x7FFFu + ((u >> 16) & 1u)) >> 16);   // RNE
}
__device__ __forceinline__ float bf2f(u16 u){ return __uint_as_float((u32)u << 16); }
__device__ __forceinline__ u32 cvt2(float a, float b){
  u32 r; asm("v_cvt_pk_bf16_f32 %0, %1, %2" : "=v"(r) : "v"(a), "v"(b)); return r;
}
__device__ __forceinline__ u64 pack4bf(float a, float b, float c, float d){
  return (u64)cvt2(a, b) | ((u64)cvt2(c, d) << 32);
}
__device__ __forceinline__ float siluf(float v){ return v / (1.0f + __expf(-v)); }

// ---------------- weight packing: W [K][256] f32 -> A-fragment blob (W^T), bf16 ----------------
__global__ void pack_kernel(const float* __restrict__ src, u16* __restrict__ dst, int K, int KB){
  int t = blockIdx.x * 256 + threadIdx.x;
  if (t >= KB * 1024) return;
  int lane = t & 63, mf = (t >> 6) & 15, kb = t >> 10;
  int g = lane >> 4, li = lane & 15;
  int m = mf * 16 + li;
  u16 o[8];
  #pragma unroll
  for (int j = 0; j < 8; ++j){
    int k = kb * 32 + ((j < 4) ? (g * 4 + j) : (16 + g * 4 + (j - 4)));
    o[j] = (k < K) ? f2bf(src[(size_t)k * 256 + m]) : (u16)0;
  }
  u16* d = dst + ((size_t)(kb * 16 + mf) * 64 + lane) * 8;
  *(u64*)(d)     = (u64)o[0] | ((u64)o[1] << 16) | ((u64)o[2] << 32) | ((u64)o[3] << 48);
  *(u64*)(d + 4) = (u64)o[4] | ((u64)o[5] << 16) | ((u64)o[6] << 32) | ((u64)o[7] << 48);
}

// ---------------- edge sort by destination row (one-time per launch) ----------------
__global__ void icnt_kernel(const int* __restrict__ ei, int* __restrict__ icnt){
  int t = blockIdx.x * 256 + threadIdx.x;
  if (t < EE) atomicAdd(&icnt[ei[t]], 1);
}
__global__ void iscan_block(const int* __restrict__ icnt, int* __restrict__ iscan, int* __restrict__ bsum){
  __shared__ int s[256];
  int i = blockIdx.x * 256 + threadIdx.x;
  int v = (i < NN) ? icnt[i] : 0;
  s[threadIdx.x] = v; __syncthreads();
  #pragma unroll
  for (int d = 1; d < 256; d <<= 1){
    int t = (threadIdx.x >= d) ? s[threadIdx.x - d] : 0;
    __syncthreads();
    s[threadIdx.x] += t;
    __syncthreads();
  }
  if (i < NN) iscan[i] = s[threadIdx.x];
  if (threadIdx.x == 255) bsum[blockIdx.x] = s[255];
}
__global__ void iscan_top(int* __restrict__ bsum, int nb){
  if (blockIdx.x == 0 && threadIdx.x == 0){
    int acc = 0;
    for (int i = 0; i < nb; ++i){ int t = bsum[i]; bsum[i] = acc; acc += t; }
  }
}
__global__ void iscan_fix(const int* __restrict__ icnt, const int* __restrict__ iscan,
                          const int* __restrict__ bsum, int* __restrict__ rstart){
  int i = blockIdx.x * 256 + threadIdx.x;
  if (i < NN) rstart[i] = bsum[blockIdx.x] + iscan[i] - icnt[i];
}
__global__ void scatter_kernel(const int* __restrict__ ei, const int* __restrict__ rstart,
                               int* __restrict__ cursor, int* __restrict__ seid,
                               int* __restrict__ srow, int* __restrict__ scol){
  int e = blockIdx.x * 256 + threadIdx.x;
  if (e < EE){
    int r = ei[e];
    int p = rstart[r] + atomicAdd(&cursor[r], 1);
    seid[p] = e; srow[p] = r; scol[p] = ei[EE + e];
  }
}

// ---------------- small utility kernels ----------------
__global__ void coord_init_kernel(const float* __restrict__ pos, float4* __restrict__ coord){
  int t = blockIdx.x * 256 + threadIdx.x;
  if (t < NN) coord[t] = make_float4(pos[3*t], pos[3*t+1], pos[3*t+2], 0.f);
}
__global__ void coord_upd_kernel(float4* __restrict__ coord, const float* __restrict__ cacc,
                                 const int* __restrict__ icnt){
  int t = blockIdx.x * 256 + threadIdx.x;
  if (t >= NN) return;
  float k = fmaxf((float)icnt[t], 1.0f);
  float4 c = coord[t];
  c.x += cacc[4*t+0] / k; c.y += cacc[4*t+1] / k; c.z += cacc[4*t+2] / k;
  coord[t] = c;
}
__global__ void pool_init_kernel(u32* __restrict__ pooled){
  int t = blockIdx.x * 256 + threadIdx.x;
  if (t < BB * HH){
    u32 u = __float_as_uint(-3.0e38f);
    pooled[t] = ~u;
  }
}
__global__ void build_z_kernel(const u32* __restrict__ pooled, const float* __restrict__ fragl,
                               const float* __restrict__ addf, float* __restrict__ z){
  int t = blockIdx.x * 256 + threadIdx.x;
  if (t >= BB * 272) return;
  int b = t / 272, j = t % 272;
  float v;
  if (j < 256){
    u32 u = pooled[b * 256 + j];
    v = (u & 0x80000000u) ? __uint_as_float(u & 0x7FFFFFFFu) : __uint_as_float(~u);
  } else if (j < 264) v = fragl[b * 8 + (j - 256)];
  else                v = addf[b * 8 + (j - 264)];
  z[t] = v;
}

// ---------------- CSR segment-sum: agg_bf[n][f] = bf16( sum_e m2[e][f] ) ----------------
__global__ __launch_bounds__(256) void agg_csr_kernel(
    const u16* __restrict__ m2b, const int* __restrict__ rstart,
    const int* __restrict__ icnt, u16* __restrict__ agg_bf){
  const int n = blockIdx.x, f = threadIdx.x;
  const int s = rstart[n], d = icnt[n];
  const u16* p = m2b + (size_t)s * 256 + f;
  float a0 = 0.f, a1 = 0.f;
  int i = 0;
  for (; i + 1 < d; i += 2){ a0 += bf2f(p[(size_t)i * 256]); a1 += bf2f(p[(size_t)(i + 1) * 256]); }
  if (i < d) a0 += bf2f(p[(size_t)i * 256]);
  agg_bf[(size_t)n * 256 + f] = f2bf(a0 + a1);
}
__global__ void agg_conv_kernel(const float* __restrict__ agg, u16* __restrict__ agg_bf){
  int t = blockIdx.x * 256 + threadIdx.x;
  if (t < NN * HH) agg_bf[t] = f2bf(agg[t]);
}

// ---------------- emb_in: h = x @ emb_in_w + b ----------------
__global__ __launch_bounds__(256) void emb_in_kernel(
    const float* __restrict__ x, const u16* __restrict__ pw,
    const float* __restrict__ bias, float* __restrict__ h, u16* __restrict__ hb){
  const int tid = threadIdx.x;
  const int w = tid >> 6, l = tid & 63, g = l >> 4, li = l & 15;
  const int nb = blockIdx.x * 64;
  const float* xp[4];
  #pragma unroll
  for (int nf = 0; nf < 4; ++nf){
    int n = nb + nf * 16 + li; if (n >= NN) n = NN - 1;
    xp[nf] = x + (size_t)n * 128 + g * 4;
  }
  f4v acc[4][4];
  #pragma unroll
  for (int a = 0; a < 4; ++a)
    #pragma unroll
    for (int b = 0; b < 4; ++b) acc[a][b] = (f4v){0.f,0.f,0.f,0.f};
  const u16* pwb = pw + ((size_t)(w * 4) * 64 + l) * 8;
  #pragma unroll
  for (int kb = 0; kb < 4; ++kb){
    s8v A[4];
    #pragma unroll
    for (int mf = 0; mf < 4; ++mf) A[mf] = *(const s8v*)(pwb + (size_t)kb * 8192 + mf * 512);
    #pragma unroll
    for (int nf = 0; nf < 4; ++nf){
      float4 fa = *(const float4*)(xp[nf] + kb * 32);
      float4 fb = *(const float4*)(xp[nf] + kb * 32 + 16);
      BU bu;
      bu.d[0] = pack4bf(fa.x, fa.y, fa.z, fa.w);
      bu.d[1] = pack4bf(fb.x, fb.y, fb.z, fb.w);
      #pragma unroll
      for (int mf = 0; mf < 4; ++mf)
        acc[mf][nf] = __builtin_amdgcn_mfma_f32_16x16x32_bf16(A[mf], bu.v, acc[mf][nf], 0, 0, 0);
    }
  }
  #pragma unroll
  for (int mf = 0; mf < 4; ++mf){
    const int fb = w * 64 + mf * 16 + g * 4;
    float b0 = bias[fb], b1 = bias[fb+1], b2 = bias[fb+2], b3 = bias[fb+3];
    #pragma unroll
    for (int nf = 0; nf < 4; ++nf){
      int n = nb + nf * 16 + li;
      if (n < NN){
        float o0 = acc[mf][nf][0] + b0, o1 = acc[mf][nf][1] + b1;
        float o2 = acc[mf][nf][2] + b2, o3 = acc[mf][nf][3] + b3;
        *(float4*)(h + (size_t)n * HH + fb) = make_float4(o0, o1, o2, o3);
        *(u64*)(hb + (size_t)n * HH + fb) = pack4bf(o0, o1, o2, o3);
      }
    }
  }
}

// ---------------- P_a = h@W1a + b1 ; P_b = h@W1b  (node-level GEMM, f32 out) ----------------
__global__ __launch_bounds__(256) void pab_kernel(
    const u16* __restrict__ hb, const u16* __restrict__ pw1, const float* __restrict__ b1,
    float* __restrict__ Pa, float* __restrict__ Pb){
  const int tid = threadIdx.x;
  const int w = tid >> 6, l = tid & 63, g = l >> 4, li = l & 15;
  const int nb = blockIdx.x * 64;
  const u16* hp[4];
  #pragma unroll
  for (int nf = 0; nf < 4; ++nf){
    int n = nb + nf * 16 + li; if (n >= NN) n = NN - 1;
    hp[nf] = hb + (size_t)n * HH + g * 4;
  }
  const u16* pwb = pw1 + ((size_t)(w * 4) * 64 + l) * 8;
  #pragma unroll
  for (int pass = 0; pass < 2; ++pass){
    f4v acc[4][4];
    #pragma unroll
    for (int a = 0; a < 4; ++a)
      #pragma unroll
      for (int b = 0; b < 4; ++b) acc[a][b] = (f4v){0.f,0.f,0.f,0.f};
    const u16* pwp = pwb + (size_t)(pass * 8) * 8192;   // W1a = kb 0..7, W1b = kb 8..15
    #pragma unroll 4
    for (int kb = 0; kb < 8; ++kb){
      s8v A[4];
      #pragma unroll
      for (int mf = 0; mf < 4; ++mf) A[mf] = *(const s8v*)(pwp + (size_t)kb * 8192 + mf * 512);
      #pragma unroll
      for (int nf = 0; nf < 4; ++nf){
        BU bu;
        bu.d[0] = *(const u64*)(hp[nf] + kb * 32);
        bu.d[1] = *(const u64*)(hp[nf] + kb * 32 + 16);
        #pragma unroll
        for (int mf = 0; mf < 4; ++mf)
          acc[mf][nf] = __builtin_amdgcn_mfma_f32_16x16x32_bf16(A[mf], bu.v, acc[mf][nf], 0, 0, 0);
      }
    }
    float* dst = pass ? Pb : Pa;
    #pragma unroll
    for (int mf = 0; mf < 4; ++mf){
      const int fb = w * 64 + mf * 16 + g * 4;
      float c0 = 0.f, c1 = 0.f, c2 = 0.f, c3 = 0.f;
      if (!pass){ c0 = b1[fb]; c1 = b1[fb+1]; c2 = b1[fb+2]; c3 = b1[fb+3]; }
      #pragma unroll
      for (int nf = 0; nf < 4; ++nf){
        int n = nb + nf * 16 + li;
        if (n < NN)
          *(float4*)(dst + (size_t)n * HH + fb) =
            make_float4(acc[mf][nf][0] + c0, acc[mf][nf][1] + c1,
                        acc[mf][nf][2] + c2, acc[mf][nf][3] + c3);
      }
    }
  }
}

// ---------------- edge kernel: 64 SORTED edges/block ----------------
// GEMM1 factored: m1 = silu(Pa[row] + Pb[col] + tail@W1c). Register-lean: no
// explicit load pipeline (compiler schedules), m2 held as packed bf16 (32 regs).
template<bool STREAM>
__global__ __launch_bounds__(256) void edge_kernel(
    const float* __restrict__ Pa, const float* __restrict__ Pb,
    const float4* __restrict__ coord,
    const int* __restrict__ srow, const int* __restrict__ scol, const int* __restrict__ seid,
    const float* __restrict__ eattr,
    const u16* __restrict__ pw1, const u16* __restrict__ pw2, const u16* __restrict__ pw3,
    const float* __restrict__ b2, const float* __restrict__ cb1, const float* __restrict__ cw2,
    float* __restrict__ agg, float* __restrict__ cacc, u64* __restrict__ m2g){
  __shared__ u64 mt[4096];            // 32KB swizzled tile [64 edges][64 4-feat chunks]
  __shared__ float4 dif[64];
  __shared__ int rows_s[64];
  __shared__ int cols_s[64];
  __shared__ int seid_s[64];
  __shared__ float bias_s[768];       // b2 | cb1 | cw2
  __shared__ float cpart[4][64];

  const int tid = threadIdx.x;
  const int w = tid >> 6, l = tid & 63, g = l >> 4, li = l & 15;
  const int eb = blockIdx.x * 64;

  if (tid < 64){
    int sp = eb + tid;
    int r = srow[sp], c = scol[sp];
    rows_s[tid] = r; cols_s[tid] = c; seid_s[tid] = seid[sp];
    float4 ca = coord[r], cb = coord[c];
    float dx = ca.x - cb.x, dy = ca.y - cb.y, dz = ca.z - cb.z;
    float rad = dx*dx + dy*dy + dz*dz;
    dif[tid] = make_float4(dx, dy, dz, rad);
  }
  for (int i = tid; i < 768; i += 256){
    float v;
    if      (i < 256) v = b2[i];
    else if (i < 512) v = cb1[i - 256];
    else              v = cw2[i - 512];
    bias_s[i] = v;
  }
  __syncthreads();

  const float* paP[4]; const float* pbP[4];
  #pragma unroll
  for (int nf = 0; nf < 4; ++nf){
    int e = nf * 16 + li;
    paP[nf] = Pa + (size_t)rows_s[e] * HH;
    pbP[nf] = Pb + (size_t)cols_s[e] * HH;
  }

  const u16* pw1b = pw1 + ((size_t)(w * 4) * 64 + l) * 8;
  const u16* pw2b = pw2 + ((size_t)(w * 4) * 64 + l) * 8;
  const u16* pw3b = pw3 + ((size_t)(w * 4) * 64 + l) * 8;

  // ---- tail k-block operands (k 512..543: radial | edge_attr | 0-pad)
  float tf[4][4];
  float rads[4];
  #pragma unroll
  for (int nf = 0; nf < 4; ++nf){
    int e = nf * 16 + li;
    const float* ep = eattr + (size_t)seid_s[e] * 16;
    if (g == 0){ tf[nf][0] = ep[0]; tf[nf][1] = ep[1]; tf[nf][2] = ep[2]; tf[nf][3] = ep[15]; }
    else { int i0 = g * 4 - 1; tf[nf][0] = ep[i0]; tf[nf][1] = ep[i0+1]; tf[nf][2] = ep[i0+2]; tf[nf][3] = ep[i0+3]; }
    rads[nf] = dif[e].w;
  }

  f4v acc[4][4];
  #pragma unroll
  for (int a = 0; a < 4; ++a)
    #pragma unroll
    for (int b = 0; b < 4; ++b) acc[a][b] = (f4v){0.f,0.f,0.f,0.f};

  // ---- tail MFMA (only remaining piece of GEMM1)
  {
    s8v at[4];
    #pragma unroll
    for (int mf = 0; mf < 4; ++mf) at[mf] = *(const s8v*)(pw1b + (size_t)16 * 8192 + mf * 512);
    #pragma unroll
    for (int nf = 0; nf < 4; ++nf){
      BU bu;
      if (g == 0){ bu.d[0] = pack4bf(rads[nf], tf[nf][0], tf[nf][1], tf[nf][2]); bu.d[1] = (u64)(cvt2(tf[nf][3], 0.f) & 0xffffu); }
      else       { bu.d[0] = pack4bf(tf[nf][0], tf[nf][1], tf[nf][2], tf[nf][3]); bu.d[1] = 0; }
      #pragma unroll
      for (int mf = 0; mf < 4; ++mf)
        acc[mf][nf] = __builtin_amdgcn_mfma_f32_16x16x32_bf16(at[mf], bu.v, acc[mf][nf], 0, 0, 0);
    }
  }

  // ---- m1 = silu(acc + Pa[row] + Pb[col])  (b1 folded into Pa)
  #pragma unroll
  for (int mf = 0; mf < 4; ++mf){
    const int fb = w * 64 + mf * 16 + g * 4;
    const int fc = fb >> 2;
    #pragma unroll
    for (int nf = 0; nf < 4; ++nf){
      int e = nf * 16 + li;
      float4 pa = *(const float4*)(paP[nf] + fb);
      float4 pb = *(const float4*)(pbP[nf] + fb);
      float v0 = siluf(acc[mf][nf][0] + pa.x + pb.x);
      float v1 = siluf(acc[mf][nf][1] + pa.y + pb.y);
      float v2 = siluf(acc[mf][nf][2] + pa.z + pb.z);
      float v3 = siluf(acc[mf][nf][3] + pa.w + pb.w);
      mt[e * 64 + (fc ^ (e & 7))] = pack4bf(v0, v1, v2, v3);
    }
  }
  __syncthreads();

  // ---- GEMM2: m2 = silu(m1 @ W2 + b2)
  #pragma unroll
  for (int a = 0; a < 4; ++a)
    #pragma unroll
    for (int b = 0; b < 4; ++b) acc[a][b] = (f4v){0.f,0.f,0.f,0.f};
  #pragma unroll 4
  for (int s = 0; s < 8; ++s){
    s8v A[4];
    #pragma unroll
    for (int mf = 0; mf < 4; ++mf) A[mf] = *(const s8v*)(pw2b + (size_t)s * 8192 + mf * 512);
    #pragma unroll
    for (int nf = 0; nf < 4; ++nf){
      int e = nf * 16 + li;
      BU bu;
      bu.d[0] = mt[e * 64 + ((s * 8 + g)     ^ (e & 7))];
      bu.d[1] = mt[e * 64 + ((s * 8 + 4 + g) ^ (e & 7))];
      #pragma unroll
      for (int mf = 0; mf < 4; ++mf)
        acc[mf][nf] = __builtin_amdgcn_mfma_f32_16x16x32_bf16(A[mf], bu.v, acc[mf][nf], 0, 0, 0);
    }
  }
  u64 pm2[4][4];                      // m2 as packed bf16 (exactly what LDS/stream need)
  #pragma unroll
  for (int mf = 0; mf < 4; ++mf){
    const int fb = w * 64 + mf * 16 + g * 4;
    #pragma unroll
    for (int nf = 0; nf < 4; ++nf)
      pm2[mf][nf] = pack4bf(siluf(acc[mf][nf][0] + bias_s[fb+0]),
                            siluf(acc[mf][nf][1] + bias_s[fb+1]),
                            siluf(acc[mf][nf][2] + bias_s[fb+2]),
                            siluf(acc[mf][nf][3] + bias_s[fb+3]));
  }
  __syncthreads();                    // all waves done reading m1
  #pragma unroll
  for (int mf = 0; mf < 4; ++mf){
    const int fc = (w * 64 + mf * 16 + g * 4) >> 2;
    #pragma unroll
    for (int nf = 0; nf < 4; ++nf){
      int e = nf * 16 + li;
      mt[e * 64 + (fc ^ (e & 7))] = pm2[mf][nf];
    }
  }
  __syncthreads();

  // ---- STREAM: coalesced write-out of m2 tile
  if (STREAM){
    u64* dst = m2g + (size_t)eb * 64;
    #pragma unroll
    for (int j = 0; j < 16; ++j){
      int q = j * 256 + tid;
      int e = q >> 6, fc = q & 63;
      dst[(size_t)e * 64 + fc] = mt[e * 64 + (fc ^ (e & 7))];
    }
  }

  // ---- GEMM3: q = silu(m2 @ CW1 + cb1); c = q . cw2
  #pragma unroll
  for (int a = 0; a < 4; ++a)
    #pragma unroll
    for (int b = 0; b < 4; ++b) acc[a][b] = (f4v){0.f,0.f,0.f,0.f};
  #pragma unroll 4
  for (int s = 0; s < 8; ++s){
    s8v A[4];
    #pragma unroll
    for (int mf = 0; mf < 4; ++mf) A[mf] = *(const s8v*)(pw3b + (size_t)s * 8192 + mf * 512);
    #pragma unroll
    for (int nf = 0; nf < 4; ++nf){
      int e = nf * 16 + li;
      BU bu;
      bu.d[0] = mt[e * 64 + ((s * 8 + g)     ^ (e & 7))];
      bu.d[1] = mt[e * 64 + ((s * 8 + 4 + g) ^ (e & 7))];
      #pragma unroll
      for (int mf = 0; mf < 4; ++mf)
        acc[mf][nf] = __builtin_amdgcn_mfma_f32_16x16x32_bf16(A[mf], bu.v, acc[mf][nf], 0, 0, 0);
    }
  }
  float cp4[4] = {0.f, 0.f, 0.f, 0.f};
  #pragma unroll
  for (int mf = 0; mf < 4; ++mf){
    const int fb = w * 64 + mf * 16 + g * 4;
    #pragma unroll
    for (int nf = 0; nf < 4; ++nf){
      #pragma unroll
      for (int r = 0; r < 4; ++r){
        float q = siluf(acc[mf][nf][r] + bias_s[256 + fb + r]);
        cp4[nf] += q * bias_s[512 + fb + r];
      }
    }
  }
  #pragma unroll
  for (int nf = 0; nf < 4; ++nf){
    float v = cp4[nf];
    v += __shfl_xor(v, 16, 64);
    v += __shfl_xor(v, 32, 64);
    if (g == 0) cpart[w][nf * 16 + li] = v;
  }
  __syncthreads();

  // ---- cacc: segmented suffix-reduce across the 64 sorted edges, head lanes atomic
  if (tid < 64){
    float c = cpart[0][tid] + cpart[1][tid] + cpart[2][tid] + cpart[3][tid];
    float4 d = dif[tid];
    const int myrow = rows_s[tid];
    float vx = d.x * c, vy = d.y * c, vz = d.z * c;
    #pragma unroll
    for (int dd = 1; dd < 64; dd <<= 1){
      const int rr = __shfl_down(myrow, dd, 64);
      const bool ok = ((tid + dd) < 64) && (rr == myrow);
      float tx = __shfl_down(vx, dd, 64);
      float ty = __shfl_down(vy, dd, 64);
      float tz = __shfl_down(vz, dd, 64);
      if (ok){ vx += tx; vy += ty; vz += tz; }
    }
    if (tid == 0 || rows_s[tid - 1] != myrow){
      atomicAdd(cacc + (size_t)myrow * 4 + 0, vx);
      atomicAdd(cacc + (size_t)myrow * 4 + 1, vy);
      atomicAdd(cacc + (size_t)myrow * 4 + 2, vz);
    }
  }

  // ---- fallback path only: agg via segmented suffix-reduce + atomics
  if (!STREAM){
    #pragma unroll
    for (int nf = 0; nf < 4; ++nf){
      const int myrow = rows_s[nf * 16 + li];
      const bool head = (li == 0) || (rows_s[nf * 16 + li - 1] != myrow);
      float v[16];
      #pragma unroll
      for (int mf = 0; mf < 4; ++mf)
        #pragma unroll
        for (int r = 0; r < 4; ++r) v[mf * 4 + r] = bf2f((u16)(pm2[mf][nf] >> (16 * r)));
      #pragma unroll
      for (int d = 1; d < 16; d <<= 1){
        const int rr = __shfl_down(myrow, d, 16);
        const bool ok = ((li + d) < 16) && (rr == myrow);
        #pragma unroll
        for (int j = 0; j < 16; ++j){
          const float vv = __shfl_down(v[j], d, 16);
          if (ok) v[j] += vv;
        }
      }
      if (head){
        #pragma unroll
        for (int mf = 0; mf < 4; ++mf){
          float* ag = agg + (size_t)myrow * HH + w * 64 + mf * 16 + g * 4;
          atomicAdd(ag + 0, v[mf * 4 + 0]);
          atomicAdd(ag + 1, v[mf * 4 + 1]);
          atomicAdd(ag + 2, v[mf * 4 + 2]);
          atomicAdd(ag + 3, v[mf * 4 + 3]);
        }
      }
    }
  }
}

// ---------------- node kernel: h += MLP([h, agg]) ; agg read as bf16 ----------------
__global__ __launch_bounds__(256) void node_kernel(
    float* __restrict__ h, u16* __restrict__ hb, const u16* __restrict__ agg_bf,
    const u16* __restrict__ pw1, const u16* __restrict__ pw2,
    const float* __restrict__ b1, const float* __restrict__ b2){
  __shared__ u64 mt[4096];
  __shared__ float bias_s[512];
  const int tid = threadIdx.x;
  const int w = tid >> 6, l = tid & 63, g = l >> 4, li = l & 15;
  const int nb = blockIdx.x * 64;
  for (int i = tid; i < 512; i += 256) bias_s[i] = (i < 256) ? b1[i] : b2[i - 256];
  __syncthreads();

  const u16* hp[4]; const u16* ap[4];
  #pragma unroll
  for (int nf = 0; nf < 4; ++nf){
    int n = nb + nf * 16 + li; if (n >= NN) n = NN - 1;
    hp[nf] = hb     + (size_t)n * HH + g * 4;
    ap[nf] = agg_bf + (size_t)n * HH + g * 4;
  }
  f4v acc[4][4];
  #pragma unroll
  for (int a = 0; a < 4; ++a)
    #pragma unroll
    for (int b = 0; b < 4; ++b) acc[a][b] = (f4v){0.f,0.f,0.f,0.f};

  const u16* pw1b = pw1 + ((size_t)(w * 4) * 64 + l) * 8;
  #pragma unroll 4
  for (int kb = 0; kb < 8; ++kb){
    s8v A[4];
    #pragma unroll
    for (int mf = 0; mf < 4; ++mf) A[mf] = *(const s8v*)(pw1b + (size_t)kb * 8192 + mf * 512);
    #pragma unroll
    for (int nf = 0; nf < 4; ++nf){
      BU bu;
      bu.d[0] = *(const u64*)(hp[nf] + kb * 32);
      bu.d[1] = *(const u64*)(hp[nf] + kb * 32 + 16);
      #pragma unroll
      for (int mf = 0; mf < 4; ++mf)
        acc[mf][nf] = __builtin_amdgcn_mfma_f32_16x16x32_bf16(A[mf], bu.v, acc[mf][nf], 0, 0, 0);
    }
  }
  #pragma unroll 4
  for (int kb = 8; kb < 16; ++kb){
    s8v A[4];
    #pragma unroll
    for (int mf = 0; mf < 4; ++mf) A[mf] = *(const s8v*)(pw1b + (size_t)kb * 8192 + mf * 512);
    #pragma unroll
    for (int nf = 0; nf < 4; ++nf){
      BU bu;
      bu.d[0] = *(const u64*)(ap[nf] + (kb - 8) * 32);
      bu.d[1] = *(const u64*)(ap[nf] + (kb - 8) * 32 + 16);
      #pragma unroll
      for (int mf = 0; mf < 4; ++mf)
        acc[mf][nf] = __builtin_amdgcn_mfma_f32_16x16x32_bf16(A[mf], bu.v, acc[mf][nf], 0, 0, 0);
    }
  }
  #pragma unroll
  for (int mf = 0; mf < 4; ++mf){
    const int fb = w * 64 + mf * 16 + g * 4;
    const int fc = fb >> 2;
    #pragma unroll
    for (int nf = 0; nf < 4; ++nf){
      int e = nf * 16 + li;
      float v0 = siluf(acc[mf][nf][0] + bias_s[fb+0]);
      float v1 = siluf(acc[mf][nf][1] + bias_s[fb+1]);
      float v2 = siluf(acc[mf][nf][2] + bias_s[fb+2]);
      float v3 = siluf(acc[mf][nf][3] + bias_s[fb+3]);
      mt[e * 64 + (fc ^ (e & 7))] = pack4bf(v0, v1, v2, v3);
    }
  }
  __syncthreads();

  #pragma unroll
  for (int a = 0; a < 4; ++a)
    #pragma unroll
    for (int b = 0; b < 4; ++b) acc[a][b] = (f4v){0.f,0.f,0.f,0.f};
  const u16* pw2b = pw2 + ((size_t)(w * 4) * 64 + l) * 8;
  #pragma unroll 4
  for (int kb = 0; kb < 8; ++kb){
    s8v A[4];
    #pragma unroll
    for (int mf = 0; mf < 4; ++mf) A[mf] = *(const s8v*)(pw2b + (size_t)kb * 8192 + mf * 512);
    #pragma unroll
    for (int nf = 0; nf < 4; ++nf){
      int e = nf * 16 + li;
      BU bu;
      bu.d[0] = mt[e * 64 + ((kb * 8 + g)     ^ (e & 7))];
      bu.d[1] = mt[e * 64 + ((kb * 8 + 4 + g) ^ (e & 7))];
      #pragma unroll
      for (int mf = 0; mf < 4; ++mf)
        acc[mf][nf] = __builtin_amdgcn_mfma_f32_16x16x32_bf16(A[mf], bu.v, acc[mf][nf], 0, 0, 0);
    }
  }
  #pragma unroll
  for (int mf = 0; mf < 4; ++mf){
    const int fb = w * 64 + mf * 16 + g * 4;
    #pragma unroll
    for (int nf = 0; nf < 4; ++nf){
      int n = nb + nf * 16 + li;
      if (n < NN){
        float4 hv = *(float4*)(h + (size_t)n * HH + fb);
        float o0 = hv.x + acc[mf][nf][0] + bias_s[256+fb+0];
        float o1 = hv.y + acc[mf][nf][1] + bias_s[256+fb+1];
        float o2 = hv.z + acc[mf][nf][2] + bias_s[256+fb+2];
        float o3 = hv.w + acc[mf][nf][3] + bias_s[256+fb+3];
        *(float4*)(h + (size_t)n * HH + fb) = make_float4(o0, o1, o2, o3);
        *(u64*)(hb + (size_t)n * HH + fb) = pack4bf(o0, o1, o2, o3);
      }
    }
  }
}

// ---------------- emb_out + max-pool ----------------
__global__ __launch_bounds__(256) void emb_out_pool_kernel(
    const u16* __restrict__ hb, const u16* __restrict__ pw,
    const float* __restrict__ bias, const int* __restrict__ batch, u32* __restrict__ pooled){
  const int tid = threadIdx.x;
  const int w = tid >> 6, l = tid & 63, g = l >> 4, li = l & 15;
  const int nb = blockIdx.x * 64;
  const u16* hp[4]; int bs[4];
  #pragma unroll
  for (int nf = 0; nf < 4; ++nf){
    int n = nb + nf * 16 + li; int nc = (n >= NN) ? NN - 1 : n;
    hp[nf] = hb + (size_t)nc * HH + g * 4;
    bs[nf] = batch[nc];
  }
  f4v acc[4][4];
  #pragma unroll
  for (int a = 0; a < 4; ++a)
    #pragma unroll
    for (int b = 0; b < 4; ++b) acc[a][b] = (f4v){0.f,0.f,0.f,0.f};
  const u16* pwb = pw + ((size_t)(w * 4) * 64 + l) * 8;
  #pragma unroll 4
  for (int kb = 0; kb < 8; ++kb){
    s8v A[4];
    #pragma unroll
    for (int mf = 0; mf < 4; ++mf) A[mf] = *(const s8v*)(pwb + (size_t)kb * 8192 + mf * 512);
    #pragma unroll
    for (int nf = 0; nf < 4; ++nf){
      BU bu;
      bu.d[0] = *(const u64*)(hp[nf] + kb * 32);
      bu.d[1] = *(const u64*)(hp[nf] + kb * 32 + 16);
      #pragma unroll
      for (int mf = 0; mf < 4; ++mf)
        acc[mf][nf] = __builtin_amdgcn_mfma_f32_16x16x32_bf16(A[mf], bu.v, acc[mf][nf], 0, 0, 0);
    }
  }
  #pragma unroll
  for (int mf = 0; mf < 4; ++mf){
    const int fb = w * 64 + mf * 16 + g * 4;
    float b0 = bias[fb], b1 = bias[fb+1], b2 = bias[fb+2], b3 = bias[fb+3];
    #pragma unroll
    for (int nf = 0; nf < 4; ++nf){
      int n = nb + nf * 16 + li;
      if (n < NN){
        float vv[4] = {acc[mf][nf][0] + b0, acc[mf][nf][1] + b1, acc[mf][nf][2] + b2, acc[mf][nf][3] + b3};
        #pragma unroll
        for (int r = 0; r < 4; ++r){
          u32 u = __float_as_uint(vv[r]);
          u = (u & 0x80000000u) ? ~u : (u | 0x80000000u);
          atomicMax(&pooled[(size_t)bs[nf] * HH + fb + r], u);
        }
      }
    }
  }
}

// ---------------- resblock + head ----------------
__global__ __launch_bounds__(256) void final_kernel(
    const float* __restrict__ z, const float* __restrict__ rw1, const float* __restrict__ rb1,
    const float* __restrict__ rw2, const float* __restrict__ rb2,
    const float* __restrict__ hw, const float* __restrict__ hbs, float* __restrict__ out){
  __shared__ float zr[272], t1[256], t2[272];
  const int b = blockIdx.x, tid = threadIdx.x;
  for (int i = tid; i < 272; i += 256) zr[i] = z[(size_t)b * 272 + i];
  __syncthreads();
  {
    float a = rb1[tid];
    for (int k = 0; k < 272; ++k) a += zr[k] * rw1[(size_t)k * 256 + tid];
    t1[tid] = siluf(a);
  }
  __syncthreads();
  for (int i = tid; i < 272; i += 256){
    float a = rb2[i] + zr[i];
    for (int k = 0; k < 256; ++k) a += t1[k] * rw2[(size_t)k * 272 + i];
    t2[i] = a;
  }
  __syncthreads();
  for (int p = tid; p < 2000; p += 256){
    float a = hbs[p];
    for (int k = 0; k < 272; ++k) a += t2[k] * hw[(size_t)k * 2000 + p];
    out[(size_t)b * 2000 + p] = a;
  }
}

extern "C" void kernel_launch(void* const* d_in, const int* in_sizes, int n_in,
                              void* d_out, int out_size, void* d_ws, size_t ws_size,
                              hipStream_t stream){
  const float* x        = (const float*)d_in[0];
  const float* pos      = (const float*)d_in[1];
  const float* eattr    = (const float*)d_in[2];
  const float* fragl    = (const float*)d_in[3];
  const float* addf     = (const float*)d_in[4];
  const int*   ei       = (const int*)d_in[5];
  const int*   batch    = (const int*)d_in[6];
  const float* emb_in_w = (const float*)d_in[7];
  const float* emb_in_b = (const float*)d_in[8];
  const float* edge_w1  = (const float*)d_in[9];
  const float* edge_b1  = (const float*)d_in[10];
  const float* edge_w2  = (const float*)d_in[11];
  const float* edge_b2  = (const float*)d_in[12];
  const float* node_w1  = (const float*)d_in[13];
  const float* node_b1  = (const float*)d_in[14];
  const float* node_w2  = (const float*)d_in[15];
  const float* node_b2  = (const float*)d_in[16];
  const float* coord_w1 = (const float*)d_in[17];
  const float* coord_b1 = (const float*)d_in[18];
  const float* coord_w2 = (const float*)d_in[19];
  const float* emb_out_w= (const float*)d_in[20];
  const float* emb_out_b= (const float*)d_in[21];
  const float* res_w1   = (const float*)d_in[22];
  const float* res_b1   = (const float*)d_in[23];
  const float* res_w2   = (const float*)d_in[24];
  const float* res_b2   = (const float*)d_in[25];
  const float* head_w   = (const float*)d_in[26];
  const float* head_b   = (const float*)d_in[27];

  char* ws = (char*)d_ws;
  size_t off = 0;
  auto alloc = [&](size_t bytes) -> void* {
    void* p = ws + off;
    off += (bytes + 255) & ~(size_t)255;
    return p;
  };
  float*  h      = (float*)alloc((size_t)NN * HH * 4);
  float*  agg    = (float*)alloc((size_t)NN * HH * 4);
  u16*    agg_bf = (u16*)  alloc((size_t)NN * HH * 2);
  u16*    hb     = (u16*)  alloc((size_t)NN * HH * 2);
  float*  Pa     = (float*)alloc((size_t)NN * HH * 4);
  float*  Pb     = (float*)alloc((size_t)NN * HH * 4);
  float4* coordb = (float4*)alloc((size_t)NN * 16);
  float*  cacc   = (float*)alloc((size_t)NN * 16);
  u32*    pooled = (u32*)  alloc((size_t)BB * HH * 4);
  float*  z      = (float*)alloc((size_t)BB * 272 * 4);
  u16*    packed = (u16*)  alloc((size_t)7680 * 256 * 2);
  int*    icnt   = (int*)  alloc((size_t)NN * 4);
  int*    iscan  = (int*)  alloc((size_t)NN * 4);
  int*    rstart = (int*)  alloc((size_t)NN * 4);
  int*    cursor = (int*)  alloc((size_t)NN * 4);
  int*    bsum   = (int*)  alloc((size_t)128 * 4);
  int*    seid   = (int*)  alloc((size_t)EE * 4);
  int*    srow   = (int*)  alloc((size_t)EE * 4);
  int*    scol   = (int*)  alloc((size_t)EE * 4);
  const size_t base_off = off;
  u64*    m2g    = (u64*)  alloc((size_t)EE * HH * 2);   // 164 MB m2 stream buffer
  const bool use_stream = (off <= ws_size);
  if (base_off > ws_size) return;

  u16* pk_embin  = packed;
  u16* pk_embout = packed + 32768 + (size_t)4 * 466944;
  auto pk_ew1 = [&](int l){ return packed + 32768 + (size_t)l * 466944; };
  auto pk_ew2 = [&](int l){ return pk_ew1(l) + 139264; };
  auto pk_cw1 = [&](int l){ return pk_ew1(l) + 204800; };
  auto pk_nw1 = [&](int l){ return pk_ew1(l) + 270336; };
  auto pk_nw2 = [&](int l){ return pk_ew1(l) + 401408; };

  pack_kernel<<<16, 256, 0, stream>>>(emb_in_w, pk_embin, 128, 4);
  for (int l = 0; l < 4; ++l){
    pack_kernel<<<68, 256, 0, stream>>>(edge_w1 + (size_t)l * 529 * 256, pk_ew1(l), 529, 17);
    pack_kernel<<<32, 256, 0, stream>>>(edge_w2 + (size_t)l * 65536,     pk_ew2(l), 256, 8);
    pack_kernel<<<32, 256, 0, stream>>>(coord_w1 + (size_t)l * 65536,    pk_cw1(l), 256, 8);
    pack_kernel<<<64, 256, 0, stream>>>(node_w1 + (size_t)l * 131072,    pk_nw1(l), 512, 16);
    pack_kernel<<<32, 256, 0, stream>>>(node_w2 + (size_t)l * 65536,     pk_nw2(l), 256, 8);
  }
  pack_kernel<<<32, 256, 0, stream>>>(emb_out_w, pk_embout, 256, 8);

  // ---- one-time edge sort by row
  const int NB = (NN + 255) / 256;   // 79
  hipMemsetAsync(icnt,   0, (size_t)NN * 4, stream);
  hipMemsetAsync(cursor, 0, (size_t)NN * 4, stream);
  icnt_kernel<<<(EE + 255) / 256, 256, 0, stream>>>(ei, icnt);
  iscan_block<<<NB, 256, 0, stream>>>(icnt, iscan, bsum);
  iscan_top<<<1, 64, 0, stream>>>(bsum, NB);
  iscan_fix<<<NB, 256, 0, stream>>>(icnt, iscan, bsum, rstart);
  scatter_kernel<<<(EE + 255) / 256, 256, 0, stream>>>(ei, rstart, cursor, seid, srow, scol);

  coord_init_kernel<<<79, 256, 0, stream>>>(pos, coordb);
  emb_in_kernel<<<313, 256, 0, stream>>>(x, pk_embin, emb_in_b, h, hb);

  for (int l = 0; l < 4; ++l){
    hipMemsetAsync(cacc, 0, (size_t)NN * 16, stream);
    pab_kernel<<<313, 256, 0, stream>>>(hb, pk_ew1(l), edge_b1 + l * 256, Pa, Pb);
    if (use_stream){
      edge_kernel<true><<<5000, 256, 0, stream>>>(Pa, Pb, coordb, srow, scol, seid, eattr,
          pk_ew1(l), pk_ew2(l), pk_cw1(l),
          edge_b2 + l * 256, coord_b1 + l * 256, coord_w2 + l * 256,
          agg, cacc, m2g);
      agg_csr_kernel<<<NN, 256, 0, stream>>>((const u16*)m2g, rstart, icnt, agg_bf);
    } else {
      hipMemsetAsync(agg, 0, (size_t)NN * HH * 4, stream);
      edge_kernel<false><<<5000, 256, 0, stream>>>(Pa, Pb, coordb, srow, scol, seid, eattr,
          pk_ew1(l), pk_ew2(l), pk_cw1(l),
          edge_b2 + l * 256, coord_b1 + l * 256, coord_w2 + l * 256,
          agg, cacc, m2g);
      agg_conv_kernel<<<(NN * HH + 255) / 256, 256, 0, stream>>>(agg, agg_bf);
    }
    coord_upd_kernel<<<79, 256, 0, stream>>>(coordb, cacc, icnt);
    node_kernel<<<313, 256, 0, stream>>>(h, hb, agg_bf, pk_nw1(l), pk_nw2(l),
        node_b1 + l * 256, node_b2 + l * 256);
  }

  pool_init_kernel<<<128, 256, 0, stream>>>(pooled);
  emb_out_pool_kernel<<<313, 256, 0, stream>>>(hb, pk_embout, emb_out_b, batch, pooled);
  build_z_kernel<<<136, 256, 0, stream>>>(pooled, fragl, addf, z);
  final_kernel<<<128, 256, 0, stream>>>(z, res_w1, res_b1, res_w2, res_b2, head_w, head_b,
                                        (float*)d_out);
}

// Round 6
// 2108.840 us; speedup vs baseline: 2.6642x; 1.0737x over previous
//
#include <hip/hip_runtime.h>

typedef unsigned short u16;
typedef unsigned int   u32;
typedef unsigned long long u64;
typedef __attribute__((ext_vector_type(8))) short s8v;   // 8 bf16 (4 VGPRs) MFMA operand
typedef __attribute__((ext_vector_type(4))) float f4v;   // MFMA accumulator

#define NN 20000
#define EE 320000
#define BB 128
#define HH 256

union BU { u64 d[2]; s8v v; };

__device__ __forceinline__ u16 f2bf(float f){
  u32 u = __float_as_uint(f);
  return (u16)((u + 0x7FFFu + ((u >> 16) & 1u)) >> 16);   // RNE
}
__device__ __forceinline__ float bf2f(u16 u){ return __uint_as_float((u32)u << 16); }
__device__ __forceinline__ u32 cvt2(float a, float b){
  u32 r; asm("v_cvt_pk_bf16_f32 %0, %1, %2" : "=v"(r) : "v"(a), "v"(b)); return r;
}
__device__ __forceinline__ u64 pack4bf(float a, float b, float c, float d){
  return (u64)cvt2(a, b) | ((u64)cvt2(c, d) << 32);
}
__device__ __forceinline__ float siluf(float v){ return v / (1.0f + __expf(-v)); }

// ---------------- weight packing: W [K][256] f32 -> A-fragment blob (W^T), bf16 ----------------
__global__ void pack_kernel(const float* __restrict__ src, u16* __restrict__ dst, int K, int KB){
  int t = blockIdx.x * 256 + threadIdx.x;
  if (t >= KB * 1024) return;
  int lane = t & 63, mf = (t >> 6) & 15, kb = t >> 10;
  int g = lane >> 4, li = lane & 15;
  int m = mf * 16 + li;
  u16 o[8];
  #pragma unroll
  for (int j = 0; j < 8; ++j){
    int k = kb * 32 + ((j < 4) ? (g * 4 + j) : (16 + g * 4 + (j - 4)));
    o[j] = (k < K) ? f2bf(src[(size_t)k * 256 + m]) : (u16)0;
  }
  u16* d = dst + ((size_t)(kb * 16 + mf) * 64 + lane) * 8;
  *(u64*)(d)     = (u64)o[0] | ((u64)o[1] << 16) | ((u64)o[2] << 32) | ((u64)o[3] << 48);
  *(u64*)(d + 4) = (u64)o[4] | ((u64)o[5] << 16) | ((u64)o[6] << 32) | ((u64)o[7] << 48);
}

// ---------------- edge sort by destination row (one-time per launch) ----------------
__global__ void icnt_kernel(const int* __restrict__ ei, int* __restrict__ icnt){
  int t = blockIdx.x * 256 + threadIdx.x;
  if (t < EE) atomicAdd(&icnt[ei[t]], 1);
}
__global__ void iscan_block(const int* __restrict__ icnt, int* __restrict__ iscan, int* __restrict__ bsum){
  __shared__ int s[256];
  int i = blockIdx.x * 256 + threadIdx.x;
  int v = (i < NN) ? icnt[i] : 0;
  s[threadIdx.x] = v; __syncthreads();
  #pragma unroll
  for (int d = 1; d < 256; d <<= 1){
    int t = (threadIdx.x >= d) ? s[threadIdx.x - d] : 0;
    __syncthreads();
    s[threadIdx.x] += t;
    __syncthreads();
  }
  if (i < NN) iscan[i] = s[threadIdx.x];
  if (threadIdx.x == 255) bsum[blockIdx.x] = s[255];
}
__global__ void iscan_top(int* __restrict__ bsum, int nb){
  if (blockIdx.x == 0 && threadIdx.x == 0){
    int acc = 0;
    for (int i = 0; i < nb; ++i){ int t = bsum[i]; bsum[i] = acc; acc += t; }
  }
}
__global__ void iscan_fix(const int* __restrict__ icnt, const int* __restrict__ iscan,
                          const int* __restrict__ bsum, int* __restrict__ rstart){
  int i = blockIdx.x * 256 + threadIdx.x;
  if (i < NN) rstart[i] = bsum[blockIdx.x] + iscan[i] - icnt[i];
}
__global__ void scatter_kernel(const int* __restrict__ ei, const int* __restrict__ rstart,
                               int* __restrict__ cursor, int* __restrict__ seid,
                               int* __restrict__ srow, int* __restrict__ scol){
  int e = blockIdx.x * 256 + threadIdx.x;
  if (e < EE){
    int r = ei[e];
    int p = rstart[r] + atomicAdd(&cursor[r], 1);
    seid[p] = e; srow[p] = r; scol[p] = ei[EE + e];
  }
}

// ---------------- small utility kernels ----------------
__global__ void coord_init_kernel(const float* __restrict__ pos, float4* __restrict__ coord){
  int t = blockIdx.x * 256 + threadIdx.x;
  if (t < NN) coord[t] = make_float4(pos[3*t], pos[3*t+1], pos[3*t+2], 0.f);
}
__global__ void coord_upd_kernel(float4* __restrict__ coord, const float* __restrict__ cacc,
                                 const int* __restrict__ icnt){
  int t = blockIdx.x * 256 + threadIdx.x;
  if (t >= NN) return;
  float k = fmaxf((float)icnt[t], 1.0f);
  float4 c = coord[t];
  c.x += cacc[4*t+0] / k; c.y += cacc[4*t+1] / k; c.z += cacc[4*t+2] / k;
  coord[t] = c;
}
__global__ void pool_init_kernel(u32* __restrict__ pooled){
  int t = blockIdx.x * 256 + threadIdx.x;
  if (t < BB * HH){
    u32 u = __float_as_uint(-3.0e38f);
    pooled[t] = ~u;
  }
}
__global__ void build_z_kernel(const u32* __restrict__ pooled, const float* __restrict__ fragl,
                               const float* __restrict__ addf, float* __restrict__ z){
  int t = blockIdx.x * 256 + threadIdx.x;
  if (t >= BB * 272) return;
  int b = t / 272, j = t % 272;
  float v;
  if (j < 256){
    u32 u = pooled[b * 256 + j];
    v = (u & 0x80000000u) ? __uint_as_float(u & 0x7FFFFFFFu) : __uint_as_float(~u);
  } else if (j < 264) v = fragl[b * 8 + (j - 256)];
  else                v = addf[b * 8 + (j - 264)];
  z[t] = v;
}

// ---------------- CSR segment-sum: agg_bf[n][f] = bf16( sum_e m2[e][f] ) ----------------
__global__ __launch_bounds__(256) void agg_csr_kernel(
    const u16* __restrict__ m2b, const int* __restrict__ rstart,
    const int* __restrict__ icnt, u16* __restrict__ agg_bf){
  const int n = blockIdx.x, f = threadIdx.x;
  const int s = rstart[n], d = icnt[n];
  const u16* p = m2b + (size_t)s * 256 + f;
  float a0 = 0.f, a1 = 0.f;
  int i = 0;
  for (; i + 1 < d; i += 2){ a0 += bf2f(p[(size_t)i * 256]); a1 += bf2f(p[(size_t)(i + 1) * 256]); }
  if (i < d) a0 += bf2f(p[(size_t)i * 256]);
  agg_bf[(size_t)n * 256 + f] = f2bf(a0 + a1);
}
__global__ void agg_conv_kernel(const float* __restrict__ agg, u16* __restrict__ agg_bf){
  int t = blockIdx.x * 256 + threadIdx.x;
  if (t < NN * HH) agg_bf[t] = f2bf(agg[t]);
}

// ---------------- emb_in: h = x @ emb_in_w + b ----------------
__global__ __launch_bounds__(256) void emb_in_kernel(
    const float* __restrict__ x, const u16* __restrict__ pw,
    const float* __restrict__ bias, float* __restrict__ h, u16* __restrict__ hb){
  const int tid = threadIdx.x;
  const int w = tid >> 6, l = tid & 63, g = l >> 4, li = l & 15;
  const int nb = blockIdx.x * 64;
  const float* xp[4];
  #pragma unroll
  for (int nf = 0; nf < 4; ++nf){
    int n = nb + nf * 16 + li; if (n >= NN) n = NN - 1;
    xp[nf] = x + (size_t)n * 128 + g * 4;
  }
  f4v acc[4][4];
  #pragma unroll
  for (int a = 0; a < 4; ++a)
    #pragma unroll
    for (int b = 0; b < 4; ++b) acc[a][b] = (f4v){0.f,0.f,0.f,0.f};
  const u16* pwb = pw + ((size_t)(w * 4) * 64 + l) * 8;
  #pragma unroll
  for (int kb = 0; kb < 4; ++kb){
    s8v A[4];
    #pragma unroll
    for (int mf = 0; mf < 4; ++mf) A[mf] = *(const s8v*)(pwb + (size_t)kb * 8192 + mf * 512);
    #pragma unroll
    for (int nf = 0; nf < 4; ++nf){
      float4 fa = *(const float4*)(xp[nf] + kb * 32);
      float4 fb = *(const float4*)(xp[nf] + kb * 32 + 16);
      BU bu;
      bu.d[0] = pack4bf(fa.x, fa.y, fa.z, fa.w);
      bu.d[1] = pack4bf(fb.x, fb.y, fb.z, fb.w);
      #pragma unroll
      for (int mf = 0; mf < 4; ++mf)
        acc[mf][nf] = __builtin_amdgcn_mfma_f32_16x16x32_bf16(A[mf], bu.v, acc[mf][nf], 0, 0, 0);
    }
  }
  #pragma unroll
  for (int mf = 0; mf < 4; ++mf){
    const int fb = w * 64 + mf * 16 + g * 4;
    float b0 = bias[fb], b1 = bias[fb+1], b2 = bias[fb+2], b3 = bias[fb+3];
    #pragma unroll
    for (int nf = 0; nf < 4; ++nf){
      int n = nb + nf * 16 + li;
      if (n < NN){
        float o0 = acc[mf][nf][0] + b0, o1 = acc[mf][nf][1] + b1;
        float o2 = acc[mf][nf][2] + b2, o3 = acc[mf][nf][3] + b3;
        *(float4*)(h + (size_t)n * HH + fb) = make_float4(o0, o1, o2, o3);
        *(u64*)(hb + (size_t)n * HH + fb) = pack4bf(o0, o1, o2, o3);
      }
    }
  }
}

// ---------------- P_a = h@W1a + b1 ; P_b = h@W1b  (node-level GEMM, f32 out) ----------------
__global__ __launch_bounds__(256) void pab_kernel(
    const u16* __restrict__ hb, const u16* __restrict__ pw1, const float* __restrict__ b1,
    float* __restrict__ Pa, float* __restrict__ Pb){
  const int tid = threadIdx.x;
  const int w = tid >> 6, l = tid & 63, g = l >> 4, li = l & 15;
  const int nb = blockIdx.x * 64;
  const u16* hp[4];
  #pragma unroll
  for (int nf = 0; nf < 4; ++nf){
    int n = nb + nf * 16 + li; if (n >= NN) n = NN - 1;
    hp[nf] = hb + (size_t)n * HH + g * 4;
  }
  const u16* pwb = pw1 + ((size_t)(w * 4) * 64 + l) * 8;
  #pragma unroll
  for (int pass = 0; pass < 2; ++pass){
    f4v acc[4][4];
    #pragma unroll
    for (int a = 0; a < 4; ++a)
      #pragma unroll
      for (int b = 0; b < 4; ++b) acc[a][b] = (f4v){0.f,0.f,0.f,0.f};
    const u16* pwp = pwb + (size_t)(pass * 8) * 8192;   // W1a = kb 0..7, W1b = kb 8..15
    #pragma unroll 4
    for (int kb = 0; kb < 8; ++kb){
      s8v A[4];
      #pragma unroll
      for (int mf = 0; mf < 4; ++mf) A[mf] = *(const s8v*)(pwp + (size_t)kb * 8192 + mf * 512);
      #pragma unroll
      for (int nf = 0; nf < 4; ++nf){
        BU bu;
        bu.d[0] = *(const u64*)(hp[nf] + kb * 32);
        bu.d[1] = *(const u64*)(hp[nf] + kb * 32 + 16);
        #pragma unroll
        for (int mf = 0; mf < 4; ++mf)
          acc[mf][nf] = __builtin_amdgcn_mfma_f32_16x16x32_bf16(A[mf], bu.v, acc[mf][nf], 0, 0, 0);
      }
    }
    float* dst = pass ? Pb : Pa;
    #pragma unroll
    for (int mf = 0; mf < 4; ++mf){
      const int fb = w * 64 + mf * 16 + g * 4;
      float c0 = 0.f, c1 = 0.f, c2 = 0.f, c3 = 0.f;
      if (!pass){ c0 = b1[fb]; c1 = b1[fb+1]; c2 = b1[fb+2]; c3 = b1[fb+3]; }
      #pragma unroll
      for (int nf = 0; nf < 4; ++nf){
        int n = nb + nf * 16 + li;
        if (n < NN)
          *(float4*)(dst + (size_t)n * HH + fb) =
            make_float4(acc[mf][nf][0] + c0, acc[mf][nf][1] + c1,
                        acc[mf][nf][2] + c2, acc[mf][nf][3] + c3);
      }
    }
  }
}

// ---------------- edge kernel: 64 SORTED edges/block, 512 threads (8 waves x 32 feats) ----------------
// Re-tiled for occupancy: halves per-wave accumulator state vs the 4-wave version,
// so 2-3 blocks (16-24 waves) fit per CU and gather/barrier latency is hidden by TLP.
// XCD-swizzled blockIdx: consecutive sorted-edge blocks share Pa/Pb rows -> same-XCD L2 hits.
template<bool STREAM>
__global__ __launch_bounds__(512) void edge_kernel(
    const float* __restrict__ Pa, const float* __restrict__ Pb,
    const float4* __restrict__ coord,
    const int* __restrict__ srow, const int* __restrict__ scol, const int* __restrict__ seid,
    const float* __restrict__ eattr,
    const u16* __restrict__ pw1, const u16* __restrict__ pw2, const u16* __restrict__ pw3,
    const float* __restrict__ b2, const float* __restrict__ cb1, const float* __restrict__ cw2,
    float* __restrict__ agg, float* __restrict__ cacc, u64* __restrict__ m2g){
  __shared__ u64 mt[4096];            // 32KB swizzled tile [64 edges][64 4-feat chunks]
  __shared__ float4 dif[64];
  __shared__ int rows_s[64];
  __shared__ int cols_s[64];
  __shared__ int seid_s[64];
  __shared__ float bias_s[768];       // b2 | cb1 | cw2
  __shared__ float cpart[8][64];

  const int tid = threadIdx.x;
  const int w = tid >> 6, l = tid & 63, g = l >> 4, li = l & 15;
  // 5000 blocks = 8 * 625: bijective XCD swizzle for L2 locality of sorted rows
  const int wg = (blockIdx.x & 7) * 625 + (blockIdx.x >> 3);
  const int eb = wg * 64;

  if (tid < 64){
    int sp = eb + tid;
    int r = srow[sp], c = scol[sp];
    rows_s[tid] = r; cols_s[tid] = c; seid_s[tid] = seid[sp];
    float4 ca = coord[r], cb = coord[c];
    float dx = ca.x - cb.x, dy = ca.y - cb.y, dz = ca.z - cb.z;
    float rad = dx*dx + dy*dy + dz*dz;
    dif[tid] = make_float4(dx, dy, dz, rad);
  }
  for (int i = tid; i < 768; i += 512){
    float v;
    if      (i < 256) v = b2[i];
    else if (i < 512) v = cb1[i - 256];
    else              v = cw2[i - 512];
    bias_s[i] = v;
  }
  __syncthreads();

  const float* paP[4]; const float* pbP[4];
  #pragma unroll
  for (int nf = 0; nf < 4; ++nf){
    int e = nf * 16 + li;
    paP[nf] = Pa + (size_t)rows_s[e] * HH;
    pbP[nf] = Pb + (size_t)cols_s[e] * HH;
  }

  // wave w owns output features w*32 .. w*32+31 (fragments mf16 = w*2, w*2+1)
  const u16* pw1b = pw1 + ((size_t)(w * 2) * 64 + l) * 8;
  const u16* pw2b = pw2 + ((size_t)(w * 2) * 64 + l) * 8;
  const u16* pw3b = pw3 + ((size_t)(w * 2) * 64 + l) * 8;

  // ---- tail k-block operands (k 512..543: radial | edge_attr | 0-pad)
  float tf[4][4];
  float rads[4];
  #pragma unroll
  for (int nf = 0; nf < 4; ++nf){
    int e = nf * 16 + li;
    const float* ep = eattr + (size_t)seid_s[e] * 16;
    if (g == 0){ tf[nf][0] = ep[0]; tf[nf][1] = ep[1]; tf[nf][2] = ep[2]; tf[nf][3] = ep[15]; }
    else { int i0 = g * 4 - 1; tf[nf][0] = ep[i0]; tf[nf][1] = ep[i0+1]; tf[nf][2] = ep[i0+2]; tf[nf][3] = ep[i0+3]; }
    rads[nf] = dif[e].w;
  }

  f4v acc[2][4];
  #pragma unroll
  for (int a = 0; a < 2; ++a)
    #pragma unroll
    for (int b = 0; b < 4; ++b) acc[a][b] = (f4v){0.f,0.f,0.f,0.f};

  // ---- tail MFMA (only remaining piece of GEMM1)
  {
    s8v at[2];
    #pragma unroll
    for (int mf = 0; mf < 2; ++mf) at[mf] = *(const s8v*)(pw1b + (size_t)16 * 8192 + mf * 512);
    #pragma unroll
    for (int nf = 0; nf < 4; ++nf){
      BU bu;
      if (g == 0){ bu.d[0] = pack4bf(rads[nf], tf[nf][0], tf[nf][1], tf[nf][2]); bu.d[1] = (u64)(cvt2(tf[nf][3], 0.f) & 0xffffu); }
      else       { bu.d[0] = pack4bf(tf[nf][0], tf[nf][1], tf[nf][2], tf[nf][3]); bu.d[1] = 0; }
      #pragma unroll
      for (int mf = 0; mf < 2; ++mf)
        acc[mf][nf] = __builtin_amdgcn_mfma_f32_16x16x32_bf16(at[mf], bu.v, acc[mf][nf], 0, 0, 0);
    }
  }

  // ---- m1 = silu(acc + Pa[row] + Pb[col])  (b1 folded into Pa)
  #pragma unroll
  for (int mf = 0; mf < 2; ++mf){
    const int fb = w * 32 + mf * 16 + g * 4;
    const int fc = fb >> 2;
    #pragma unroll
    for (int nf = 0; nf < 4; ++nf){
      int e = nf * 16 + li;
      float4 pa = *(const float4*)(paP[nf] + fb);
      float4 pb = *(const float4*)(pbP[nf] + fb);
      float v0 = siluf(acc[mf][nf][0] + pa.x + pb.x);
      float v1 = siluf(acc[mf][nf][1] + pa.y + pb.y);
      float v2 = siluf(acc[mf][nf][2] + pa.z + pb.z);
      float v3 = siluf(acc[mf][nf][3] + pa.w + pb.w);
      mt[e * 64 + (fc ^ (e & 7))] = pack4bf(v0, v1, v2, v3);
    }
  }
  __syncthreads();

  // ---- GEMM2: m2 = silu(m1 @ W2 + b2)
  #pragma unroll
  for (int a = 0; a < 2; ++a)
    #pragma unroll
    for (int b = 0; b < 4; ++b) acc[a][b] = (f4v){0.f,0.f,0.f,0.f};
  #pragma unroll 4
  for (int s = 0; s < 8; ++s){
    s8v A[2];
    #pragma unroll
    for (int mf = 0; mf < 2; ++mf) A[mf] = *(const s8v*)(pw2b + (size_t)s * 8192 + mf * 512);
    #pragma unroll
    for (int nf = 0; nf < 4; ++nf){
      int e = nf * 16 + li;
      BU bu;
      bu.d[0] = mt[e * 64 + ((s * 8 + g)     ^ (e & 7))];
      bu.d[1] = mt[e * 64 + ((s * 8 + 4 + g) ^ (e & 7))];
      #pragma unroll
      for (int mf = 0; mf < 2; ++mf)
        acc[mf][nf] = __builtin_amdgcn_mfma_f32_16x16x32_bf16(A[mf], bu.v, acc[mf][nf], 0, 0, 0);
    }
  }
  u64 pm2[2][4];                      // m2 as packed bf16 (exactly what LDS/stream need)
  #pragma unroll
  for (int mf = 0; mf < 2; ++mf){
    const int fb = w * 32 + mf * 16 + g * 4;
    #pragma unroll
    for (int nf = 0; nf < 4; ++nf)
      pm2[mf][nf] = pack4bf(siluf(acc[mf][nf][0] + bias_s[fb+0]),
                            siluf(acc[mf][nf][1] + bias_s[fb+1]),
                            siluf(acc[mf][nf][2] + bias_s[fb+2]),
                            siluf(acc[mf][nf][3] + bias_s[fb+3]));
  }
  __syncthreads();                    // all waves done reading m1
  #pragma unroll
  for (int mf = 0; mf < 2; ++mf){
    const int fc = (w * 32 + mf * 16 + g * 4) >> 2;
    #pragma unroll
    for (int nf = 0; nf < 4; ++nf){
      int e = nf * 16 + li;
      mt[e * 64 + (fc ^ (e & 7))] = pm2[mf][nf];
    }
  }
  __syncthreads();

  // ---- STREAM: coalesced write-out of m2 tile
  if (STREAM){
    u64* dst = m2g + (size_t)eb * 64;
    #pragma unroll
    for (int j = 0; j < 8; ++j){
      int q = j * 512 + tid;
      int e = q >> 6, fc = q & 63;
      dst[(size_t)e * 64 + fc] = mt[e * 64 + (fc ^ (e & 7))];
    }
  }

  // ---- GEMM3: q = silu(m2 @ CW1 + cb1); c = q . cw2
  #pragma unroll
  for (int a = 0; a < 2; ++a)
    #pragma unroll
    for (int b = 0; b < 4; ++b) acc[a][b] = (f4v){0.f,0.f,0.f,0.f};
  #pragma unroll 4
  for (int s = 0; s < 8; ++s){
    s8v A[2];
    #pragma unroll
    for (int mf = 0; mf < 2; ++mf) A[mf] = *(const s8v*)(pw3b + (size_t)s * 8192 + mf * 512);
    #pragma unroll
    for (int nf = 0; nf < 4; ++nf){
      int e = nf * 16 + li;
      BU bu;
      bu.d[0] = mt[e * 64 + ((s * 8 + g)     ^ (e & 7))];
      bu.d[1] = mt[e * 64 + ((s * 8 + 4 + g) ^ (e & 7))];
      #pragma unroll
      for (int mf = 0; mf < 2; ++mf)
        acc[mf][nf] = __builtin_amdgcn_mfma_f32_16x16x32_bf16(A[mf], bu.v, acc[mf][nf], 0, 0, 0);
    }
  }
  float cp4[4] = {0.f, 0.f, 0.f, 0.f};
  #pragma unroll
  for (int mf = 0; mf < 2; ++mf){
    const int fb = w * 32 + mf * 16 + g * 4;
    #pragma unroll
    for (int nf = 0; nf < 4; ++nf){
      #pragma unroll
      for (int r = 0; r < 4; ++r){
        float q = siluf(acc[mf][nf][r] + bias_s[256 + fb + r]);
        cp4[nf] += q * bias_s[512 + fb + r];
      }
    }
  }
  #pragma unroll
  for (int nf = 0; nf < 4; ++nf){
    float v = cp4[nf];
    v += __shfl_xor(v, 16, 64);
    v += __shfl_xor(v, 32, 64);
    if (g == 0) cpart[w][nf * 16 + li] = v;
  }
  __syncthreads();

  // ---- cacc: segmented suffix-reduce across the 64 sorted edges, head lanes atomic
  if (tid < 64){
    float c = cpart[0][tid] + cpart[1][tid] + cpart[2][tid] + cpart[3][tid]
            + cpart[4][tid] + cpart[5][tid] + cpart[6][tid] + cpart[7][tid];
    float4 d = dif[tid];
    const int myrow = rows_s[tid];
    float vx = d.x * c, vy = d.y * c, vz = d.z * c;
    #pragma unroll
    for (int dd = 1; dd < 64; dd <<= 1){
      const int rr = __shfl_down(myrow, dd, 64);
      const bool ok = ((tid + dd) < 64) && (rr == myrow);
      float tx = __shfl_down(vx, dd, 64);
      float ty = __shfl_down(vy, dd, 64);
      float tz = __shfl_down(vz, dd, 64);
      if (ok){ vx += tx; vy += ty; vz += tz; }
    }
    if (tid == 0 || rows_s[tid - 1] != myrow){
      atomicAdd(cacc + (size_t)myrow * 4 + 0, vx);
      atomicAdd(cacc + (size_t)myrow * 4 + 1, vy);
      atomicAdd(cacc + (size_t)myrow * 4 + 2, vz);
    }
  }

  // ---- fallback path only: agg via segmented suffix-reduce + atomics
  if (!STREAM){
    #pragma unroll
    for (int nf = 0; nf < 4; ++nf){
      const int myrow = rows_s[nf * 16 + li];
      const bool head = (li == 0) || (rows_s[nf * 16 + li - 1] != myrow);
      float v[8];
      #pragma unroll
      for (int mf = 0; mf < 2; ++mf)
        #pragma unroll
        for (int r = 0; r < 4; ++r) v[mf * 4 + r] = bf2f((u16)(pm2[mf][nf] >> (16 * r)));
      #pragma unroll
      for (int d = 1; d < 16; d <<= 1){
        const int rr = __shfl_down(myrow, d, 16);
        const bool ok = ((li + d) < 16) && (rr == myrow);
        #pragma unroll
        for (int j = 0; j < 8; ++j){
          const float vv = __shfl_down(v[j], d, 16);
          if (ok) v[j] += vv;
        }
      }
      if (head){
        #pragma unroll
        for (int mf = 0; mf < 2; ++mf){
          float* ag = agg + (size_t)myrow * HH + w * 32 + mf * 16 + g * 4;
          atomicAdd(ag + 0, v[mf * 4 + 0]);
          atomicAdd(ag + 1, v[mf * 4 + 1]);
          atomicAdd(ag + 2, v[mf * 4 + 2]);
          atomicAdd(ag + 3, v[mf * 4 + 3]);
        }
      }
    }
  }
}

// ---------------- node kernel: h += MLP([h, agg]) ; agg read as bf16 ----------------
__global__ __launch_bounds__(256) void node_kernel(
    float* __restrict__ h, u16* __restrict__ hb, const u16* __restrict__ agg_bf,
    const u16* __restrict__ pw1, const u16* __restrict__ pw2,
    const float* __restrict__ b1, const float* __restrict__ b2){
  __shared__ u64 mt[4096];
  __shared__ float bias_s[512];
  const int tid = threadIdx.x;
  const int w = tid >> 6, l = tid & 63, g = l >> 4, li = l & 15;
  const int nb = blockIdx.x * 64;
  for (int i = tid; i < 512; i += 256) bias_s[i] = (i < 256) ? b1[i] : b2[i - 256];
  __syncthreads();

  const u16* hp[4]; const u16* ap[4];
  #pragma unroll
  for (int nf = 0; nf < 4; ++nf){
    int n = nb + nf * 16 + li; if (n >= NN) n = NN - 1;
    hp[nf] = hb     + (size_t)n * HH + g * 4;
    ap[nf] = agg_bf + (size_t)n * HH + g * 4;
  }
  f4v acc[4][4];
  #pragma unroll
  for (int a = 0; a < 4; ++a)
    #pragma unroll
    for (int b = 0; b < 4; ++b) acc[a][b] = (f4v){0.f,0.f,0.f,0.f};

  const u16* pw1b = pw1 + ((size_t)(w * 4) * 64 + l) * 8;
  #pragma unroll 4
  for (int kb = 0; kb < 8; ++kb){
    s8v A[4];
    #pragma unroll
    for (int mf = 0; mf < 4; ++mf) A[mf] = *(const s8v*)(pw1b + (size_t)kb * 8192 + mf * 512);
    #pragma unroll
    for (int nf = 0; nf < 4; ++nf){
      BU bu;
      bu.d[0] = *(const u64*)(hp[nf] + kb * 32);
      bu.d[1] = *(const u64*)(hp[nf] + kb * 32 + 16);
      #pragma unroll
      for (int mf = 0; mf < 4; ++mf)
        acc[mf][nf] = __builtin_amdgcn_mfma_f32_16x16x32_bf16(A[mf], bu.v, acc[mf][nf], 0, 0, 0);
    }
  }
  #pragma unroll 4
  for (int kb = 8; kb < 16; ++kb){
    s8v A[4];
    #pragma unroll
    for (int mf = 0; mf < 4; ++mf) A[mf] = *(const s8v*)(pw1b + (size_t)kb * 8192 + mf * 512);
    #pragma unroll
    for (int nf = 0; nf < 4; ++nf){
      BU bu;
      bu.d[0] = *(const u64*)(ap[nf] + (kb - 8) * 32);
      bu.d[1] = *(const u64*)(ap[nf] + (kb - 8) * 32 + 16);
      #pragma unroll
      for (int mf = 0; mf < 4; ++mf)
        acc[mf][nf] = __builtin_amdgcn_mfma_f32_16x16x32_bf16(A[mf], bu.v, acc[mf][nf], 0, 0, 0);
    }
  }
  #pragma unroll
  for (int mf = 0; mf < 4; ++mf){
    const int fb = w * 64 + mf * 16 + g * 4;
    const int fc = fb >> 2;
    #pragma unroll
    for (int nf = 0; nf < 4; ++nf){
      int e = nf * 16 + li;
      float v0 = siluf(acc[mf][nf][0] + bias_s[fb+0]);
      float v1 = siluf(acc[mf][nf][1] + bias_s[fb+1]);
      float v2 = siluf(acc[mf][nf][2] + bias_s[fb+2]);
      float v3 = siluf(acc[mf][nf][3] + bias_s[fb+3]);
      mt[e * 64 + (fc ^ (e & 7))] = pack4bf(v0, v1, v2, v3);
    }
  }
  __syncthreads();

  #pragma unroll
  for (int a = 0; a < 4; ++a)
    #pragma unroll
    for (int b = 0; b < 4; ++b) acc[a][b] = (f4v){0.f,0.f,0.f,0.f};
  const u16* pw2b = pw2 + ((size_t)(w * 4) * 64 + l) * 8;
  #pragma unroll 4
  for (int kb = 0; kb < 8; ++kb){
    s8v A[4];
    #pragma unroll
    for (int mf = 0; mf < 4; ++mf) A[mf] = *(const s8v*)(pw2b + (size_t)kb * 8192 + mf * 512);
    #pragma unroll
    for (int nf = 0; nf < 4; ++nf){
      int e = nf * 16 + li;
      BU bu;
      bu.d[0] = mt[e * 64 + ((kb * 8 + g)     ^ (e & 7))];
      bu.d[1] = mt[e * 64 + ((kb * 8 + 4 + g) ^ (e & 7))];
      #pragma unroll
      for (int mf = 0; mf < 4; ++mf)
        acc[mf][nf] = __builtin_amdgcn_mfma_f32_16x16x32_bf16(A[mf], bu.v, acc[mf][nf], 0, 0, 0);
    }
  }
  #pragma unroll
  for (int mf = 0; mf < 4; ++mf){
    const int fb = w * 64 + mf * 16 + g * 4;
    #pragma unroll
    for (int nf = 0; nf < 4; ++nf){
      int n = nb + nf * 16 + li;
      if (n < NN){
        float4 hv = *(float4*)(h + (size_t)n * HH + fb);
        float o0 = hv.x + acc[mf][nf][0] + bias_s[256+fb+0];
        float o1 = hv.y + acc[mf][nf][1] + bias_s[256+fb+1];
        float o2 = hv.z + acc[mf][nf][2] + bias_s[256+fb+2];
        float o3 = hv.w + acc[mf][nf][3] + bias_s[256+fb+3];
        *(float4*)(h + (size_t)n * HH + fb) = make_float4(o0, o1, o2, o3);
        *(u64*)(hb + (size_t)n * HH + fb) = pack4bf(o0, o1, o2, o3);
      }
    }
  }
}

// ---------------- emb_out + max-pool ----------------
__global__ __launch_bounds__(256) void emb_out_pool_kernel(
    const u16* __restrict__ hb, const u16* __restrict__ pw,
    const float* __restrict__ bias, const int* __restrict__ batch, u32* __restrict__ pooled){
  const int tid = threadIdx.x;
  const int w = tid >> 6, l = tid & 63, g = l >> 4, li = l & 15;
  const int nb = blockIdx.x * 64;
  const u16* hp[4]; int bs[4];
  #pragma unroll
  for (int nf = 0; nf < 4; ++nf){
    int n = nb + nf * 16 + li; int nc = (n >= NN) ? NN - 1 : n;
    hp[nf] = hb + (size_t)nc * HH + g * 4;
    bs[nf] = batch[nc];
  }
  f4v acc[4][4];
  #pragma unroll
  for (int a = 0; a < 4; ++a)
    #pragma unroll
    for (int b = 0; b < 4; ++b) acc[a][b] = (f4v){0.f,0.f,0.f,0.f};
  const u16* pwb = pw + ((size_t)(w * 4) * 64 + l) * 8;
  #pragma unroll 4
  for (int kb = 0; kb < 8; ++kb){
    s8v A[4];
    #pragma unroll
    for (int mf = 0; mf < 4; ++mf) A[mf] = *(const s8v*)(pwb + (size_t)kb * 8192 + mf * 512);
    #pragma unroll
    for (int nf = 0; nf < 4; ++nf){
      BU bu;
      bu.d[0] = *(const u64*)(hp[nf] + kb * 32);
      bu.d[1] = *(const u64*)(hp[nf] + kb * 32 + 16);
      #pragma unroll
      for (int mf = 0; mf < 4; ++mf)
        acc[mf][nf] = __builtin_amdgcn_mfma_f32_16x16x32_bf16(A[mf], bu.v, acc[mf][nf], 0, 0, 0);
    }
  }
  #pragma unroll
  for (int mf = 0; mf < 4; ++mf){
    const int fb = w * 64 + mf * 16 + g * 4;
    float b0 = bias[fb], b1 = bias[fb+1], b2 = bias[fb+2], b3 = bias[fb+3];
    #pragma unroll
    for (int nf = 0; nf < 4; ++nf){
      int n = nb + nf * 16 + li;
      if (n < NN){
        float vv[4] = {acc[mf][nf][0] + b0, acc[mf][nf][1] + b1, acc[mf][nf][2] + b2, acc[mf][nf][3] + b3};
        #pragma unroll
        for (int r = 0; r < 4; ++r){
          u32 u = __float_as_uint(vv[r]);
          u = (u & 0x80000000u) ? ~u : (u | 0x80000000u);
          atomicMax(&pooled[(size_t)bs[nf] * HH + fb + r], u);
        }
      }
    }
  }
}

// ---------------- resblock + head ----------------
__global__ __launch_bounds__(256) void final_kernel(
    const float* __restrict__ z, const float* __restrict__ rw1, const float* __restrict__ rb1,
    const float* __restrict__ rw2, const float* __restrict__ rb2,
    const float* __restrict__ hw, const float* __restrict__ hbs, float* __restrict__ out){
  __shared__ float zr[272], t1[256], t2[272];
  const int b = blockIdx.x, tid = threadIdx.x;
  for (int i = tid; i < 272; i += 256) zr[i] = z[(size_t)b * 272 + i];
  __syncthreads();
  {
    float a = rb1[tid];
    for (int k = 0; k < 272; ++k) a += zr[k] * rw1[(size_t)k * 256 + tid];
    t1[tid] = siluf(a);
  }
  __syncthreads();
  for (int i = tid; i < 272; i += 256){
    float a = rb2[i] + zr[i];
    for (int k = 0; k < 256; ++k) a += t1[k] * rw2[(size_t)k * 272 + i];
    t2[i] = a;
  }
  __syncthreads();
  for (int p = tid; p < 2000; p += 256){
    float a = hbs[p];
    for (int k = 0; k < 272; ++k) a += t2[k] * hw[(size_t)k * 2000 + p];
    out[(size_t)b * 2000 + p] = a;
  }
}

extern "C" void kernel_launch(void* const* d_in, const int* in_sizes, int n_in,
                              void* d_out, int out_size, void* d_ws, size_t ws_size,
                              hipStream_t stream){
  const float* x        = (const float*)d_in[0];
  const float* pos      = (const float*)d_in[1];
  const float* eattr    = (const float*)d_in[2];
  const float* fragl    = (const float*)d_in[3];
  const float* addf     = (const float*)d_in[4];
  const int*   ei       = (const int*)d_in[5];
  const int*   batch    = (const int*)d_in[6];
  const float* emb_in_w = (const float*)d_in[7];
  const float* emb_in_b = (const float*)d_in[8];
  const float* edge_w1  = (const float*)d_in[9];
  const float* edge_b1  = (const float*)d_in[10];
  const float* edge_w2  = (const float*)d_in[11];
  const float* edge_b2  = (const float*)d_in[12];
  const float* node_w1  = (const float*)d_in[13];
  const float* node_b1  = (const float*)d_in[14];
  const float* node_w2  = (const float*)d_in[15];
  const float* node_b2  = (const float*)d_in[16];
  const float* coord_w1 = (const float*)d_in[17];
  const float* coord_b1 = (const float*)d_in[18];
  const float* coord_w2 = (const float*)d_in[19];
  const float* emb_out_w= (const float*)d_in[20];
  const float* emb_out_b= (const float*)d_in[21];
  const float* res_w1   = (const float*)d_in[22];
  const float* res_b1   = (const float*)d_in[23];
  const float* res_w2   = (const float*)d_in[24];
  const float* res_b2   = (const float*)d_in[25];
  const float* head_w   = (const float*)d_in[26];
  const float* head_b   = (const float*)d_in[27];

  char* ws = (char*)d_ws;
  size_t off = 0;
  auto alloc = [&](size_t bytes) -> void* {
    void* p = ws + off;
    off += (bytes + 255) & ~(size_t)255;
    return p;
  };
  float*  h      = (float*)alloc((size_t)NN * HH * 4);
  float*  agg    = (float*)alloc((size_t)NN * HH * 4);
  u16*    agg_bf = (u16*)  alloc((size_t)NN * HH * 2);
  u16*    hb     = (u16*)  alloc((size_t)NN * HH * 2);
  float*  Pa     = (float*)alloc((size_t)NN * HH * 4);
  float*  Pb     = (float*)alloc((size_t)NN * HH * 4);
  float4* coordb = (float4*)alloc((size_t)NN * 16);
  float*  cacc   = (float*)alloc((size_t)NN * 16);
  u32*    pooled = (u32*)  alloc((size_t)BB * HH * 4);
  float*  z      = (float*)alloc((size_t)BB * 272 * 4);
  u16*    packed = (u16*)  alloc((size_t)7680 * 256 * 2);
  int*    icnt   = (int*)  alloc((size_t)NN * 4);
  int*    iscan  = (int*)  alloc((size_t)NN * 4);
  int*    rstart = (int*)  alloc((size_t)NN * 4);
  int*    cursor = (int*)  alloc((size_t)NN * 4);
  int*    bsum   = (int*)  alloc((size_t)128 * 4);
  int*    seid   = (int*)  alloc((size_t)EE * 4);
  int*    srow   = (int*)  alloc((size_t)EE * 4);
  int*    scol   = (int*)  alloc((size_t)EE * 4);
  const size_t base_off = off;
  u64*    m2g    = (u64*)  alloc((size_t)EE * HH * 2);   // 164 MB m2 stream buffer
  const bool use_stream = (off <= ws_size);
  if (base_off > ws_size) return;

  u16* pk_embin  = packed;
  u16* pk_embout = packed + 32768 + (size_t)4 * 466944;
  auto pk_ew1 = [&](int l){ return packed + 32768 + (size_t)l * 466944; };
  auto pk_ew2 = [&](int l){ return pk_ew1(l) + 139264; };
  auto pk_cw1 = [&](int l){ return pk_ew1(l) + 204800; };
  auto pk_nw1 = [&](int l){ return pk_ew1(l) + 270336; };
  auto pk_nw2 = [&](int l){ return pk_ew1(l) + 401408; };

  pack_kernel<<<16, 256, 0, stream>>>(emb_in_w, pk_embin, 128, 4);
  for (int l = 0; l < 4; ++l){
    pack_kernel<<<68, 256, 0, stream>>>(edge_w1 + (size_t)l * 529 * 256, pk_ew1(l), 529, 17);
    pack_kernel<<<32, 256, 0, stream>>>(edge_w2 + (size_t)l * 65536,     pk_ew2(l), 256, 8);
    pack_kernel<<<32, 256, 0, stream>>>(coord_w1 + (size_t)l * 65536,    pk_cw1(l), 256, 8);
    pack_kernel<<<64, 256, 0, stream>>>(node_w1 + (size_t)l * 131072,    pk_nw1(l), 512, 16);
    pack_kernel<<<32, 256, 0, stream>>>(node_w2 + (size_t)l * 65536,     pk_nw2(l), 256, 8);
  }
  pack_kernel<<<32, 256, 0, stream>>>(emb_out_w, pk_embout, 256, 8);

  // ---- one-time edge sort by row
  const int NB = (NN + 255) / 256;   // 79
  hipMemsetAsync(icnt,   0, (size_t)NN * 4, stream);
  hipMemsetAsync(cursor, 0, (size_t)NN * 4, stream);
  icnt_kernel<<<(EE + 255) / 256, 256, 0, stream>>>(ei, icnt);
  iscan_block<<<NB, 256, 0, stream>>>(icnt, iscan, bsum);
  iscan_top<<<1, 64, 0, stream>>>(bsum, NB);
  iscan_fix<<<NB, 256, 0, stream>>>(icnt, iscan, bsum, rstart);
  scatter_kernel<<<(EE + 255) / 256, 256, 0, stream>>>(ei, rstart, cursor, seid, srow, scol);

  coord_init_kernel<<<79, 256, 0, stream>>>(pos, coordb);
  emb_in_kernel<<<313, 256, 0, stream>>>(x, pk_embin, emb_in_b, h, hb);

  for (int l = 0; l < 4; ++l){
    hipMemsetAsync(cacc, 0, (size_t)NN * 16, stream);
    pab_kernel<<<313, 256, 0, stream>>>(hb, pk_ew1(l), edge_b1 + l * 256, Pa, Pb);
    if (use_stream){
      edge_kernel<true><<<5000, 512, 0, stream>>>(Pa, Pb, coordb, srow, scol, seid, eattr,
          pk_ew1(l), pk_ew2(l), pk_cw1(l),
          edge_b2 + l * 256, coord_b1 + l * 256, coord_w2 + l * 256,
          agg, cacc, m2g);
      agg_csr_kernel<<<NN, 256, 0, stream>>>((const u16*)m2g, rstart, icnt, agg_bf);
    } else {
      hipMemsetAsync(agg, 0, (size_t)NN * HH * 4, stream);
      edge_kernel<false><<<5000, 512, 0, stream>>>(Pa, Pb, coordb, srow, scol, seid, eattr,
          pk_ew1(l), pk_ew2(l), pk_cw1(l),
          edge_b2 + l * 256, coord_b1 + l * 256, coord_w2 + l * 256,
          agg, cacc, m2g);
      agg_conv_kernel<<<(NN * HH + 255) / 256, 256, 0, stream>>>(agg, agg_bf);
    }
    coord_upd_kernel<<<79, 256, 0, stream>>>(coordb, cacc, icnt);
    node_kernel<<<313, 256, 0, stream>>>(h, hb, agg_bf, pk_nw1(l), pk_nw2(l),
        node_b1 + l * 256, node_b2 + l * 256);
  }

  pool_init_kernel<<<128, 256, 0, stream>>>(pooled);
  emb_out_pool_kernel<<<313, 256, 0, stream>>>(hb, pk_embout, emb_out_b, batch, pooled);
  build_z_kernel<<<136, 256, 0, stream>>>(pooled, fragl, addf, z);
  final_kernel<<<128, 256, 0, stream>>>(z, res_w1, res_b1, res_w2, res_b2, head_w, head_b,
                                        (float*)d_out);
}

// Round 7
// 1971.412 us; speedup vs baseline: 2.8499x; 1.0697x over previous
//
#include <hip/hip_runtime.h>

typedef unsigned short u16;
typedef unsigned int   u32;
typedef unsigned long long u64;
typedef __attribute__((ext_vector_type(8))) short s8v;   // 8 bf16 (4 VGPRs) MFMA operand
typedef __attribute__((ext_vector_type(4))) float f4v;   // MFMA accumulator

#define NN 20000
#define EE 320000
#define BB 128
#define HH 256

union BU { u64 d[2]; s8v v; };

__device__ __forceinline__ u16 f2bf(float f){
  u32 u = __float_as_uint(f);
  return (u16)((u + 0x7FFFu + ((u >> 16) & 1u)) >> 16);   // RNE
}
__device__ __forceinline__ float bf2f(u16 u){ return __uint_as_float((u32)u << 16); }
__device__ __forceinline__ u32 cvt2(float a, float b){
  u32 r; asm("v_cvt_pk_bf16_f32 %0, %1, %2" : "=v"(r) : "v"(a), "v"(b)); return r;
}
__device__ __forceinline__ u64 pack4bf(float a, float b, float c, float d){
  return (u64)cvt2(a, b) | ((u64)cvt2(c, d) << 32);
}
// silu via v_rcp (1 instr) instead of full-precision divide (~9 instr); 1-ulp rcp error << bf16 rounding
__device__ __forceinline__ float siluf(float v){
  return v * __builtin_amdgcn_rcpf(1.0f + __expf(-v));
}

// ---------------- weight packing: W [K][256] f32 -> A-fragment blob (W^T), bf16 ----------------
__global__ void pack_kernel(const float* __restrict__ src, u16* __restrict__ dst, int K, int KB){
  int t = blockIdx.x * 256 + threadIdx.x;
  if (t >= KB * 1024) return;
  int lane = t & 63, mf = (t >> 6) & 15, kb = t >> 10;
  int g = lane >> 4, li = lane & 15;
  int m = mf * 16 + li;
  u16 o[8];
  #pragma unroll
  for (int j = 0; j < 8; ++j){
    int k = kb * 32 + ((j < 4) ? (g * 4 + j) : (16 + g * 4 + (j - 4)));
    o[j] = (k < K) ? f2bf(src[(size_t)k * 256 + m]) : (u16)0;
  }
  u16* d = dst + ((size_t)(kb * 16 + mf) * 64 + lane) * 8;
  *(u64*)(d)     = (u64)o[0] | ((u64)o[1] << 16) | ((u64)o[2] << 32) | ((u64)o[3] << 48);
  *(u64*)(d + 4) = (u64)o[4] | ((u64)o[5] << 16) | ((u64)o[6] << 32) | ((u64)o[7] << 48);
}

// ---------------- edge sort by destination row (one-time per launch) ----------------
__global__ void icnt_kernel(const int* __restrict__ ei, int* __restrict__ icnt){
  int t = blockIdx.x * 256 + threadIdx.x;
  if (t < EE) atomicAdd(&icnt[ei[t]], 1);
}
__global__ void iscan_block(const int* __restrict__ icnt, int* __restrict__ iscan, int* __restrict__ bsum){
  __shared__ int s[256];
  int i = blockIdx.x * 256 + threadIdx.x;
  int v = (i < NN) ? icnt[i] : 0;
  s[threadIdx.x] = v; __syncthreads();
  #pragma unroll
  for (int d = 1; d < 256; d <<= 1){
    int t = (threadIdx.x >= d) ? s[threadIdx.x - d] : 0;
    __syncthreads();
    s[threadIdx.x] += t;
    __syncthreads();
  }
  if (i < NN) iscan[i] = s[threadIdx.x];
  if (threadIdx.x == 255) bsum[blockIdx.x] = s[255];
}
__global__ void iscan_top(int* __restrict__ bsum, int nb){
  if (blockIdx.x == 0 && threadIdx.x == 0){
    int acc = 0;
    for (int i = 0; i < nb; ++i){ int t = bsum[i]; bsum[i] = acc; acc += t; }
  }
}
__global__ void iscan_fix(const int* __restrict__ icnt, const int* __restrict__ iscan,
                          const int* __restrict__ bsum, int* __restrict__ rstart){
  int i = blockIdx.x * 256 + threadIdx.x;
  if (i < NN) rstart[i] = bsum[blockIdx.x] + iscan[i] - icnt[i];
}
__global__ void scatter_kernel(const int* __restrict__ ei, const int* __restrict__ rstart,
                               int* __restrict__ cursor, int* __restrict__ seid,
                               int* __restrict__ srow, int* __restrict__ scol){
  int e = blockIdx.x * 256 + threadIdx.x;
  if (e < EE){
    int r = ei[e];
    int p = rstart[r] + atomicAdd(&cursor[r], 1);
    seid[p] = e; srow[p] = r; scol[p] = ei[EE + e];
  }
}

// ---------------- small utility kernels ----------------
__global__ void coord_init_kernel(const float* __restrict__ pos, float4* __restrict__ coord){
  int t = blockIdx.x * 256 + threadIdx.x;
  if (t < NN) coord[t] = make_float4(pos[3*t], pos[3*t+1], pos[3*t+2], 0.f);
}
__global__ void coord_upd_kernel(float4* __restrict__ coord, const float* __restrict__ cacc,
                                 const int* __restrict__ icnt){
  int t = blockIdx.x * 256 + threadIdx.x;
  if (t >= NN) return;
  float k = fmaxf((float)icnt[t], 1.0f);
  float4 c = coord[t];
  c.x += cacc[4*t+0] / k; c.y += cacc[4*t+1] / k; c.z += cacc[4*t+2] / k;
  coord[t] = c;
}
__global__ void pool_init_kernel(u32* __restrict__ pooled){
  int t = blockIdx.x * 256 + threadIdx.x;
  if (t < BB * HH){
    u32 u = __float_as_uint(-3.0e38f);
    pooled[t] = ~u;
  }
}
__global__ void build_z_kernel(const u32* __restrict__ pooled, const float* __restrict__ fragl,
                               const float* __restrict__ addf, float* __restrict__ z){
  int t = blockIdx.x * 256 + threadIdx.x;
  if (t >= BB * 272) return;
  int b = t / 272, j = t % 272;
  float v;
  if (j < 256){
    u32 u = pooled[b * 256 + j];
    v = (u & 0x80000000u) ? __uint_as_float(u & 0x7FFFFFFFu) : __uint_as_float(~u);
  } else if (j < 264) v = fragl[b * 8 + (j - 256)];
  else                v = addf[b * 8 + (j - 264)];
  z[t] = v;
}

// ---------------- CSR segment-sum: agg_bf[n][f] = bf16( sum_e m2[e][f] ) ----------------
__global__ __launch_bounds__(256) void agg_csr_kernel(
    const u16* __restrict__ m2b, const int* __restrict__ rstart,
    const int* __restrict__ icnt, u16* __restrict__ agg_bf){
  const int n = blockIdx.x, f = threadIdx.x;
  const int s = rstart[n], d = icnt[n];
  const u16* p = m2b + (size_t)s * 256 + f;
  float a0 = 0.f, a1 = 0.f;
  int i = 0;
  for (; i + 1 < d; i += 2){ a0 += bf2f(p[(size_t)i * 256]); a1 += bf2f(p[(size_t)(i + 1) * 256]); }
  if (i < d) a0 += bf2f(p[(size_t)i * 256]);
  agg_bf[(size_t)n * 256 + f] = f2bf(a0 + a1);
}
__global__ void agg_conv_kernel(const float* __restrict__ agg, u16* __restrict__ agg_bf){
  int t = blockIdx.x * 256 + threadIdx.x;
  if (t < NN * HH) agg_bf[t] = f2bf(agg[t]);
}

// ---------------- emb_in: h = x @ emb_in_w + b ----------------
__global__ __launch_bounds__(256) void emb_in_kernel(
    const float* __restrict__ x, const u16* __restrict__ pw,
    const float* __restrict__ bias, float* __restrict__ h, u16* __restrict__ hb){
  const int tid = threadIdx.x;
  const int w = tid >> 6, l = tid & 63, g = l >> 4, li = l & 15;
  const int nb = blockIdx.x * 64;
  const float* xp[4];
  #pragma unroll
  for (int nf = 0; nf < 4; ++nf){
    int n = nb + nf * 16 + li; if (n >= NN) n = NN - 1;
    xp[nf] = x + (size_t)n * 128 + g * 4;
  }
  f4v acc[4][4];
  #pragma unroll
  for (int a = 0; a < 4; ++a)
    #pragma unroll
    for (int b = 0; b < 4; ++b) acc[a][b] = (f4v){0.f,0.f,0.f,0.f};
  const u16* pwb = pw + ((size_t)(w * 4) * 64 + l) * 8;
  #pragma unroll
  for (int kb = 0; kb < 4; ++kb){
    s8v A[4];
    #pragma unroll
    for (int mf = 0; mf < 4; ++mf) A[mf] = *(const s8v*)(pwb + (size_t)kb * 8192 + mf * 512);
    #pragma unroll
    for (int nf = 0; nf < 4; ++nf){
      float4 fa = *(const float4*)(xp[nf] + kb * 32);
      float4 fb = *(const float4*)(xp[nf] + kb * 32 + 16);
      BU bu;
      bu.d[0] = pack4bf(fa.x, fa.y, fa.z, fa.w);
      bu.d[1] = pack4bf(fb.x, fb.y, fb.z, fb.w);
      #pragma unroll
      for (int mf = 0; mf < 4; ++mf)
        acc[mf][nf] = __builtin_amdgcn_mfma_f32_16x16x32_bf16(A[mf], bu.v, acc[mf][nf], 0, 0, 0);
    }
  }
  #pragma unroll
  for (int mf = 0; mf < 4; ++mf){
    const int fb = w * 64 + mf * 16 + g * 4;
    float b0 = bias[fb], b1 = bias[fb+1], b2 = bias[fb+2], b3 = bias[fb+3];
    #pragma unroll
    for (int nf = 0; nf < 4; ++nf){
      int n = nb + nf * 16 + li;
      if (n < NN){
        float o0 = acc[mf][nf][0] + b0, o1 = acc[mf][nf][1] + b1;
        float o2 = acc[mf][nf][2] + b2, o3 = acc[mf][nf][3] + b3;
        *(float4*)(h + (size_t)n * HH + fb) = make_float4(o0, o1, o2, o3);
        *(u64*)(hb + (size_t)n * HH + fb) = pack4bf(o0, o1, o2, o3);
      }
    }
  }
}

// ---------------- P_a = h@W1a + b1 ; P_b = h@W1b  (node-level GEMM, f32 out) ----------------
__global__ __launch_bounds__(256) void pab_kernel(
    const u16* __restrict__ hb, const u16* __restrict__ pw1, const float* __restrict__ b1,
    float* __restrict__ Pa, float* __restrict__ Pb){
  const int tid = threadIdx.x;
  const int w = tid >> 6, l = tid & 63, g = l >> 4, li = l & 15;
  const int nb = blockIdx.x * 64;
  const u16* hp[4];
  #pragma unroll
  for (int nf = 0; nf < 4; ++nf){
    int n = nb + nf * 16 + li; if (n >= NN) n = NN - 1;
    hp[nf] = hb + (size_t)n * HH + g * 4;
  }
  const u16* pwb = pw1 + ((size_t)(w * 4) * 64 + l) * 8;
  #pragma unroll
  for (int pass = 0; pass < 2; ++pass){
    f4v acc[4][4];
    #pragma unroll
    for (int a = 0; a < 4; ++a)
      #pragma unroll
      for (int b = 0; b < 4; ++b) acc[a][b] = (f4v){0.f,0.f,0.f,0.f};
    const u16* pwp = pwb + (size_t)(pass * 8) * 8192;   // W1a = kb 0..7, W1b = kb 8..15
    #pragma unroll 4
    for (int kb = 0; kb < 8; ++kb){
      s8v A[4];
      #pragma unroll
      for (int mf = 0; mf < 4; ++mf) A[mf] = *(const s8v*)(pwp + (size_t)kb * 8192 + mf * 512);
      #pragma unroll
      for (int nf = 0; nf < 4; ++nf){
        BU bu;
        bu.d[0] = *(const u64*)(hp[nf] + kb * 32);
        bu.d[1] = *(const u64*)(hp[nf] + kb * 32 + 16);
        #pragma unroll
        for (int mf = 0; mf < 4; ++mf)
          acc[mf][nf] = __builtin_amdgcn_mfma_f32_16x16x32_bf16(A[mf], bu.v, acc[mf][nf], 0, 0, 0);
      }
    }
    float* dst = pass ? Pb : Pa;
    #pragma unroll
    for (int mf = 0; mf < 4; ++mf){
      const int fb = w * 64 + mf * 16 + g * 4;
      float c0 = 0.f, c1 = 0.f, c2 = 0.f, c3 = 0.f;
      if (!pass){ c0 = b1[fb]; c1 = b1[fb+1]; c2 = b1[fb+2]; c3 = b1[fb+3]; }
      #pragma unroll
      for (int nf = 0; nf < 4; ++nf){
        int n = nb + nf * 16 + li;
        if (n < NN)
          *(float4*)(dst + (size_t)n * HH + fb) =
            make_float4(acc[mf][nf][0] + c0, acc[mf][nf][1] + c1,
                        acc[mf][nf][2] + c2, acc[mf][nf][3] + c3);
      }
    }
  }
}

// ---------------- edge kernel: 64 SORTED edges/block, 512 threads (8 waves x 32 feats) ----------------
// VALU-lean: all mt[] LDS accesses use precomputed per-thread bases + compile-time
// immediate offsets (XOR-swizzle distributes over the add: (s*8+g)^sw == s*8+(g^sw)).
template<bool STREAM>
__global__ __launch_bounds__(512) void edge_kernel(
    const float* __restrict__ Pa, const float* __restrict__ Pb,
    const float4* __restrict__ coord,
    const int* __restrict__ srow, const int* __restrict__ scol, const int* __restrict__ seid,
    const float* __restrict__ eattr,
    const u16* __restrict__ pw1, const u16* __restrict__ pw2, const u16* __restrict__ pw3,
    const float* __restrict__ b2, const float* __restrict__ cb1, const float* __restrict__ cw2,
    float* __restrict__ agg, float* __restrict__ cacc, u64* __restrict__ m2g){
  __shared__ u64 mt[4096];            // 32KB swizzled tile [64 edges][64 4-feat chunks]
  __shared__ float4 dif[64];
  __shared__ int rows_s[64];
  __shared__ int cols_s[64];
  __shared__ int seid_s[64];
  __shared__ float bias_s[768];       // b2 | cb1 | cw2
  __shared__ float cpart[8][64];

  const int tid = threadIdx.x;
  const int w = tid >> 6, l = tid & 63, g = l >> 4, li = l & 15;
  // 5000 blocks = 8 * 625: bijective XCD swizzle for L2 locality of sorted rows
  const int wg = (blockIdx.x & 7) * 625 + (blockIdx.x >> 3);
  const int eb = wg * 64;

  if (tid < 64){
    int sp = eb + tid;
    int r = srow[sp], c = scol[sp];
    rows_s[tid] = r; cols_s[tid] = c; seid_s[tid] = seid[sp];
    float4 ca = coord[r], cb = coord[c];
    float dx = ca.x - cb.x, dy = ca.y - cb.y, dz = ca.z - cb.z;
    float rad = dx*dx + dy*dy + dz*dz;
    dif[tid] = make_float4(dx, dy, dz, rad);
  }
  for (int i = tid; i < 768; i += 512){
    float v;
    if      (i < 256) v = b2[i];
    else if (i < 512) v = cb1[i - 256];
    else              v = cw2[i - 512];
    bias_s[i] = v;
  }
  __syncthreads();

  const float* paP[4]; const float* pbP[4];
  int rdA[4], wrA[4];                 // precomputed LDS u64-index bases per nf
  #pragma unroll
  for (int nf = 0; nf < 4; ++nf){
    int e = nf * 16 + li;
    paP[nf] = Pa + (size_t)rows_s[e] * HH;
    pbP[nf] = Pb + (size_t)cols_s[e] * HH;
    const int gsw = g ^ (e & 7);
    rdA[nf] = e * 64 + gsw;           // read lo-half base; hi-half = rdA^4
    wrA[nf] = e * 64 + w * 8 + gsw;   // write base for mf=0; mf=1 = wrA^4
  }

  // wave w owns output features w*32 .. w*32+31 (fragments mf16 = w*2, w*2+1)
  const u16* pw1b = pw1 + ((size_t)(w * 2) * 64 + l) * 8;
  const u16* pw2b = pw2 + ((size_t)(w * 2) * 64 + l) * 8;
  const u16* pw3b = pw3 + ((size_t)(w * 2) * 64 + l) * 8;

  // ---- tail k-block operands (k 512..543: radial | edge_attr | 0-pad)
  float tf[4][4];
  float rads[4];
  #pragma unroll
  for (int nf = 0; nf < 4; ++nf){
    int e = nf * 16 + li;
    const float* ep = eattr + (size_t)seid_s[e] * 16;
    if (g == 0){ tf[nf][0] = ep[0]; tf[nf][1] = ep[1]; tf[nf][2] = ep[2]; tf[nf][3] = ep[15]; }
    else { int i0 = g * 4 - 1; tf[nf][0] = ep[i0]; tf[nf][1] = ep[i0+1]; tf[nf][2] = ep[i0+2]; tf[nf][3] = ep[i0+3]; }
    rads[nf] = dif[e].w;
  }

  f4v acc[2][4];
  #pragma unroll
  for (int a = 0; a < 2; ++a)
    #pragma unroll
    for (int b = 0; b < 4; ++b) acc[a][b] = (f4v){0.f,0.f,0.f,0.f};

  // ---- tail MFMA (only remaining piece of GEMM1)
  {
    s8v at[2];
    #pragma unroll
    for (int mf = 0; mf < 2; ++mf) at[mf] = *(const s8v*)(pw1b + (size_t)16 * 8192 + mf * 512);
    #pragma unroll
    for (int nf = 0; nf < 4; ++nf){
      BU bu;
      if (g == 0){ bu.d[0] = pack4bf(rads[nf], tf[nf][0], tf[nf][1], tf[nf][2]); bu.d[1] = (u64)(cvt2(tf[nf][3], 0.f) & 0xffffu); }
      else       { bu.d[0] = pack4bf(tf[nf][0], tf[nf][1], tf[nf][2], tf[nf][3]); bu.d[1] = 0; }
      #pragma unroll
      for (int mf = 0; mf < 2; ++mf)
        acc[mf][nf] = __builtin_amdgcn_mfma_f32_16x16x32_bf16(at[mf], bu.v, acc[mf][nf], 0, 0, 0);
    }
  }

  // ---- m1 = silu(acc + Pa[row] + Pb[col])  (b1 folded into Pa)
  #pragma unroll
  for (int mf = 0; mf < 2; ++mf){
    const int fb = w * 32 + mf * 16 + g * 4;
    #pragma unroll
    for (int nf = 0; nf < 4; ++nf){
      float4 pa = *(const float4*)(paP[nf] + fb);
      float4 pb = *(const float4*)(pbP[nf] + fb);
      float v0 = siluf(acc[mf][nf][0] + pa.x + pb.x);
      float v1 = siluf(acc[mf][nf][1] + pa.y + pb.y);
      float v2 = siluf(acc[mf][nf][2] + pa.z + pb.z);
      float v3 = siluf(acc[mf][nf][3] + pa.w + pb.w);
      mt[(mf ? (wrA[nf] ^ 4) : wrA[nf])] = pack4bf(v0, v1, v2, v3);
    }
  }
  __syncthreads();

  // ---- GEMM2: m2 = silu(m1 @ W2 + b2)
  #pragma unroll
  for (int a = 0; a < 2; ++a)
    #pragma unroll
    for (int b = 0; b < 4; ++b) acc[a][b] = (f4v){0.f,0.f,0.f,0.f};
  #pragma unroll
  for (int s = 0; s < 8; ++s){
    s8v A[2];
    #pragma unroll
    for (int mf = 0; mf < 2; ++mf) A[mf] = *(const s8v*)(pw2b + (size_t)s * 8192 + mf * 512);
    #pragma unroll
    for (int nf = 0; nf < 4; ++nf){
      BU bu;
      bu.d[0] = mt[rdA[nf] + s * 8];
      bu.d[1] = mt[(rdA[nf] ^ 4) + s * 8];
      #pragma unroll
      for (int mf = 0; mf < 2; ++mf)
        acc[mf][nf] = __builtin_amdgcn_mfma_f32_16x16x32_bf16(A[mf], bu.v, acc[mf][nf], 0, 0, 0);
    }
  }
  u64 pm2[2][4];                      // m2 as packed bf16 (exactly what LDS/stream need)
  #pragma unroll
  for (int mf = 0; mf < 2; ++mf){
    const int fb = w * 32 + mf * 16 + g * 4;
    const float4 bb = *(const float4*)&bias_s[fb];
    #pragma unroll
    for (int nf = 0; nf < 4; ++nf)
      pm2[mf][nf] = pack4bf(siluf(acc[mf][nf][0] + bb.x),
                            siluf(acc[mf][nf][1] + bb.y),
                            siluf(acc[mf][nf][2] + bb.z),
                            siluf(acc[mf][nf][3] + bb.w));
  }
  __syncthreads();                    // all waves done reading m1
  #pragma unroll
  for (int mf = 0; mf < 2; ++mf)
    #pragma unroll
    for (int nf = 0; nf < 4; ++nf)
      mt[(mf ? (wrA[nf] ^ 4) : wrA[nf])] = pm2[mf][nf];
  __syncthreads();

  // ---- STREAM: coalesced write-out of m2 tile (precomputed swizzle bases)
  if (STREAM){
    u64* dst = m2g + (size_t)eb * 64 + (size_t)w * 64 + (tid & 63);
    const int sbase = w * 64 + ((tid & 63) ^ w);
    #pragma unroll
    for (int j = 0; j < 8; ++j)
      dst[j * 512] = mt[sbase + j * 512];
  }

  // ---- GEMM3: q = silu(m2 @ CW1 + cb1); c = q . cw2
  #pragma unroll
  for (int a = 0; a < 2; ++a)
    #pragma unroll
    for (int b = 0; b < 4; ++b) acc[a][b] = (f4v){0.f,0.f,0.f,0.f};
  #pragma unroll
  for (int s = 0; s < 8; ++s){
    s8v A[2];
    #pragma unroll
    for (int mf = 0; mf < 2; ++mf) A[mf] = *(const s8v*)(pw3b + (size_t)s * 8192 + mf * 512);
    #pragma unroll
    for (int nf = 0; nf < 4; ++nf){
      BU bu;
      bu.d[0] = mt[rdA[nf] + s * 8];
      bu.d[1] = mt[(rdA[nf] ^ 4) + s * 8];
      #pragma unroll
      for (int mf = 0; mf < 2; ++mf)
        acc[mf][nf] = __builtin_amdgcn_mfma_f32_16x16x32_bf16(A[mf], bu.v, acc[mf][nf], 0, 0, 0);
    }
  }
  float cp4[4] = {0.f, 0.f, 0.f, 0.f};
  #pragma unroll
  for (int mf = 0; mf < 2; ++mf){
    const int fb = w * 32 + mf * 16 + g * 4;
    const float4 cb = *(const float4*)&bias_s[256 + fb];
    const float4 cw = *(const float4*)&bias_s[512 + fb];
    #pragma unroll
    for (int nf = 0; nf < 4; ++nf){
      cp4[nf] += siluf(acc[mf][nf][0] + cb.x) * cw.x;
      cp4[nf] += siluf(acc[mf][nf][1] + cb.y) * cw.y;
      cp4[nf] += siluf(acc[mf][nf][2] + cb.z) * cw.z;
      cp4[nf] += siluf(acc[mf][nf][3] + cb.w) * cw.w;
    }
  }
  #pragma unroll
  for (int nf = 0; nf < 4; ++nf){
    float v = cp4[nf];
    v += __shfl_xor(v, 16, 64);
    v += __shfl_xor(v, 32, 64);
    if (g == 0) cpart[w][nf * 16 + li] = v;
  }
  __syncthreads();

  // ---- cacc: segmented suffix-reduce across the 64 sorted edges, head lanes atomic
  if (tid < 64){
    float c = cpart[0][tid] + cpart[1][tid] + cpart[2][tid] + cpart[3][tid]
            + cpart[4][tid] + cpart[5][tid] + cpart[6][tid] + cpart[7][tid];
    float4 d = dif[tid];
    const int myrow = rows_s[tid];
    float vx = d.x * c, vy = d.y * c, vz = d.z * c;
    #pragma unroll
    for (int dd = 1; dd < 64; dd <<= 1){
      const int rr = __shfl_down(myrow, dd, 64);
      const bool ok = ((tid + dd) < 64) && (rr == myrow);
      float tx = __shfl_down(vx, dd, 64);
      float ty = __shfl_down(vy, dd, 64);
      float tz = __shfl_down(vz, dd, 64);
      if (ok){ vx += tx; vy += ty; vz += tz; }
    }
    if (tid == 0 || rows_s[tid - 1] != myrow){
      atomicAdd(cacc + (size_t)myrow * 4 + 0, vx);
      atomicAdd(cacc + (size_t)myrow * 4 + 1, vy);
      atomicAdd(cacc + (size_t)myrow * 4 + 2, vz);
    }
  }

  // ---- fallback path only: agg via segmented suffix-reduce + atomics
  if (!STREAM){
    #pragma unroll
    for (int nf = 0; nf < 4; ++nf){
      const int myrow = rows_s[nf * 16 + li];
      const bool head = (li == 0) || (rows_s[nf * 16 + li - 1] != myrow);
      float v[8];
      #pragma unroll
      for (int mf = 0; mf < 2; ++mf)
        #pragma unroll
        for (int r = 0; r < 4; ++r) v[mf * 4 + r] = bf2f((u16)(pm2[mf][nf] >> (16 * r)));
      #pragma unroll
      for (int d = 1; d < 16; d <<= 1){
        const int rr = __shfl_down(myrow, d, 16);
        const bool ok = ((li + d) < 16) && (rr == myrow);
        #pragma unroll
        for (int j = 0; j < 8; ++j){
          const float vv = __shfl_down(v[j], d, 16);
          if (ok) v[j] += vv;
        }
      }
      if (head){
        #pragma unroll
        for (int mf = 0; mf < 2; ++mf){
          float* ag = agg + (size_t)myrow * HH + w * 32 + mf * 16 + g * 4;
          atomicAdd(ag + 0, v[mf * 4 + 0]);
          atomicAdd(ag + 1, v[mf * 4 + 1]);
          atomicAdd(ag + 2, v[mf * 4 + 2]);
          atomicAdd(ag + 3, v[mf * 4 + 3]);
        }
      }
    }
  }
}

// ---------------- node kernel: h += MLP([h, agg]) ; agg read as bf16 ----------------
__global__ __launch_bounds__(256) void node_kernel(
    float* __restrict__ h, u16* __restrict__ hb, const u16* __restrict__ agg_bf,
    const u16* __restrict__ pw1, const u16* __restrict__ pw2,
    const float* __restrict__ b1, const float* __restrict__ b2){
  __shared__ u64 mt[4096];
  __shared__ float bias_s[512];
  const int tid = threadIdx.x;
  const int w = tid >> 6, l = tid & 63, g = l >> 4, li = l & 15;
  const int nb = blockIdx.x * 64;
  for (int i = tid; i < 512; i += 256) bias_s[i] = (i < 256) ? b1[i] : b2[i - 256];
  __syncthreads();

  const u16* hp[4]; const u16* ap[4];
  int rdA[4], wrA[4];
  #pragma unroll
  for (int nf = 0; nf < 4; ++nf){
    int n = nb + nf * 16 + li; if (n >= NN) n = NN - 1;
    hp[nf] = hb     + (size_t)n * HH + g * 4;
    ap[nf] = agg_bf + (size_t)n * HH + g * 4;
    int e = nf * 16 + li;
    const int gsw = g ^ (e & 7);
    rdA[nf] = e * 64 + gsw;
    wrA[nf] = e * 64 + w * 16 + gsw;  // mf: {0:+0, 1:^4, 2:+8, 3:^4+8}
  }
  f4v acc[4][4];
  #pragma unroll
  for (int a = 0; a < 4; ++a)
    #pragma unroll
    for (int b = 0; b < 4; ++b) acc[a][b] = (f4v){0.f,0.f,0.f,0.f};

  const u16* pw1b = pw1 + ((size_t)(w * 4) * 64 + l) * 8;
  #pragma unroll 4
  for (int kb = 0; kb < 8; ++kb){
    s8v A[4];
    #pragma unroll
    for (int mf = 0; mf < 4; ++mf) A[mf] = *(const s8v*)(pw1b + (size_t)kb * 8192 + mf * 512);
    #pragma unroll
    for (int nf = 0; nf < 4; ++nf){
      BU bu;
      bu.d[0] = *(const u64*)(hp[nf] + kb * 32);
      bu.d[1] = *(const u64*)(hp[nf] + kb * 32 + 16);
      #pragma unroll
      for (int mf = 0; mf < 4; ++mf)
        acc[mf][nf] = __builtin_amdgcn_mfma_f32_16x16x32_bf16(A[mf], bu.v, acc[mf][nf], 0, 0, 0);
    }
  }
  #pragma unroll 4
  for (int kb = 8; kb < 16; ++kb){
    s8v A[4];
    #pragma unroll
    for (int mf = 0; mf < 4; ++mf) A[mf] = *(const s8v*)(pw1b + (size_t)kb * 8192 + mf * 512);
    #pragma unroll
    for (int nf = 0; nf < 4; ++nf){
      BU bu;
      bu.d[0] = *(const u64*)(ap[nf] + (kb - 8) * 32);
      bu.d[1] = *(const u64*)(ap[nf] + (kb - 8) * 32 + 16);
      #pragma unroll
      for (int mf = 0; mf < 4; ++mf)
        acc[mf][nf] = __builtin_amdgcn_mfma_f32_16x16x32_bf16(A[mf], bu.v, acc[mf][nf], 0, 0, 0);
    }
  }
  #pragma unroll
  for (int mf = 0; mf < 4; ++mf){
    const int fb = w * 64 + mf * 16 + g * 4;
    const float4 bb = *(const float4*)&bias_s[fb];
    #pragma unroll
    for (int nf = 0; nf < 4; ++nf){
      float v0 = siluf(acc[mf][nf][0] + bb.x);
      float v1 = siluf(acc[mf][nf][1] + bb.y);
      float v2 = siluf(acc[mf][nf][2] + bb.z);
      float v3 = siluf(acc[mf][nf][3] + bb.w);
      const int wr = (mf & 1 ? (wrA[nf] ^ 4) : wrA[nf]) + (mf & 2 ? 8 : 0);
      mt[wr] = pack4bf(v0, v1, v2, v3);
    }
  }
  __syncthreads();

  #pragma unroll
  for (int a = 0; a < 4; ++a)
    #pragma unroll
    for (int b = 0; b < 4; ++b) acc[a][b] = (f4v){0.f,0.f,0.f,0.f};
  const u16* pw2b = pw2 + ((size_t)(w * 4) * 64 + l) * 8;
  #pragma unroll 4
  for (int kb = 0; kb < 8; ++kb){
    s8v A[4];
    #pragma unroll
    for (int mf = 0; mf < 4; ++mf) A[mf] = *(const s8v*)(pw2b + (size_t)kb * 8192 + mf * 512);
    #pragma unroll
    for (int nf = 0; nf < 4; ++nf){
      BU bu;
      bu.d[0] = mt[rdA[nf] + kb * 8];
      bu.d[1] = mt[(rdA[nf] ^ 4) + kb * 8];
      #pragma unroll
      for (int mf = 0; mf < 4; ++mf)
        acc[mf][nf] = __builtin_amdgcn_mfma_f32_16x16x32_bf16(A[mf], bu.v, acc[mf][nf], 0, 0, 0);
    }
  }
  #pragma unroll
  for (int mf = 0; mf < 4; ++mf){
    const int fb = w * 64 + mf * 16 + g * 4;
    const float4 bb = *(const float4*)&bias_s[256 + fb];
    #pragma unroll
    for (int nf = 0; nf < 4; ++nf){
      int n = nb + nf * 16 + li;
      if (n < NN){
        float4 hv = *(float4*)(h + (size_t)n * HH + fb);
        float o0 = hv.x + acc[mf][nf][0] + bb.x;
        float o1 = hv.y + acc[mf][nf][1] + bb.y;
        float o2 = hv.z + acc[mf][nf][2] + bb.z;
        float o3 = hv.w + acc[mf][nf][3] + bb.w;
        *(float4*)(h + (size_t)n * HH + fb) = make_float4(o0, o1, o2, o3);
        *(u64*)(hb + (size_t)n * HH + fb) = pack4bf(o0, o1, o2, o3);
      }
    }
  }
}

// ---------------- emb_out + max-pool ----------------
__global__ __launch_bounds__(256) void emb_out_pool_kernel(
    const u16* __restrict__ hb, const u16* __restrict__ pw,
    const float* __restrict__ bias, const int* __restrict__ batch, u32* __restrict__ pooled){
  const int tid = threadIdx.x;
  const int w = tid >> 6, l = tid & 63, g = l >> 4, li = l & 15;
  const int nb = blockIdx.x * 64;
  const u16* hp[4]; int bs[4];
  #pragma unroll
  for (int nf = 0; nf < 4; ++nf){
    int n = nb + nf * 16 + li; int nc = (n >= NN) ? NN - 1 : n;
    hp[nf] = hb + (size_t)nc * HH + g * 4;
    bs[nf] = batch[nc];
  }
  f4v acc[4][4];
  #pragma unroll
  for (int a = 0; a < 4; ++a)
    #pragma unroll
    for (int b = 0; b < 4; ++b) acc[a][b] = (f4v){0.f,0.f,0.f,0.f};
  const u16* pwb = pw + ((size_t)(w * 4) * 64 + l) * 8;
  #pragma unroll 4
  for (int kb = 0; kb < 8; ++kb){
    s8v A[4];
    #pragma unroll
    for (int mf = 0; mf < 4; ++mf) A[mf] = *(const s8v*)(pwb + (size_t)kb * 8192 + mf * 512);
    #pragma unroll
    for (int nf = 0; nf < 4; ++nf){
      BU bu;
      bu.d[0] = *(const u64*)(hp[nf] + kb * 32);
      bu.d[1] = *(const u64*)(hp[nf] + kb * 32 + 16);
      #pragma unroll
      for (int mf = 0; mf < 4; ++mf)
        acc[mf][nf] = __builtin_amdgcn_mfma_f32_16x16x32_bf16(A[mf], bu.v, acc[mf][nf], 0, 0, 0);
    }
  }
  #pragma unroll
  for (int mf = 0; mf < 4; ++mf){
    const int fb = w * 64 + mf * 16 + g * 4;
    float b0 = bias[fb], b1 = bias[fb+1], b2 = bias[fb+2], b3 = bias[fb+3];
    #pragma unroll
    for (int nf = 0; nf < 4; ++nf){
      int n = nb + nf * 16 + li;
      if (n < NN){
        float vv[4] = {acc[mf][nf][0] + b0, acc[mf][nf][1] + b1, acc[mf][nf][2] + b2, acc[mf][nf][3] + b3};
        #pragma unroll
        for (int r = 0; r < 4; ++r){
          u32 u = __float_as_uint(vv[r]);
          u = (u & 0x80000000u) ? ~u : (u | 0x80000000u);
          atomicMax(&pooled[(size_t)bs[nf] * HH + fb + r], u);
        }
      }
    }
  }
}

// ---------------- resblock + head ----------------
__global__ __launch_bounds__(256) void final_kernel(
    const float* __restrict__ z, const float* __restrict__ rw1, const float* __restrict__ rb1,
    const float* __restrict__ rw2, const float* __restrict__ rb2,
    const float* __restrict__ hw, const float* __restrict__ hbs, float* __restrict__ out){
  __shared__ float zr[272], t1[256], t2[272];
  const int b = blockIdx.x, tid = threadIdx.x;
  for (int i = tid; i < 272; i += 256) zr[i] = z[(size_t)b * 272 + i];
  __syncthreads();
  {
    float a = rb1[tid];
    for (int k = 0; k < 272; ++k) a += zr[k] * rw1[(size_t)k * 256 + tid];
    t1[tid] = siluf(a);
  }
  __syncthreads();
  for (int i = tid; i < 272; i += 256){
    float a = rb2[i] + zr[i];
    for (int k = 0; k < 256; ++k) a += t1[k] * rw2[(size_t)k * 272 + i];
    t2[i] = a;
  }
  __syncthreads();
  for (int p = tid; p < 2000; p += 256){
    float a = hbs[p];
    for (int k = 0; k < 272; ++k) a += t2[k] * hw[(size_t)k * 2000 + p];
    out[(size_t)b * 2000 + p] = a;
  }
}

extern "C" void kernel_launch(void* const* d_in, const int* in_sizes, int n_in,
                              void* d_out, int out_size, void* d_ws, size_t ws_size,
                              hipStream_t stream){
  const float* x        = (const float*)d_in[0];
  const float* pos      = (const float*)d_in[1];
  const float* eattr    = (const float*)d_in[2];
  const float* fragl    = (const float*)d_in[3];
  const float* addf     = (const float*)d_in[4];
  const int*   ei       = (const int*)d_in[5];
  const int*   batch    = (const int*)d_in[6];
  const float* emb_in_w = (const float*)d_in[7];
  const float* emb_in_b = (const float*)d_in[8];
  const float* edge_w1  = (const float*)d_in[9];
  const float* edge_b1  = (const float*)d_in[10];
  const float* edge_w2  = (const float*)d_in[11];
  const float* edge_b2  = (const float*)d_in[12];
  const float* node_w1  = (const float*)d_in[13];
  const float* node_b1  = (const float*)d_in[14];
  const float* node_w2  = (const float*)d_in[15];
  const float* node_b2  = (const float*)d_in[16];
  const float* coord_w1 = (const float*)d_in[17];
  const float* coord_b1 = (const float*)d_in[18];
  const float* coord_w2 = (const float*)d_in[19];
  const float* emb_out_w= (const float*)d_in[20];
  const float* emb_out_b= (const float*)d_in[21];
  const float* res_w1   = (const float*)d_in[22];
  const float* res_b1   = (const float*)d_in[23];
  const float* res_w2   = (const float*)d_in[24];
  const float* res_b2   = (const float*)d_in[25];
  const float* head_w   = (const float*)d_in[26];
  const float* head_b   = (const float*)d_in[27];

  char* ws = (char*)d_ws;
  size_t off = 0;
  auto alloc = [&](size_t bytes) -> void* {
    void* p = ws + off;
    off += (bytes + 255) & ~(size_t)255;
    return p;
  };
  float*  h      = (float*)alloc((size_t)NN * HH * 4);
  float*  agg    = (float*)alloc((size_t)NN * HH * 4);
  u16*    agg_bf = (u16*)  alloc((size_t)NN * HH * 2);
  u16*    hb     = (u16*)  alloc((size_t)NN * HH * 2);
  float*  Pa     = (float*)alloc((size_t)NN * HH * 4);
  float*  Pb     = (float*)alloc((size_t)NN * HH * 4);
  float4* coordb = (float4*)alloc((size_t)NN * 16);
  float*  cacc   = (float*)alloc((size_t)NN * 16);
  u32*    pooled = (u32*)  alloc((size_t)BB * HH * 4);
  float*  z      = (float*)alloc((size_t)BB * 272 * 4);
  u16*    packed = (u16*)  alloc((size_t)7680 * 256 * 2);
  int*    icnt   = (int*)  alloc((size_t)NN * 4);
  int*    iscan  = (int*)  alloc((size_t)NN * 4);
  int*    rstart = (int*)  alloc((size_t)NN * 4);
  int*    cursor = (int*)  alloc((size_t)NN * 4);
  int*    bsum   = (int*)  alloc((size_t)128 * 4);
  int*    seid   = (int*)  alloc((size_t)EE * 4);
  int*    srow   = (int*)  alloc((size_t)EE * 4);
  int*    scol   = (int*)  alloc((size_t)EE * 4);
  const size_t base_off = off;
  u64*    m2g    = (u64*)  alloc((size_t)EE * HH * 2);   // 164 MB m2 stream buffer
  const bool use_stream = (off <= ws_size);
  if (base_off > ws_size) return;

  u16* pk_embin  = packed;
  u16* pk_embout = packed + 32768 + (size_t)4 * 466944;
  auto pk_ew1 = [&](int l){ return packed + 32768 + (size_t)l * 466944; };
  auto pk_ew2 = [&](int l){ return pk_ew1(l) + 139264; };
  auto pk_cw1 = [&](int l){ return pk_ew1(l) + 204800; };
  auto pk_nw1 = [&](int l){ return pk_ew1(l) + 270336; };
  auto pk_nw2 = [&](int l){ return pk_ew1(l) + 401408; };

  pack_kernel<<<16, 256, 0, stream>>>(emb_in_w, pk_embin, 128, 4);
  for (int l = 0; l < 4; ++l){
    pack_kernel<<<68, 256, 0, stream>>>(edge_w1 + (size_t)l * 529 * 256, pk_ew1(l), 529, 17);
    pack_kernel<<<32, 256, 0, stream>>>(edge_w2 + (size_t)l * 65536,     pk_ew2(l), 256, 8);
    pack_kernel<<<32, 256, 0, stream>>>(coord_w1 + (size_t)l * 65536,    pk_cw1(l), 256, 8);
    pack_kernel<<<64, 256, 0, stream>>>(node_w1 + (size_t)l * 131072,    pk_nw1(l), 512, 16);
    pack_kernel<<<32, 256, 0, stream>>>(node_w2 + (size_t)l * 65536,     pk_nw2(l), 256, 8);
  }
  pack_kernel<<<32, 256, 0, stream>>>(emb_out_w, pk_embout, 256, 8);

  // ---- one-time edge sort by row
  const int NB = (NN + 255) / 256;   // 79
  hipMemsetAsync(icnt,   0, (size_t)NN * 4, stream);
  hipMemsetAsync(cursor, 0, (size_t)NN * 4, stream);
  icnt_kernel<<<(EE + 255) / 256, 256, 0, stream>>>(ei, icnt);
  iscan_block<<<NB, 256, 0, stream>>>(icnt, iscan, bsum);
  iscan_top<<<1, 64, 0, stream>>>(bsum, NB);
  iscan_fix<<<NB, 256, 0, stream>>>(icnt, iscan, bsum, rstart);
  scatter_kernel<<<(EE + 255) / 256, 256, 0, stream>>>(ei, rstart, cursor, seid, srow, scol);

  coord_init_kernel<<<79, 256, 0, stream>>>(pos, coordb);
  emb_in_kernel<<<313, 256, 0, stream>>>(x, pk_embin, emb_in_b, h, hb);

  for (int l = 0; l < 4; ++l){
    hipMemsetAsync(cacc, 0, (size_t)NN * 16, stream);
    pab_kernel<<<313, 256, 0, stream>>>(hb, pk_ew1(l), edge_b1 + l * 256, Pa, Pb);
    if (use_stream){
      edge_kernel<true><<<5000, 512, 0, stream>>>(Pa, Pb, coordb, srow, scol, seid, eattr,
          pk_ew1(l), pk_ew2(l), pk_cw1(l),
          edge_b2 + l * 256, coord_b1 + l * 256, coord_w2 + l * 256,
          agg, cacc, m2g);
      agg_csr_kernel<<<NN, 256, 0, stream>>>((const u16*)m2g, rstart, icnt, agg_bf);
    } else {
      hipMemsetAsync(agg, 0, (size_t)NN * HH * 4, stream);
      edge_kernel<false><<<5000, 512, 0, stream>>>(Pa, Pb, coordb, srow, scol, seid, eattr,
          pk_ew1(l), pk_ew2(l), pk_cw1(l),
          edge_b2 + l * 256, coord_b1 + l * 256, coord_w2 + l * 256,
          agg, cacc, m2g);
      agg_conv_kernel<<<(NN * HH + 255) / 256, 256, 0, stream>>>(agg, agg_bf);
    }
    coord_upd_kernel<<<79, 256, 0, stream>>>(coordb, cacc, icnt);
    node_kernel<<<313, 256, 0, stream>>>(h, hb, agg_bf, pk_nw1(l), pk_nw2(l),
        node_b1 + l * 256, node_b2 + l * 256);
  }

  pool_init_kernel<<<128, 256, 0, stream>>>(pooled);
  emb_out_pool_kernel<<<313, 256, 0, stream>>>(hb, pk_embout, emb_out_b, batch, pooled);
  build_z_kernel<<<136, 256, 0, stream>>>(pooled, fragl, addf, z);
  final_kernel<<<128, 256, 0, stream>>>(z, res_w1, res_b1, res_w2, res_b2, head_w, head_b,
                                        (float*)d_out);
}

// Round 8
// 1711.349 us; speedup vs baseline: 3.2830x; 1.1520x over previous
//
#include <hip/hip_runtime.h>

typedef unsigned short u16;
typedef unsigned int   u32;
typedef unsigned long long u64;
typedef __attribute__((ext_vector_type(8))) short s8v;   // 8 bf16 (4 VGPRs) MFMA operand
typedef __attribute__((ext_vector_type(4))) float f4v;   // MFMA accumulator

#define NN 20000
#define EE 320000
#define BB 128
#define HH 256

union BU { u64 d[2]; s8v v; };

__device__ __forceinline__ u16 f2bf(float f){
  u32 u = __float_as_uint(f);
  return (u16)((u + 0x7FFFu + ((u >> 16) & 1u)) >> 16);   // RNE
}
__device__ __forceinline__ float bf2f(u16 u){ return __uint_as_float((u32)u << 16); }
__device__ __forceinline__ u32 cvt2(float a, float b){
  u32 r; asm("v_cvt_pk_bf16_f32 %0, %1, %2" : "=v"(r) : "v"(a), "v"(b)); return r;
}
__device__ __forceinline__ u64 pack4bf(float a, float b, float c, float d){
  return (u64)cvt2(a, b) | ((u64)cvt2(c, d) << 32);
}
// silu via v_rcp (1 instr) instead of full-precision divide (~9 instr); 1-ulp rcp error << bf16 rounding
__device__ __forceinline__ float siluf(float v){
  return v * __builtin_amdgcn_rcpf(1.0f + __expf(-v));
}

// ---------------- weight packing: W [K][256] f32 -> A-fragment blob (W^T), bf16 ----------------
__global__ void pack_kernel(const float* __restrict__ src, u16* __restrict__ dst, int K, int KB){
  int t = blockIdx.x * 256 + threadIdx.x;
  if (t >= KB * 1024) return;
  int lane = t & 63, mf = (t >> 6) & 15, kb = t >> 10;
  int g = lane >> 4, li = lane & 15;
  int m = mf * 16 + li;
  u16 o[8];
  #pragma unroll
  for (int j = 0; j < 8; ++j){
    int k = kb * 32 + ((j < 4) ? (g * 4 + j) : (16 + g * 4 + (j - 4)));
    o[j] = (k < K) ? f2bf(src[(size_t)k * 256 + m]) : (u16)0;
  }
  u16* d = dst + ((size_t)(kb * 16 + mf) * 64 + lane) * 8;
  *(u64*)(d)     = (u64)o[0] | ((u64)o[1] << 16) | ((u64)o[2] << 32) | ((u64)o[3] << 48);
  *(u64*)(d + 4) = (u64)o[4] | ((u64)o[5] << 16) | ((u64)o[6] << 32) | ((u64)o[7] << 48);
}

// ---------------- edge sort by destination row (one-time per launch) ----------------
__global__ void icnt_kernel(const int* __restrict__ ei, int* __restrict__ icnt){
  int t = blockIdx.x * 256 + threadIdx.x;
  if (t < EE) atomicAdd(&icnt[ei[t]], 1);
}
__global__ void iscan_block(const int* __restrict__ icnt, int* __restrict__ iscan, int* __restrict__ bsum){
  __shared__ int s[256];
  int i = blockIdx.x * 256 + threadIdx.x;
  int v = (i < NN) ? icnt[i] : 0;
  s[threadIdx.x] = v; __syncthreads();
  #pragma unroll
  for (int d = 1; d < 256; d <<= 1){
    int t = (threadIdx.x >= d) ? s[threadIdx.x - d] : 0;
    __syncthreads();
    s[threadIdx.x] += t;
    __syncthreads();
  }
  if (i < NN) iscan[i] = s[threadIdx.x];
  if (threadIdx.x == 255) bsum[blockIdx.x] = s[255];
}
__global__ void iscan_top(int* __restrict__ bsum, int nb){
  if (blockIdx.x == 0 && threadIdx.x == 0){
    int acc = 0;
    for (int i = 0; i < nb; ++i){ int t = bsum[i]; bsum[i] = acc; acc += t; }
  }
}
__global__ void iscan_fix(const int* __restrict__ icnt, const int* __restrict__ iscan,
                          const int* __restrict__ bsum, int* __restrict__ rstart){
  int i = blockIdx.x * 256 + threadIdx.x;
  if (i < NN) rstart[i] = bsum[blockIdx.x] + iscan[i] - icnt[i];
}
__global__ void scatter_kernel(const int* __restrict__ ei, const int* __restrict__ rstart,
                               int* __restrict__ cursor, int* __restrict__ seid,
                               int* __restrict__ srow, int* __restrict__ scol){
  int e = blockIdx.x * 256 + threadIdx.x;
  if (e < EE){
    int r = ei[e];
    int p = rstart[r] + atomicAdd(&cursor[r], 1);
    seid[p] = e; srow[p] = r; scol[p] = ei[EE + e];
  }
}
// per-graph node ranges from the SORTED batch array (run once)
__global__ void bstart_kernel(const int* __restrict__ batch, int* __restrict__ bstart){
  int n = blockIdx.x * 256 + threadIdx.x;
  if (n >= NN) return;
  int b = batch[n];
  if (n == 0){ for (int x = 0; x <= b; ++x) bstart[x] = 0; }
  else {
    int pb = batch[n - 1];
    for (int x = pb + 1; x <= b; ++x) bstart[x] = n;
  }
  if (n == NN - 1) bstart[BB] = NN;
}

// ---------------- small utility kernels ----------------
__global__ void coord_init_kernel(const float* __restrict__ pos, float4* __restrict__ coord){
  int t = blockIdx.x * 256 + threadIdx.x;
  if (t < NN) coord[t] = make_float4(pos[3*t], pos[3*t+1], pos[3*t+2], 0.f);
}
__global__ void coord_upd_kernel(float4* __restrict__ coord, const float* __restrict__ cacc,
                                 const int* __restrict__ icnt){
  int t = blockIdx.x * 256 + threadIdx.x;
  if (t >= NN) return;
  float k = fmaxf((float)icnt[t], 1.0f);
  float4 c = coord[t];
  c.x += cacc[4*t+0] / k; c.y += cacc[4*t+1] / k; c.z += cacc[4*t+2] / k;
  coord[t] = c;
}

// ---------------- CSR segment-sum: agg_bf[n][f] = bf16( sum_e m2[e][f] ) ----------------
__global__ __launch_bounds__(256) void agg_csr_kernel(
    const u16* __restrict__ m2b, const int* __restrict__ rstart,
    const int* __restrict__ icnt, u16* __restrict__ agg_bf){
  const int n = blockIdx.x, f = threadIdx.x;
  const int s = rstart[n], d = icnt[n];
  const u16* p = m2b + (size_t)s * 256 + f;
  float a0 = 0.f, a1 = 0.f;
  int i = 0;
  for (; i + 1 < d; i += 2){ a0 += bf2f(p[(size_t)i * 256]); a1 += bf2f(p[(size_t)(i + 1) * 256]); }
  if (i < d) a0 += bf2f(p[(size_t)i * 256]);
  agg_bf[(size_t)n * 256 + f] = f2bf(a0 + a1);
}
__global__ void agg_conv_kernel(const float* __restrict__ agg, u16* __restrict__ agg_bf){
  int t = blockIdx.x * 256 + threadIdx.x;
  if (t < NN * HH) agg_bf[t] = f2bf(agg[t]);
}

// ---------------- emb_in: h = x @ emb_in_w + b ----------------
__global__ __launch_bounds__(256) void emb_in_kernel(
    const float* __restrict__ x, const u16* __restrict__ pw,
    const float* __restrict__ bias, float* __restrict__ h, u16* __restrict__ hb){
  const int tid = threadIdx.x;
  const int w = tid >> 6, l = tid & 63, g = l >> 4, li = l & 15;
  const int nb = blockIdx.x * 64;
  const float* xp[4];
  #pragma unroll
  for (int nf = 0; nf < 4; ++nf){
    int n = nb + nf * 16 + li; if (n >= NN) n = NN - 1;
    xp[nf] = x + (size_t)n * 128 + g * 4;
  }
  f4v acc[4][4];
  #pragma unroll
  for (int a = 0; a < 4; ++a)
    #pragma unroll
    for (int b = 0; b < 4; ++b) acc[a][b] = (f4v){0.f,0.f,0.f,0.f};
  const u16* pwb = pw + ((size_t)(w * 4) * 64 + l) * 8;
  #pragma unroll
  for (int kb = 0; kb < 4; ++kb){
    s8v A[4];
    #pragma unroll
    for (int mf = 0; mf < 4; ++mf) A[mf] = *(const s8v*)(pwb + (size_t)kb * 8192 + mf * 512);
    #pragma unroll
    for (int nf = 0; nf < 4; ++nf){
      float4 fa = *(const float4*)(xp[nf] + kb * 32);
      float4 fb = *(const float4*)(xp[nf] + kb * 32 + 16);
      BU bu;
      bu.d[0] = pack4bf(fa.x, fa.y, fa.z, fa.w);
      bu.d[1] = pack4bf(fb.x, fb.y, fb.z, fb.w);
      #pragma unroll
      for (int mf = 0; mf < 4; ++mf)
        acc[mf][nf] = __builtin_amdgcn_mfma_f32_16x16x32_bf16(A[mf], bu.v, acc[mf][nf], 0, 0, 0);
    }
  }
  #pragma unroll
  for (int mf = 0; mf < 4; ++mf){
    const int fb = w * 64 + mf * 16 + g * 4;
    float b0 = bias[fb], b1 = bias[fb+1], b2 = bias[fb+2], b3 = bias[fb+3];
    #pragma unroll
    for (int nf = 0; nf < 4; ++nf){
      int n = nb + nf * 16 + li;
      if (n < NN){
        float o0 = acc[mf][nf][0] + b0, o1 = acc[mf][nf][1] + b1;
        float o2 = acc[mf][nf][2] + b2, o3 = acc[mf][nf][3] + b3;
        *(float4*)(h + (size_t)n * HH + fb) = make_float4(o0, o1, o2, o3);
        *(u64*)(hb + (size_t)n * HH + fb) = pack4bf(o0, o1, o2, o3);
      }
    }
  }
}

// ---------------- P_a = h@W1a + b1 ; P_b = h@W1b  (node-level GEMM, f32 out) ----------------
__global__ __launch_bounds__(256) void pab_kernel(
    const u16* __restrict__ hb, const u16* __restrict__ pw1, const float* __restrict__ b1,
    float* __restrict__ Pa, float* __restrict__ Pb){
  const int tid = threadIdx.x;
  const int w = tid >> 6, l = tid & 63, g = l >> 4, li = l & 15;
  const int nb = blockIdx.x * 64;
  const u16* hp[4];
  #pragma unroll
  for (int nf = 0; nf < 4; ++nf){
    int n = nb + nf * 16 + li; if (n >= NN) n = NN - 1;
    hp[nf] = hb + (size_t)n * HH + g * 4;
  }
  const u16* pwb = pw1 + ((size_t)(w * 4) * 64 + l) * 8;
  #pragma unroll
  for (int pass = 0; pass < 2; ++pass){
    f4v acc[4][4];
    #pragma unroll
    for (int a = 0; a < 4; ++a)
      #pragma unroll
      for (int b = 0; b < 4; ++b) acc[a][b] = (f4v){0.f,0.f,0.f,0.f};
    const u16* pwp = pwb + (size_t)(pass * 8) * 8192;   // W1a = kb 0..7, W1b = kb 8..15
    #pragma unroll 4
    for (int kb = 0; kb < 8; ++kb){
      s8v A[4];
      #pragma unroll
      for (int mf = 0; mf < 4; ++mf) A[mf] = *(const s8v*)(pwp + (size_t)kb * 8192 + mf * 512);
      #pragma unroll
      for (int nf = 0; nf < 4; ++nf){
        BU bu;
        bu.d[0] = *(const u64*)(hp[nf] + kb * 32);
        bu.d[1] = *(const u64*)(hp[nf] + kb * 32 + 16);
        #pragma unroll
        for (int mf = 0; mf < 4; ++mf)
          acc[mf][nf] = __builtin_amdgcn_mfma_f32_16x16x32_bf16(A[mf], bu.v, acc[mf][nf], 0, 0, 0);
      }
    }
    float* dst = pass ? Pb : Pa;
    #pragma unroll
    for (int mf = 0; mf < 4; ++mf){
      const int fb = w * 64 + mf * 16 + g * 4;
      float c0 = 0.f, c1 = 0.f, c2 = 0.f, c3 = 0.f;
      if (!pass){ c0 = b1[fb]; c1 = b1[fb+1]; c2 = b1[fb+2]; c3 = b1[fb+3]; }
      #pragma unroll
      for (int nf = 0; nf < 4; ++nf){
        int n = nb + nf * 16 + li;
        if (n < NN)
          *(float4*)(dst + (size_t)n * HH + fb) =
            make_float4(acc[mf][nf][0] + c0, acc[mf][nf][1] + c1,
                        acc[mf][nf][2] + c2, acc[mf][nf][3] + c3);
      }
    }
  }
}

// ---------------- emb_out: ho = h @ emb_out_w + b  (f32 out, no atomics) ----------------
__global__ __launch_bounds__(256) void emb_out_kernel(
    const u16* __restrict__ hb, const u16* __restrict__ pw,
    const float* __restrict__ bias, float* __restrict__ ho){
  const int tid = threadIdx.x;
  const int w = tid >> 6, l = tid & 63, g = l >> 4, li = l & 15;
  const int nb = blockIdx.x * 64;
  const u16* hp[4];
  #pragma unroll
  for (int nf = 0; nf < 4; ++nf){
    int n = nb + nf * 16 + li; if (n >= NN) n = NN - 1;
    hp[nf] = hb + (size_t)n * HH + g * 4;
  }
  f4v acc[4][4];
  #pragma unroll
  for (int a = 0; a < 4; ++a)
    #pragma unroll
    for (int b = 0; b < 4; ++b) acc[a][b] = (f4v){0.f,0.f,0.f,0.f};
  const u16* pwb = pw + ((size_t)(w * 4) * 64 + l) * 8;
  #pragma unroll 4
  for (int kb = 0; kb < 8; ++kb){
    s8v A[4];
    #pragma unroll
    for (int mf = 0; mf < 4; ++mf) A[mf] = *(const s8v*)(pwb + (size_t)kb * 8192 + mf * 512);
    #pragma unroll
    for (int nf = 0; nf < 4; ++nf){
      BU bu;
      bu.d[0] = *(const u64*)(hp[nf] + kb * 32);
      bu.d[1] = *(const u64*)(hp[nf] + kb * 32 + 16);
      #pragma unroll
      for (int mf = 0; mf < 4; ++mf)
        acc[mf][nf] = __builtin_amdgcn_mfma_f32_16x16x32_bf16(A[mf], bu.v, acc[mf][nf], 0, 0, 0);
    }
  }
  #pragma unroll
  for (int mf = 0; mf < 4; ++mf){
    const int fb = w * 64 + mf * 16 + g * 4;
    float b0 = bias[fb], b1 = bias[fb+1], b2 = bias[fb+2], b3 = bias[fb+3];
    #pragma unroll
    for (int nf = 0; nf < 4; ++nf){
      int n = nb + nf * 16 + li;
      if (n < NN)
        *(float4*)(ho + (size_t)n * HH + fb) =
          make_float4(acc[mf][nf][0] + b0, acc[mf][nf][1] + b1,
                      acc[mf][nf][2] + b2, acc[mf][nf][3] + b3);
    }
  }
}

// ---------------- max-pool over contiguous per-graph node ranges + build z ----------------
// grid = BB*4 blocks of 64 threads; block (b, q) handles features q*64..q*64+63 of graph b.
__global__ __launch_bounds__(64) void pool_csr_kernel(
    const float* __restrict__ ho, const int* __restrict__ bstart,
    const float* __restrict__ fragl, const float* __restrict__ addf, float* __restrict__ z){
  const int b = blockIdx.x >> 2, q = blockIdx.x & 3;
  const int f = q * 64 + threadIdx.x;
  const int s = bstart[b], e = bstart[b + 1];
  const float* p = ho + (size_t)s * HH + f;
  float m0 = -3.0e38f, m1 = -3.0e38f;
  int n = s;
  for (; n + 1 < e; n += 2){ m0 = fmaxf(m0, p[0]); m1 = fmaxf(m1, p[HH]); p += 2 * HH; }
  if (n < e) m0 = fmaxf(m0, p[0]);
  z[(size_t)b * 272 + f] = fmaxf(m0, m1);
  if (q == 0 && threadIdx.x < 16){
    int j = threadIdx.x;
    float v = (j < 8) ? fragl[b * 8 + j] : addf[b * 8 + (j - 8)];
    z[(size_t)b * 272 + 256 + j] = v;
  }
}

// ---------------- edge kernel: 64 SORTED edges/block, 512 threads (8 waves x 32 feats) ----------------
template<bool STREAM>
__global__ __launch_bounds__(512) void edge_kernel(
    const float* __restrict__ Pa, const float* __restrict__ Pb,
    const float4* __restrict__ coord,
    const int* __restrict__ srow, const int* __restrict__ scol, const int* __restrict__ seid,
    const float* __restrict__ eattr,
    const u16* __restrict__ pw1, const u16* __restrict__ pw2, const u16* __restrict__ pw3,
    const float* __restrict__ b2, const float* __restrict__ cb1, const float* __restrict__ cw2,
    float* __restrict__ agg, float* __restrict__ cacc, u64* __restrict__ m2g){
  __shared__ u64 mt[4096];            // 32KB swizzled tile [64 edges][64 4-feat chunks]
  __shared__ float4 dif[64];
  __shared__ int rows_s[64];
  __shared__ int cols_s[64];
  __shared__ int seid_s[64];
  __shared__ float bias_s[768];       // b2 | cb1 | cw2
  __shared__ float cpart[8][64];

  const int tid = threadIdx.x;
  const int w = tid >> 6, l = tid & 63, g = l >> 4, li = l & 15;
  const int wg = (blockIdx.x & 7) * 625 + (blockIdx.x >> 3);
  const int eb = wg * 64;

  if (tid < 64){
    int sp = eb + tid;
    int r = srow[sp], c = scol[sp];
    rows_s[tid] = r; cols_s[tid] = c; seid_s[tid] = seid[sp];
    float4 ca = coord[r], cb = coord[c];
    float dx = ca.x - cb.x, dy = ca.y - cb.y, dz = ca.z - cb.z;
    float rad = dx*dx + dy*dy + dz*dz;
    dif[tid] = make_float4(dx, dy, dz, rad);
  }
  for (int i = tid; i < 768; i += 512){
    float v;
    if      (i < 256) v = b2[i];
    else if (i < 512) v = cb1[i - 256];
    else              v = cw2[i - 512];
    bias_s[i] = v;
  }
  __syncthreads();

  const float* paP[4]; const float* pbP[4];
  int rdA[4], wrA[4];                 // precomputed LDS u64-index bases per nf
  #pragma unroll
  for (int nf = 0; nf < 4; ++nf){
    int e = nf * 16 + li;
    paP[nf] = Pa + (size_t)rows_s[e] * HH;
    pbP[nf] = Pb + (size_t)cols_s[e] * HH;
    const int gsw = g ^ (e & 7);
    rdA[nf] = e * 64 + gsw;           // read lo-half base; hi-half = rdA^4
    wrA[nf] = e * 64 + w * 8 + gsw;   // write base for mf=0; mf=1 = wrA^4
  }

  const u16* pw1b = pw1 + ((size_t)(w * 2) * 64 + l) * 8;
  const u16* pw2b = pw2 + ((size_t)(w * 2) * 64 + l) * 8;
  const u16* pw3b = pw3 + ((size_t)(w * 2) * 64 + l) * 8;

  // ---- tail k-block operands (k 512..543: radial | edge_attr | 0-pad)
  float tf[4][4];
  float rads[4];
  #pragma unroll
  for (int nf = 0; nf < 4; ++nf){
    int e = nf * 16 + li;
    const float* ep = eattr + (size_t)seid_s[e] * 16;
    if (g == 0){ tf[nf][0] = ep[0]; tf[nf][1] = ep[1]; tf[nf][2] = ep[2]; tf[nf][3] = ep[15]; }
    else { int i0 = g * 4 - 1; tf[nf][0] = ep[i0]; tf[nf][1] = ep[i0+1]; tf[nf][2] = ep[i0+2]; tf[nf][3] = ep[i0+3]; }
    rads[nf] = dif[e].w;
  }

  f4v acc[2][4];
  #pragma unroll
  for (int a = 0; a < 2; ++a)
    #pragma unroll
    for (int b = 0; b < 4; ++b) acc[a][b] = (f4v){0.f,0.f,0.f,0.f};

  // ---- tail MFMA (only remaining piece of GEMM1)
  {
    s8v at[2];
    #pragma unroll
    for (int mf = 0; mf < 2; ++mf) at[mf] = *(const s8v*)(pw1b + (size_t)16 * 8192 + mf * 512);
    #pragma unroll
    for (int nf = 0; nf < 4; ++nf){
      BU bu;
      if (g == 0){ bu.d[0] = pack4bf(rads[nf], tf[nf][0], tf[nf][1], tf[nf][2]); bu.d[1] = (u64)(cvt2(tf[nf][3], 0.f) & 0xffffu); }
      else       { bu.d[0] = pack4bf(tf[nf][0], tf[nf][1], tf[nf][2], tf[nf][3]); bu.d[1] = 0; }
      #pragma unroll
      for (int mf = 0; mf < 2; ++mf)
        acc[mf][nf] = __builtin_amdgcn_mfma_f32_16x16x32_bf16(at[mf], bu.v, acc[mf][nf], 0, 0, 0);
    }
  }

  // ---- m1 = silu(acc + Pa[row] + Pb[col])  (b1 folded into Pa)
  #pragma unroll
  for (int mf = 0; mf < 2; ++mf){
    const int fb = w * 32 + mf * 16 + g * 4;
    #pragma unroll
    for (int nf = 0; nf < 4; ++nf){
      float4 pa = *(const float4*)(paP[nf] + fb);
      float4 pb = *(const float4*)(pbP[nf] + fb);
      float v0 = siluf(acc[mf][nf][0] + pa.x + pb.x);
      float v1 = siluf(acc[mf][nf][1] + pa.y + pb.y);
      float v2 = siluf(acc[mf][nf][2] + pa.z + pb.z);
      float v3 = siluf(acc[mf][nf][3] + pa.w + pb.w);
      mt[(mf ? (wrA[nf] ^ 4) : wrA[nf])] = pack4bf(v0, v1, v2, v3);
    }
  }
  __syncthreads();

  // ---- GEMM2: m2 = silu(m1 @ W2 + b2)
  #pragma unroll
  for (int a = 0; a < 2; ++a)
    #pragma unroll
    for (int b = 0; b < 4; ++b) acc[a][b] = (f4v){0.f,0.f,0.f,0.f};
  #pragma unroll
  for (int s = 0; s < 8; ++s){
    s8v A[2];
    #pragma unroll
    for (int mf = 0; mf < 2; ++mf) A[mf] = *(const s8v*)(pw2b + (size_t)s * 8192 + mf * 512);
    #pragma unroll
    for (int nf = 0; nf < 4; ++nf){
      BU bu;
      bu.d[0] = mt[rdA[nf] + s * 8];
      bu.d[1] = mt[(rdA[nf] ^ 4) + s * 8];
      #pragma unroll
      for (int mf = 0; mf < 2; ++mf)
        acc[mf][nf] = __builtin_amdgcn_mfma_f32_16x16x32_bf16(A[mf], bu.v, acc[mf][nf], 0, 0, 0);
    }
  }
  u64 pm2[2][4];
  #pragma unroll
  for (int mf = 0; mf < 2; ++mf){
    const int fb = w * 32 + mf * 16 + g * 4;
    const float4 bb = *(const float4*)&bias_s[fb];
    #pragma unroll
    for (int nf = 0; nf < 4; ++nf)
      pm2[mf][nf] = pack4bf(siluf(acc[mf][nf][0] + bb.x),
                            siluf(acc[mf][nf][1] + bb.y),
                            siluf(acc[mf][nf][2] + bb.z),
                            siluf(acc[mf][nf][3] + bb.w));
  }
  __syncthreads();                    // all waves done reading m1
  #pragma unroll
  for (int mf = 0; mf < 2; ++mf)
    #pragma unroll
    for (int nf = 0; nf < 4; ++nf)
      mt[(mf ? (wrA[nf] ^ 4) : wrA[nf])] = pm2[mf][nf];
  __syncthreads();

  // ---- STREAM: coalesced write-out of m2 tile (precomputed swizzle bases)
  if (STREAM){
    u64* dst = m2g + (size_t)eb * 64 + (size_t)w * 64 + (tid & 63);
    const int sbase = w * 64 + ((tid & 63) ^ w);
    #pragma unroll
    for (int j = 0; j < 8; ++j)
      dst[j * 512] = mt[sbase + j * 512];
  }

  // ---- GEMM3: q = silu(m2 @ CW1 + cb1); c = q . cw2
  #pragma unroll
  for (int a = 0; a < 2; ++a)
    #pragma unroll
    for (int b = 0; b < 4; ++b) acc[a][b] = (f4v){0.f,0.f,0.f,0.f};
  #pragma unroll
  for (int s = 0; s < 8; ++s){
    s8v A[2];
    #pragma unroll
    for (int mf = 0; mf < 2; ++mf) A[mf] = *(const s8v*)(pw3b + (size_t)s * 8192 + mf * 512);
    #pragma unroll
    for (int nf = 0; nf < 4; ++nf){
      BU bu;
      bu.d[0] = mt[rdA[nf] + s * 8];
      bu.d[1] = mt[(rdA[nf] ^ 4) + s * 8];
      #pragma unroll
      for (int mf = 0; mf < 2; ++mf)
        acc[mf][nf] = __builtin_amdgcn_mfma_f32_16x16x32_bf16(A[mf], bu.v, acc[mf][nf], 0, 0, 0);
    }
  }
  float cp4[4] = {0.f, 0.f, 0.f, 0.f};
  #pragma unroll
  for (int mf = 0; mf < 2; ++mf){
    const int fb = w * 32 + mf * 16 + g * 4;
    const float4 cb = *(const float4*)&bias_s[256 + fb];
    const float4 cw = *(const float4*)&bias_s[512 + fb];
    #pragma unroll
    for (int nf = 0; nf < 4; ++nf){
      cp4[nf] += siluf(acc[mf][nf][0] + cb.x) * cw.x;
      cp4[nf] += siluf(acc[mf][nf][1] + cb.y) * cw.y;
      cp4[nf] += siluf(acc[mf][nf][2] + cb.z) * cw.z;
      cp4[nf] += siluf(acc[mf][nf][3] + cb.w) * cw.w;
    }
  }
  #pragma unroll
  for (int nf = 0; nf < 4; ++nf){
    float v = cp4[nf];
    v += __shfl_xor(v, 16, 64);
    v += __shfl_xor(v, 32, 64);
    if (g == 0) cpart[w][nf * 16 + li] = v;
  }
  __syncthreads();

  // ---- cacc: segmented suffix-reduce across the 64 sorted edges, head lanes atomic
  if (tid < 64){
    float c = cpart[0][tid] + cpart[1][tid] + cpart[2][tid] + cpart[3][tid]
            + cpart[4][tid] + cpart[5][tid] + cpart[6][tid] + cpart[7][tid];
    float4 d = dif[tid];
    const int myrow = rows_s[tid];
    float vx = d.x * c, vy = d.y * c, vz = d.z * c;
    #pragma unroll
    for (int dd = 1; dd < 64; dd <<= 1){
      const int rr = __shfl_down(myrow, dd, 64);
      const bool ok = ((tid + dd) < 64) && (rr == myrow);
      float tx = __shfl_down(vx, dd, 64);
      float ty = __shfl_down(vy, dd, 64);
      float tz = __shfl_down(vz, dd, 64);
      if (ok){ vx += tx; vy += ty; vz += tz; }
    }
    if (tid == 0 || rows_s[tid - 1] != myrow){
      atomicAdd(cacc + (size_t)myrow * 4 + 0, vx);
      atomicAdd(cacc + (size_t)myrow * 4 + 1, vy);
      atomicAdd(cacc + (size_t)myrow * 4 + 2, vz);
    }
  }

  // ---- fallback path only: agg via segmented suffix-reduce + atomics
  if (!STREAM){
    #pragma unroll
    for (int nf = 0; nf < 4; ++nf){
      const int myrow = rows_s[nf * 16 + li];
      const bool head = (li == 0) || (rows_s[nf * 16 + li - 1] != myrow);
      float v[8];
      #pragma unroll
      for (int mf = 0; mf < 2; ++mf)
        #pragma unroll
        for (int r = 0; r < 4; ++r) v[mf * 4 + r] = bf2f((u16)(pm2[mf][nf] >> (16 * r)));
      #pragma unroll
      for (int d = 1; d < 16; d <<= 1){
        const int rr = __shfl_down(myrow, d, 16);
        const bool ok = ((li + d) < 16) && (rr == myrow);
        #pragma unroll
        for (int j = 0; j < 8; ++j){
          const float vv = __shfl_down(v[j], d, 16);
          if (ok) v[j] += vv;
        }
      }
      if (head){
        #pragma unroll
        for (int mf = 0; mf < 2; ++mf){
          float* ag = agg + (size_t)myrow * HH + w * 32 + mf * 16 + g * 4;
          atomicAdd(ag + 0, v[mf * 4 + 0]);
          atomicAdd(ag + 1, v[mf * 4 + 1]);
          atomicAdd(ag + 2, v[mf * 4 + 2]);
          atomicAdd(ag + 3, v[mf * 4 + 3]);
        }
      }
    }
  }
}

// ---------------- node kernel: h += MLP([h, agg]) ; agg read as bf16 ----------------
__global__ __launch_bounds__(256) void node_kernel(
    float* __restrict__ h, u16* __restrict__ hb, const u16* __restrict__ agg_bf,
    const u16* __restrict__ pw1, const u16* __restrict__ pw2,
    const float* __restrict__ b1, const float* __restrict__ b2){
  __shared__ u64 mt[4096];
  __shared__ float bias_s[512];
  const int tid = threadIdx.x;
  const int w = tid >> 6, l = tid & 63, g = l >> 4, li = l & 15;
  const int nb = blockIdx.x * 64;
  for (int i = tid; i < 512; i += 256) bias_s[i] = (i < 256) ? b1[i] : b2[i - 256];
  __syncthreads();

  const u16* hp[4]; const u16* ap[4];
  int rdA[4], wrA[4];
  #pragma unroll
  for (int nf = 0; nf < 4; ++nf){
    int n = nb + nf * 16 + li; if (n >= NN) n = NN - 1;
    hp[nf] = hb     + (size_t)n * HH + g * 4;
    ap[nf] = agg_bf + (size_t)n * HH + g * 4;
    int e = nf * 16 + li;
    const int gsw = g ^ (e & 7);
    rdA[nf] = e * 64 + gsw;
    wrA[nf] = e * 64 + w * 16 + gsw;  // mf: {0:+0, 1:^4, 2:+8, 3:^4+8}
  }
  f4v acc[4][4];
  #pragma unroll
  for (int a = 0; a < 4; ++a)
    #pragma unroll
    for (int b = 0; b < 4; ++b) acc[a][b] = (f4v){0.f,0.f,0.f,0.f};

  const u16* pw1b = pw1 + ((size_t)(w * 4) * 64 + l) * 8;
  #pragma unroll 4
  for (int kb = 0; kb < 8; ++kb){
    s8v A[4];
    #pragma unroll
    for (int mf = 0; mf < 4; ++mf) A[mf] = *(const s8v*)(pw1b + (size_t)kb * 8192 + mf * 512);
    #pragma unroll
    for (int nf = 0; nf < 4; ++nf){
      BU bu;
      bu.d[0] = *(const u64*)(hp[nf] + kb * 32);
      bu.d[1] = *(const u64*)(hp[nf] + kb * 32 + 16);
      #pragma unroll
      for (int mf = 0; mf < 4; ++mf)
        acc[mf][nf] = __builtin_amdgcn_mfma_f32_16x16x32_bf16(A[mf], bu.v, acc[mf][nf], 0, 0, 0);
    }
  }
  #pragma unroll 4
  for (int kb = 8; kb < 16; ++kb){
    s8v A[4];
    #pragma unroll
    for (int mf = 0; mf < 4; ++mf) A[mf] = *(const s8v*)(pw1b + (size_t)kb * 8192 + mf * 512);
    #pragma unroll
    for (int nf = 0; nf < 4; ++nf){
      BU bu;
      bu.d[0] = *(const u64*)(ap[nf] + (kb - 8) * 32);
      bu.d[1] = *(const u64*)(ap[nf] + (kb - 8) * 32 + 16);
      #pragma unroll
      for (int mf = 0; mf < 4; ++mf)
        acc[mf][nf] = __builtin_amdgcn_mfma_f32_16x16x32_bf16(A[mf], bu.v, acc[mf][nf], 0, 0, 0);
    }
  }
  #pragma unroll
  for (int mf = 0; mf < 4; ++mf){
    const int fb = w * 64 + mf * 16 + g * 4;
    const float4 bb = *(const float4*)&bias_s[fb];
    #pragma unroll
    for (int nf = 0; nf < 4; ++nf){
      float v0 = siluf(acc[mf][nf][0] + bb.x);
      float v1 = siluf(acc[mf][nf][1] + bb.y);
      float v2 = siluf(acc[mf][nf][2] + bb.z);
      float v3 = siluf(acc[mf][nf][3] + bb.w);
      const int wr = (mf & 1 ? (wrA[nf] ^ 4) : wrA[nf]) + (mf & 2 ? 8 : 0);
      mt[wr] = pack4bf(v0, v1, v2, v3);
    }
  }
  __syncthreads();

  #pragma unroll
  for (int a = 0; a < 4; ++a)
    #pragma unroll
    for (int b = 0; b < 4; ++b) acc[a][b] = (f4v){0.f,0.f,0.f,0.f};
  const u16* pw2b = pw2 + ((size_t)(w * 4) * 64 + l) * 8;
  #pragma unroll 4
  for (int kb = 0; kb < 8; ++kb){
    s8v A[4];
    #pragma unroll
    for (int mf = 0; mf < 4; ++mf) A[mf] = *(const s8v*)(pw2b + (size_t)kb * 8192 + mf * 512);
    #pragma unroll
    for (int nf = 0; nf < 4; ++nf){
      BU bu;
      bu.d[0] = mt[rdA[nf] + kb * 8];
      bu.d[1] = mt[(rdA[nf] ^ 4) + kb * 8];
      #pragma unroll
      for (int mf = 0; mf < 4; ++mf)
        acc[mf][nf] = __builtin_amdgcn_mfma_f32_16x16x32_bf16(A[mf], bu.v, acc[mf][nf], 0, 0, 0);
    }
  }
  #pragma unroll
  for (int mf = 0; mf < 4; ++mf){
    const int fb = w * 64 + mf * 16 + g * 4;
    const float4 bb = *(const float4*)&bias_s[256 + fb];
    #pragma unroll
    for (int nf = 0; nf < 4; ++nf){
      int n = nb + nf * 16 + li;
      if (n < NN){
        float4 hv = *(float4*)(h + (size_t)n * HH + fb);
        float o0 = hv.x + acc[mf][nf][0] + bb.x;
        float o1 = hv.y + acc[mf][nf][1] + bb.y;
        float o2 = hv.z + acc[mf][nf][2] + bb.z;
        float o3 = hv.w + acc[mf][nf][3] + bb.w;
        *(float4*)(h + (size_t)n * HH + fb) = make_float4(o0, o1, o2, o3);
        *(u64*)(hb + (size_t)n * HH + fb) = pack4bf(o0, o1, o2, o3);
      }
    }
  }
}

// ---------------- resblock + head ----------------
__global__ __launch_bounds__(256) void final_kernel(
    const float* __restrict__ z, const float* __restrict__ rw1, const float* __restrict__ rb1,
    const float* __restrict__ rw2, const float* __restrict__ rb2,
    const float* __restrict__ hw, const float* __restrict__ hbs, float* __restrict__ out){
  __shared__ float zr[272], t1[256], t2[272];
  const int b = blockIdx.x, tid = threadIdx.x;
  for (int i = tid; i < 272; i += 256) zr[i] = z[(size_t)b * 272 + i];
  __syncthreads();
  {
    float a = rb1[tid];
    for (int k = 0; k < 272; ++k) a += zr[k] * rw1[(size_t)k * 256 + tid];
    t1[tid] = siluf(a);
  }
  __syncthreads();
  for (int i = tid; i < 272; i += 256){
    float a = rb2[i] + zr[i];
    for (int k = 0; k < 256; ++k) a += t1[k] * rw2[(size_t)k * 272 + i];
    t2[i] = a;
  }
  __syncthreads();
  for (int p = tid; p < 2000; p += 256){
    float a = hbs[p];
    for (int k = 0; k < 272; ++k) a += t2[k] * hw[(size_t)k * 2000 + p];
    out[(size_t)b * 2000 + p] = a;
  }
}

extern "C" void kernel_launch(void* const* d_in, const int* in_sizes, int n_in,
                              void* d_out, int out_size, void* d_ws, size_t ws_size,
                              hipStream_t stream){
  const float* x        = (const float*)d_in[0];
  const float* pos      = (const float*)d_in[1];
  const float* eattr    = (const float*)d_in[2];
  const float* fragl    = (const float*)d_in[3];
  const float* addf     = (const float*)d_in[4];
  const int*   ei       = (const int*)d_in[5];
  const int*   batch    = (const int*)d_in[6];
  const float* emb_in_w = (const float*)d_in[7];
  const float* emb_in_b = (const float*)d_in[8];
  const float* edge_w1  = (const float*)d_in[9];
  const float* edge_b1  = (const float*)d_in[10];
  const float* edge_w2  = (const float*)d_in[11];
  const float* edge_b2  = (const float*)d_in[12];
  const float* node_w1  = (const float*)d_in[13];
  const float* node_b1  = (const float*)d_in[14];
  const float* node_w2  = (const float*)d_in[15];
  const float* node_b2  = (const float*)d_in[16];
  const float* coord_w1 = (const float*)d_in[17];
  const float* coord_b1 = (const float*)d_in[18];
  const float* coord_w2 = (const float*)d_in[19];
  const float* emb_out_w= (const float*)d_in[20];
  const float* emb_out_b= (const float*)d_in[21];
  const float* res_w1   = (const float*)d_in[22];
  const float* res_b1   = (const float*)d_in[23];
  const float* res_w2   = (const float*)d_in[24];
  const float* res_b2   = (const float*)d_in[25];
  const float* head_w   = (const float*)d_in[26];
  const float* head_b   = (const float*)d_in[27];

  char* ws = (char*)d_ws;
  size_t off = 0;
  auto alloc = [&](size_t bytes) -> void* {
    void* p = ws + off;
    off += (bytes + 255) & ~(size_t)255;
    return p;
  };
  float*  h      = (float*)alloc((size_t)NN * HH * 4);
  float*  agg    = (float*)alloc((size_t)NN * HH * 4);
  u16*    agg_bf = (u16*)  alloc((size_t)NN * HH * 2);
  u16*    hb     = (u16*)  alloc((size_t)NN * HH * 2);
  float*  Pa     = (float*)alloc((size_t)NN * HH * 4);
  float*  Pb     = (float*)alloc((size_t)NN * HH * 4);
  float*  ho     = (float*)alloc((size_t)NN * HH * 4);
  float4* coordb = (float4*)alloc((size_t)NN * 16);
  float*  cacc   = (float*)alloc((size_t)NN * 16);
  float*  z      = (float*)alloc((size_t)BB * 272 * 4);
  u16*    packed = (u16*)  alloc((size_t)7680 * 256 * 2);
  int*    icnt   = (int*)  alloc((size_t)NN * 4);
  int*    iscan  = (int*)  alloc((size_t)NN * 4);
  int*    rstart = (int*)  alloc((size_t)NN * 4);
  int*    cursor = (int*)  alloc((size_t)NN * 4);
  int*    bsum   = (int*)  alloc((size_t)128 * 4);
  int*    bstart = (int*)  alloc((size_t)(BB + 1) * 4);
  int*    seid   = (int*)  alloc((size_t)EE * 4);
  int*    srow   = (int*)  alloc((size_t)EE * 4);
  int*    scol   = (int*)  alloc((size_t)EE * 4);
  const size_t base_off = off;
  u64*    m2g    = (u64*)  alloc((size_t)EE * HH * 2);   // 164 MB m2 stream buffer
  const bool use_stream = (off <= ws_size);
  if (base_off > ws_size) return;

  u16* pk_embin  = packed;
  u16* pk_embout = packed + 32768 + (size_t)4 * 466944;
  auto pk_ew1 = [&](int l){ return packed + 32768 + (size_t)l * 466944; };
  auto pk_ew2 = [&](int l){ return pk_ew1(l) + 139264; };
  auto pk_cw1 = [&](int l){ return pk_ew1(l) + 204800; };
  auto pk_nw1 = [&](int l){ return pk_ew1(l) + 270336; };
  auto pk_nw2 = [&](int l){ return pk_ew1(l) + 401408; };

  pack_kernel<<<16, 256, 0, stream>>>(emb_in_w, pk_embin, 128, 4);
  for (int l = 0; l < 4; ++l){
    pack_kernel<<<68, 256, 0, stream>>>(edge_w1 + (size_t)l * 529 * 256, pk_ew1(l), 529, 17);
    pack_kernel<<<32, 256, 0, stream>>>(edge_w2 + (size_t)l * 65536,     pk_ew2(l), 256, 8);
    pack_kernel<<<32, 256, 0, stream>>>(coord_w1 + (size_t)l * 65536,    pk_cw1(l), 256, 8);
    pack_kernel<<<64, 256, 0, stream>>>(node_w1 + (size_t)l * 131072,    pk_nw1(l), 512, 16);
    pack_kernel<<<32, 256, 0, stream>>>(node_w2 + (size_t)l * 65536,     pk_nw2(l), 256, 8);
  }
  pack_kernel<<<32, 256, 0, stream>>>(emb_out_w, pk_embout, 256, 8);

  // ---- one-time edge sort by row + per-graph ranges
  const int NB = (NN + 255) / 256;   // 79
  hipMemsetAsync(icnt,   0, (size_t)NN * 4, stream);
  hipMemsetAsync(cursor, 0, (size_t)NN * 4, stream);
  icnt_kernel<<<(EE + 255) / 256, 256, 0, stream>>>(ei, icnt);
  iscan_block<<<NB, 256, 0, stream>>>(icnt, iscan, bsum);
  iscan_top<<<1, 64, 0, stream>>>(bsum, NB);
  iscan_fix<<<NB, 256, 0, stream>>>(icnt, iscan, bsum, rstart);
  scatter_kernel<<<(EE + 255) / 256, 256, 0, stream>>>(ei, rstart, cursor, seid, srow, scol);
  bstart_kernel<<<NB, 256, 0, stream>>>(batch, bstart);

  coord_init_kernel<<<79, 256, 0, stream>>>(pos, coordb);
  emb_in_kernel<<<313, 256, 0, stream>>>(x, pk_embin, emb_in_b, h, hb);

  for (int l = 0; l < 4; ++l){
    hipMemsetAsync(cacc, 0, (size_t)NN * 16, stream);
    pab_kernel<<<313, 256, 0, stream>>>(hb, pk_ew1(l), edge_b1 + l * 256, Pa, Pb);
    if (use_stream){
      edge_kernel<true><<<5000, 512, 0, stream>>>(Pa, Pb, coordb, srow, scol, seid, eattr,
          pk_ew1(l), pk_ew2(l), pk_cw1(l),
          edge_b2 + l * 256, coord_b1 + l * 256, coord_w2 + l * 256,
          agg, cacc, m2g);
      agg_csr_kernel<<<NN, 256, 0, stream>>>((const u16*)m2g, rstart, icnt, agg_bf);
    } else {
      hipMemsetAsync(agg, 0, (size_t)NN * HH * 4, stream);
      edge_kernel<false><<<5000, 512, 0, stream>>>(Pa, Pb, coordb, srow, scol, seid, eattr,
          pk_ew1(l), pk_ew2(l), pk_cw1(l),
          edge_b2 + l * 256, coord_b1 + l * 256, coord_w2 + l * 256,
          agg, cacc, m2g);
      agg_conv_kernel<<<(NN * HH + 255) / 256, 256, 0, stream>>>(agg, agg_bf);
    }
    coord_upd_kernel<<<79, 256, 0, stream>>>(coordb, cacc, icnt);
    node_kernel<<<313, 256, 0, stream>>>(h, hb, agg_bf, pk_nw1(l), pk_nw2(l),
        node_b1 + l * 256, node_b2 + l * 256);
  }

  emb_out_kernel<<<313, 256, 0, stream>>>(hb, pk_embout, emb_out_b, ho);
  pool_csr_kernel<<<BB * 4, 64, 0, stream>>>(ho, bstart, fragl, addf, z);
  final_kernel<<<128, 256, 0, stream>>>(z, res_w1, res_b1, res_w2, res_b2, head_w, head_b,
                                        (float*)d_out);
}

// Round 9
// 1578.163 us; speedup vs baseline: 3.5601x; 1.0844x over previous
//
#include <hip/hip_runtime.h>

typedef unsigned short u16;
typedef unsigned int   u32;
typedef unsigned long long u64;
typedef __attribute__((ext_vector_type(8))) short s8v;   // 8 bf16 (4 VGPRs) MFMA operand
typedef __attribute__((ext_vector_type(4))) float f4v;   // MFMA accumulator

#define NN 20000
#define EE 320000
#define BB 128
#define HH 256

union BU { u64 d[2]; s8v v; };

__device__ __forceinline__ u16 f2bf(float f){
  u32 u = __float_as_uint(f);
  return (u16)((u + 0x7FFFu + ((u >> 16) & 1u)) >> 16);   // RNE
}
__device__ __forceinline__ float bf2f(u16 u){ return __uint_as_float((u32)u << 16); }
__device__ __forceinline__ u32 cvt2(float a, float b){
  u32 r; asm("v_cvt_pk_bf16_f32 %0, %1, %2" : "=v"(r) : "v"(a), "v"(b)); return r;
}
__device__ __forceinline__ u64 pack4bf(float a, float b, float c, float d){
  return (u64)cvt2(a, b) | ((u64)cvt2(c, d) << 32);
}
// silu via v_rcp (1 instr) instead of full-precision divide; 1-ulp rcp error << bf16 rounding
__device__ __forceinline__ float siluf(float v){
  return v * __builtin_amdgcn_rcpf(1.0f + __expf(-v));
}

// ---------------- weight packing: W [K][256] f32 -> A-fragment blob (W^T), bf16 ----------------
__global__ void pack_kernel(const float* __restrict__ src, u16* __restrict__ dst, int K, int KB){
  int t = blockIdx.x * 256 + threadIdx.x;
  if (t >= KB * 1024) return;
  int lane = t & 63, mf = (t >> 6) & 15, kb = t >> 10;
  int g = lane >> 4, li = lane & 15;
  int m = mf * 16 + li;
  u16 o[8];
  #pragma unroll
  for (int j = 0; j < 8; ++j){
    int k = kb * 32 + ((j < 4) ? (g * 4 + j) : (16 + g * 4 + (j - 4)));
    o[j] = (k < K) ? f2bf(src[(size_t)k * 256 + m]) : (u16)0;
  }
  u16* d = dst + ((size_t)(kb * 16 + mf) * 64 + lane) * 8;
  *(u64*)(d)     = (u64)o[0] | ((u64)o[1] << 16) | ((u64)o[2] << 32) | ((u64)o[3] << 48);
  *(u64*)(d + 4) = (u64)o[4] | ((u64)o[5] << 16) | ((u64)o[6] << 32) | ((u64)o[7] << 48);
}

// ---------------- edge sort by destination row (one-time per launch) ----------------
__global__ void icnt_kernel(const int* __restrict__ ei, int* __restrict__ icnt){
  int t = blockIdx.x * 256 + threadIdx.x;
  if (t < EE) atomicAdd(&icnt[ei[t]], 1);
}
__global__ void iscan_block(const int* __restrict__ icnt, int* __restrict__ iscan, int* __restrict__ bsum){
  __shared__ int s[256];
  int i = blockIdx.x * 256 + threadIdx.x;
  int v = (i < NN) ? icnt[i] : 0;
  s[threadIdx.x] = v; __syncthreads();
  #pragma unroll
  for (int d = 1; d < 256; d <<= 1){
    int t = (threadIdx.x >= d) ? s[threadIdx.x - d] : 0;
    __syncthreads();
    s[threadIdx.x] += t;
    __syncthreads();
  }
  if (i < NN) iscan[i] = s[threadIdx.x];
  if (threadIdx.x == 255) bsum[blockIdx.x] = s[255];
}
__global__ void iscan_top(int* __restrict__ bsum, int nb){
  if (blockIdx.x == 0 && threadIdx.x == 0){
    int acc = 0;
    for (int i = 0; i < nb; ++i){ int t = bsum[i]; bsum[i] = acc; acc += t; }
  }
}
__global__ void iscan_fix(const int* __restrict__ icnt, const int* __restrict__ iscan,
                          const int* __restrict__ bsum, int* __restrict__ rstart){
  int i = blockIdx.x * 256 + threadIdx.x;
  if (i < NN) rstart[i] = bsum[blockIdx.x] + iscan[i] - icnt[i];
}
__global__ void scatter_kernel(const int* __restrict__ ei, const int* __restrict__ rstart,
                               int* __restrict__ cursor, int* __restrict__ seid,
                               int* __restrict__ srow, int* __restrict__ scol){
  int e = blockIdx.x * 256 + threadIdx.x;
  if (e < EE){
    int r = ei[e];
    int p = rstart[r] + atomicAdd(&cursor[r], 1);
    seid[p] = e; srow[p] = r; scol[p] = ei[EE + e];
  }
}
// per-graph node ranges from the SORTED batch array (run once)
__global__ void bstart_kernel(const int* __restrict__ batch, int* __restrict__ bstart){
  int n = blockIdx.x * 256 + threadIdx.x;
  if (n >= NN) return;
  int b = batch[n];
  if (n == 0){ for (int x = 0; x <= b; ++x) bstart[x] = 0; }
  else {
    int pb = batch[n - 1];
    for (int x = pb + 1; x <= b; ++x) bstart[x] = n;
  }
  if (n == NN - 1) bstart[BB] = NN;
}

// ---------------- small utility kernels ----------------
__global__ void coord_init_kernel(const float* __restrict__ pos, float4* __restrict__ coord){
  int t = blockIdx.x * 256 + threadIdx.x;
  if (t < NN) coord[t] = make_float4(pos[3*t], pos[3*t+1], pos[3*t+2], 0.f);
}
__global__ void coord_upd_kernel(float4* __restrict__ coord, const float* __restrict__ cacc,
                                 const int* __restrict__ icnt){
  int t = blockIdx.x * 256 + threadIdx.x;
  if (t >= NN) return;
  float k = fmaxf((float)icnt[t], 1.0f);
  float4 c = coord[t];
  c.x += cacc[4*t+0] / k; c.y += cacc[4*t+1] / k; c.z += cacc[4*t+2] / k;
  coord[t] = c;
}

// ---------------- CSR segment-sum: agg_bf[n][f] = bf16( sum_e m2[e][f] ) ----------------
__global__ __launch_bounds__(256) void agg_csr_kernel(
    const u16* __restrict__ m2b, const int* __restrict__ rstart,
    const int* __restrict__ icnt, u16* __restrict__ agg_bf){
  const int n = blockIdx.x, f = threadIdx.x;
  const int s = rstart[n], d = icnt[n];
  const u16* p = m2b + (size_t)s * 256 + f;
  float a0 = 0.f, a1 = 0.f;
  int i = 0;
  for (; i + 1 < d; i += 2){ a0 += bf2f(p[(size_t)i * 256]); a1 += bf2f(p[(size_t)(i + 1) * 256]); }
  if (i < d) a0 += bf2f(p[(size_t)i * 256]);
  agg_bf[(size_t)n * 256 + f] = f2bf(a0 + a1);
}
__global__ void agg_conv_kernel(const float* __restrict__ agg, u16* __restrict__ agg_bf){
  int t = blockIdx.x * 256 + threadIdx.x;
  if (t < NN * HH) agg_bf[t] = f2bf(agg[t]);
}

// ---------------- emb_in (+ fused pab for layer 0) ----------------
// LDS pair layout (shared by all tiled kernels below): logical chunk c=(a,b4,g)
// [c = a*8 + b4*4 + g, features f=4c..4c+3] stored as ulonglong2 pair at
// mt2[e*32 + ((a*4+g) ^ (e&7))]; pair = (b4=0, b4=1). Precompute per-thread:
// pbase = e*32 + (g^(e&3)), pm4 = e&4; index(a) = pbase + ((4a) ^ pm4).
__global__ __launch_bounds__(256) void emb_in_kernel(
    const float* __restrict__ x, const u16* __restrict__ pw,
    const float* __restrict__ bias, float* __restrict__ h, u16* __restrict__ hb,
    const u16* __restrict__ pw1n, const float* __restrict__ b1n,
    float* __restrict__ Pa, float* __restrict__ Pb){
  __shared__ ulonglong2 mt2[2048];
  const int tid = threadIdx.x;
  const int w = tid >> 6, l = tid & 63, g = l >> 4, li = l & 15;
  const int nb = blockIdx.x * 64;
  const float* xp[4];
  int pbase[4], pm4[4];
  #pragma unroll
  for (int nf = 0; nf < 4; ++nf){
    int n = nb + nf * 16 + li; if (n >= NN) n = NN - 1;
    xp[nf] = x + (size_t)n * 128 + g * 4;
    int e = nf * 16 + li;
    pbase[nf] = e * 32 + (g ^ (e & 3));
    pm4[nf] = e & 4;
  }
  f4v acc[4][4];
  #pragma unroll
  for (int a = 0; a < 4; ++a)
    #pragma unroll
    for (int b = 0; b < 4; ++b) acc[a][b] = (f4v){0.f,0.f,0.f,0.f};
  const u16* pwb = pw + ((size_t)(w * 4) * 64 + l) * 8;
  #pragma unroll
  for (int kb = 0; kb < 4; ++kb){
    s8v A[4];
    #pragma unroll
    for (int mf = 0; mf < 4; ++mf) A[mf] = *(const s8v*)(pwb + (size_t)kb * 8192 + mf * 512);
    #pragma unroll
    for (int nf = 0; nf < 4; ++nf){
      float4 fa = *(const float4*)(xp[nf] + kb * 32);
      float4 fb = *(const float4*)(xp[nf] + kb * 32 + 16);
      BU bu;
      bu.d[0] = pack4bf(fa.x, fa.y, fa.z, fa.w);
      bu.d[1] = pack4bf(fb.x, fb.y, fb.z, fb.w);
      #pragma unroll
      for (int mf = 0; mf < 4; ++mf)
        acc[mf][nf] = __builtin_amdgcn_mfma_f32_16x16x32_bf16(A[mf], bu.v, acc[mf][nf], 0, 0, 0);
    }
  }
  u64 pm[4][4];
  #pragma unroll
  for (int mf = 0; mf < 4; ++mf){
    const int fb = w * 64 + mf * 16 + g * 4;
    float b0 = bias[fb], b1 = bias[fb+1], b2 = bias[fb+2], b3 = bias[fb+3];
    #pragma unroll
    for (int nf = 0; nf < 4; ++nf){
      int n = nb + nf * 16 + li;
      float o0 = acc[mf][nf][0] + b0, o1 = acc[mf][nf][1] + b1;
      float o2 = acc[mf][nf][2] + b2, o3 = acc[mf][nf][3] + b3;
      pm[mf][nf] = pack4bf(o0, o1, o2, o3);
      if (n < NN){
        *(float4*)(h + (size_t)n * HH + fb) = make_float4(o0, o1, o2, o3);
        *(u64*)(hb + (size_t)n * HH + fb) = pm[mf][nf];
      }
    }
  }
  // tile for fused pab
  #pragma unroll
  for (int nf = 0; nf < 4; ++nf){
    ulonglong2 t0; t0.x = pm[0][nf]; t0.y = pm[1][nf];
    ulonglong2 t1; t1.x = pm[2][nf]; t1.y = pm[3][nf];
    mt2[pbase[nf] + ((8 * w)     ^ pm4[nf])] = t0;
    mt2[pbase[nf] + ((8 * w + 4) ^ pm4[nf])] = t1;
  }
  __syncthreads();
  const u16* pwn = pw1n + ((size_t)(w * 4) * 64 + l) * 8;
  #pragma unroll
  for (int pass = 0; pass < 2; ++pass){
    #pragma unroll
    for (int a = 0; a < 4; ++a)
      #pragma unroll
      for (int b = 0; b < 4; ++b) acc[a][b] = (f4v){0.f,0.f,0.f,0.f};
    const u16* pwp = pwn + (size_t)(pass * 8) * 8192;
    #pragma unroll 4
    for (int kb = 0; kb < 8; ++kb){
      s8v A[4];
      #pragma unroll
      for (int mf = 0; mf < 4; ++mf) A[mf] = *(const s8v*)(pwp + (size_t)kb * 8192 + mf * 512);
      #pragma unroll
      for (int nf = 0; nf < 4; ++nf){
        ulonglong2 pr = mt2[pbase[nf] + ((4 * kb) ^ pm4[nf])];
        BU bu; bu.d[0] = pr.x; bu.d[1] = pr.y;
        #pragma unroll
        for (int mf = 0; mf < 4; ++mf)
          acc[mf][nf] = __builtin_amdgcn_mfma_f32_16x16x32_bf16(A[mf], bu.v, acc[mf][nf], 0, 0, 0);
      }
    }
    float* dst = pass ? Pb : Pa;
    #pragma unroll
    for (int mf = 0; mf < 4; ++mf){
      const int fb = w * 64 + mf * 16 + g * 4;
      float c0 = 0.f, c1 = 0.f, c2 = 0.f, c3 = 0.f;
      if (!pass){ c0 = b1n[fb]; c1 = b1n[fb+1]; c2 = b1n[fb+2]; c3 = b1n[fb+3]; }
      #pragma unroll
      for (int nf = 0; nf < 4; ++nf){
        int n = nb + nf * 16 + li;
        if (n < NN)
          *(float4*)(dst + (size_t)n * HH + fb) =
            make_float4(acc[mf][nf][0] + c0, acc[mf][nf][1] + c1,
                        acc[mf][nf][2] + c2, acc[mf][nf][3] + c3);
      }
    }
  }
}

// ---------------- emb_out: ho = h @ emb_out_w + b  (f32 out, no atomics) ----------------
__global__ __launch_bounds__(256) void emb_out_kernel(
    const u16* __restrict__ hb, const u16* __restrict__ pw,
    const float* __restrict__ bias, float* __restrict__ ho){
  const int tid = threadIdx.x;
  const int w = tid >> 6, l = tid & 63, g = l >> 4, li = l & 15;
  const int nb = blockIdx.x * 64;
  const u16* hp[4];
  #pragma unroll
  for (int nf = 0; nf < 4; ++nf){
    int n = nb + nf * 16 + li; if (n >= NN) n = NN - 1;
    hp[nf] = hb + (size_t)n * HH + g * 4;
  }
  f4v acc[4][4];
  #pragma unroll
  for (int a = 0; a < 4; ++a)
    #pragma unroll
    for (int b = 0; b < 4; ++b) acc[a][b] = (f4v){0.f,0.f,0.f,0.f};
  const u16* pwb = pw + ((size_t)(w * 4) * 64 + l) * 8;
  #pragma unroll 4
  for (int kb = 0; kb < 8; ++kb){
    s8v A[4];
    #pragma unroll
    for (int mf = 0; mf < 4; ++mf) A[mf] = *(const s8v*)(pwb + (size_t)kb * 8192 + mf * 512);
    #pragma unroll
    for (int nf = 0; nf < 4; ++nf){
      BU bu;
      bu.d[0] = *(const u64*)(hp[nf] + kb * 32);
      bu.d[1] = *(const u64*)(hp[nf] + kb * 32 + 16);
      #pragma unroll
      for (int mf = 0; mf < 4; ++mf)
        acc[mf][nf] = __builtin_amdgcn_mfma_f32_16x16x32_bf16(A[mf], bu.v, acc[mf][nf], 0, 0, 0);
    }
  }
  #pragma unroll
  for (int mf = 0; mf < 4; ++mf){
    const int fb = w * 64 + mf * 16 + g * 4;
    float b0 = bias[fb], b1 = bias[fb+1], b2 = bias[fb+2], b3 = bias[fb+3];
    #pragma unroll
    for (int nf = 0; nf < 4; ++nf){
      int n = nb + nf * 16 + li;
      if (n < NN)
        *(float4*)(ho + (size_t)n * HH + fb) =
          make_float4(acc[mf][nf][0] + b0, acc[mf][nf][1] + b1,
                      acc[mf][nf][2] + b2, acc[mf][nf][3] + b3);
    }
  }
}

// ---------------- max-pool over contiguous per-graph node ranges + build z ----------------
__global__ __launch_bounds__(64) void pool_csr_kernel(
    const float* __restrict__ ho, const int* __restrict__ bstart,
    const float* __restrict__ fragl, const float* __restrict__ addf, float* __restrict__ z){
  const int b = blockIdx.x >> 2, q = blockIdx.x & 3;
  const int f = q * 64 + threadIdx.x;
  const int s = bstart[b], e = bstart[b + 1];
  const float* p = ho + (size_t)s * HH + f;
  float m0 = -3.0e38f, m1 = -3.0e38f;
  int n = s;
  for (; n + 1 < e; n += 2){ m0 = fmaxf(m0, p[0]); m1 = fmaxf(m1, p[HH]); p += 2 * HH; }
  if (n < e) m0 = fmaxf(m0, p[0]);
  z[(size_t)b * 272 + f] = fmaxf(m0, m1);
  if (q == 0 && threadIdx.x < 16){
    int j = threadIdx.x;
    float v = (j < 8) ? fragl[b * 8 + j] : addf[b * 8 + (j - 8)];
    z[(size_t)b * 272 + 256 + j] = v;
  }
}

// ---------------- edge kernel: 64 SORTED edges/block, 512 threads (8 waves x 32 feats) ----------------
// b128 pair LDS layout + early Pa/Pb register prefetch (T14).
template<bool STREAM>
__global__ __launch_bounds__(512, 4) void edge_kernel(
    const float* __restrict__ Pa, const float* __restrict__ Pb,
    const float4* __restrict__ coord,
    const int* __restrict__ srow, const int* __restrict__ scol, const int* __restrict__ seid,
    const float* __restrict__ eattr,
    const u16* __restrict__ pw1, const u16* __restrict__ pw2, const u16* __restrict__ pw3,
    const float* __restrict__ b2, const float* __restrict__ cb1, const float* __restrict__ cw2,
    float* __restrict__ agg, float* __restrict__ cacc, u64* __restrict__ m2g){
  __shared__ ulonglong2 mt2[2048];    // 32KB pair tile [64 edges][32 pairs]
  __shared__ float4 dif[64];
  __shared__ int rows_s[64];
  __shared__ int cols_s[64];
  __shared__ int seid_s[64];
  __shared__ float bias_s[768];       // b2 | cb1 | cw2
  __shared__ float cpart[8][64];

  const int tid = threadIdx.x;
  const int w = tid >> 6, l = tid & 63, g = l >> 4, li = l & 15;
  const int wg = (blockIdx.x & 7) * 625 + (blockIdx.x >> 3);
  const int eb = wg * 64;

  if (tid < 64){
    int sp = eb + tid;
    int r = srow[sp], c = scol[sp];
    rows_s[tid] = r; cols_s[tid] = c; seid_s[tid] = seid[sp];
    float4 ca = coord[r], cb = coord[c];
    float dx = ca.x - cb.x, dy = ca.y - cb.y, dz = ca.z - cb.z;
    float rad = dx*dx + dy*dy + dz*dz;
    dif[tid] = make_float4(dx, dy, dz, rad);
  }
  for (int i = tid; i < 768; i += 512){
    float v;
    if      (i < 256) v = b2[i];
    else if (i < 512) v = cb1[i - 256];
    else              v = cw2[i - 512];
    bias_s[i] = v;
  }
  __syncthreads();

  const float* paP[4]; const float* pbP[4];
  int pbase[4], pm4[4], wrI[4];
  #pragma unroll
  for (int nf = 0; nf < 4; ++nf){
    int e = nf * 16 + li;
    paP[nf] = Pa + (size_t)rows_s[e] * HH;
    pbP[nf] = Pb + (size_t)cols_s[e] * HH;
    pbase[nf] = e * 32 + (g ^ (e & 3));
    pm4[nf] = e & 4;
    wrI[nf] = pbase[nf] + ((4 * w) ^ pm4[nf]);
  }

  // ---- EARLY Pa/Pb gather issue (latency hides under eattr + tail MFMA)
  float4 pa[2][4], pb[2][4];
  #pragma unroll
  for (int mf = 0; mf < 2; ++mf){
    const int fb = w * 32 + mf * 16 + g * 4;
    #pragma unroll
    for (int nf = 0; nf < 4; ++nf){
      pa[mf][nf] = *(const float4*)(paP[nf] + fb);
      pb[mf][nf] = *(const float4*)(pbP[nf] + fb);
    }
  }

  const u16* pw1b = pw1 + ((size_t)(w * 2) * 64 + l) * 8;
  const u16* pw2b = pw2 + ((size_t)(w * 2) * 64 + l) * 8;
  const u16* pw3b = pw3 + ((size_t)(w * 2) * 64 + l) * 8;

  // ---- tail k-block operands (k 512..543: radial | edge_attr | 0-pad)
  float tf[4][4];
  float rads[4];
  #pragma unroll
  for (int nf = 0; nf < 4; ++nf){
    int e = nf * 16 + li;
    const float* ep = eattr + (size_t)seid_s[e] * 16;
    if (g == 0){ tf[nf][0] = ep[0]; tf[nf][1] = ep[1]; tf[nf][2] = ep[2]; tf[nf][3] = ep[15]; }
    else { int i0 = g * 4 - 1; tf[nf][0] = ep[i0]; tf[nf][1] = ep[i0+1]; tf[nf][2] = ep[i0+2]; tf[nf][3] = ep[i0+3]; }
    rads[nf] = dif[e].w;
  }

  f4v acc[2][4];
  #pragma unroll
  for (int a = 0; a < 2; ++a)
    #pragma unroll
    for (int b = 0; b < 4; ++b) acc[a][b] = (f4v){0.f,0.f,0.f,0.f};

  // ---- tail MFMA (only remaining piece of GEMM1)
  {
    s8v at[2];
    #pragma unroll
    for (int mf = 0; mf < 2; ++mf) at[mf] = *(const s8v*)(pw1b + (size_t)16 * 8192 + mf * 512);
    #pragma unroll
    for (int nf = 0; nf < 4; ++nf){
      BU bu;
      if (g == 0){ bu.d[0] = pack4bf(rads[nf], tf[nf][0], tf[nf][1], tf[nf][2]); bu.d[1] = (u64)(cvt2(tf[nf][3], 0.f) & 0xffffu); }
      else       { bu.d[0] = pack4bf(tf[nf][0], tf[nf][1], tf[nf][2], tf[nf][3]); bu.d[1] = 0; }
      #pragma unroll
      for (int mf = 0; mf < 2; ++mf)
        acc[mf][nf] = __builtin_amdgcn_mfma_f32_16x16x32_bf16(at[mf], bu.v, acc[mf][nf], 0, 0, 0);
    }
  }

  // ---- m1 = silu(acc + Pa[row] + Pb[col])  (b1 folded into Pa) -> b128 tile write
  #pragma unroll
  for (int nf = 0; nf < 4; ++nf){
    ulonglong2 t;
    {
      float v0 = siluf(acc[0][nf][0] + pa[0][nf].x + pb[0][nf].x);
      float v1 = siluf(acc[0][nf][1] + pa[0][nf].y + pb[0][nf].y);
      float v2 = siluf(acc[0][nf][2] + pa[0][nf].z + pb[0][nf].z);
      float v3 = siluf(acc[0][nf][3] + pa[0][nf].w + pb[0][nf].w);
      t.x = pack4bf(v0, v1, v2, v3);
    }
    {
      float v0 = siluf(acc[1][nf][0] + pa[1][nf].x + pb[1][nf].x);
      float v1 = siluf(acc[1][nf][1] + pa[1][nf].y + pb[1][nf].y);
      float v2 = siluf(acc[1][nf][2] + pa[1][nf].z + pb[1][nf].z);
      float v3 = siluf(acc[1][nf][3] + pa[1][nf].w + pb[1][nf].w);
      t.y = pack4bf(v0, v1, v2, v3);
    }
    mt2[wrI[nf]] = t;
  }
  __syncthreads();

  // ---- GEMM2: m2 = silu(m1 @ W2 + b2)
  #pragma unroll
  for (int a = 0; a < 2; ++a)
    #pragma unroll
    for (int b = 0; b < 4; ++b) acc[a][b] = (f4v){0.f,0.f,0.f,0.f};
  #pragma unroll
  for (int s = 0; s < 8; ++s){
    s8v A[2];
    #pragma unroll
    for (int mf = 0; mf < 2; ++mf) A[mf] = *(const s8v*)(pw2b + (size_t)s * 8192 + mf * 512);
    #pragma unroll
    for (int nf = 0; nf < 4; ++nf){
      ulonglong2 pr = mt2[pbase[nf] + ((4 * s) ^ pm4[nf])];
      BU bu; bu.d[0] = pr.x; bu.d[1] = pr.y;
      #pragma unroll
      for (int mf = 0; mf < 2; ++mf)
        acc[mf][nf] = __builtin_amdgcn_mfma_f32_16x16x32_bf16(A[mf], bu.v, acc[mf][nf], 0, 0, 0);
    }
  }
  u64 pm2[2][4];
  #pragma unroll
  for (int mf = 0; mf < 2; ++mf){
    const int fb = w * 32 + mf * 16 + g * 4;
    const float4 bb = *(const float4*)&bias_s[fb];
    #pragma unroll
    for (int nf = 0; nf < 4; ++nf)
      pm2[mf][nf] = pack4bf(siluf(acc[mf][nf][0] + bb.x),
                            siluf(acc[mf][nf][1] + bb.y),
                            siluf(acc[mf][nf][2] + bb.z),
                            siluf(acc[mf][nf][3] + bb.w));
  }
  __syncthreads();                    // all waves done reading m1
  #pragma unroll
  for (int nf = 0; nf < 4; ++nf){
    ulonglong2 t; t.x = pm2[0][nf]; t.y = pm2[1][nf];
    mt2[wrI[nf]] = t;
  }
  __syncthreads();

  // ---- STREAM: coalesced write-out of m2 tile (unpermute to standard [e][f])
  if (STREAM){
    const u64* mtU = (const u64*)mt2;
    u64* dst = m2g + (size_t)eb * 64;
    #pragma unroll
    for (int j = 0; j < 8; ++j){
      int q8 = j * 512 + tid;
      int e = q8 >> 6, c = q8 & 63;
      int q = (c & 0x38) | ((c & 3) << 1) | ((c >> 2) & 1);
      dst[q8] = mtU[(e << 6) + (q ^ ((e & 7) << 1))];
    }
  }

  // ---- GEMM3: q = silu(m2 @ CW1 + cb1); c = q . cw2
  #pragma unroll
  for (int a = 0; a < 2; ++a)
    #pragma unroll
    for (int b = 0; b < 4; ++b) acc[a][b] = (f4v){0.f,0.f,0.f,0.f};
  #pragma unroll
  for (int s = 0; s < 8; ++s){
    s8v A[2];
    #pragma unroll
    for (int mf = 0; mf < 2; ++mf) A[mf] = *(const s8v*)(pw3b + (size_t)s * 8192 + mf * 512);
    #pragma unroll
    for (int nf = 0; nf < 4; ++nf){
      ulonglong2 pr = mt2[pbase[nf] + ((4 * s) ^ pm4[nf])];
      BU bu; bu.d[0] = pr.x; bu.d[1] = pr.y;
      #pragma unroll
      for (int mf = 0; mf < 2; ++mf)
        acc[mf][nf] = __builtin_amdgcn_mfma_f32_16x16x32_bf16(A[mf], bu.v, acc[mf][nf], 0, 0, 0);
    }
  }
  float cp4[4] = {0.f, 0.f, 0.f, 0.f};
  #pragma unroll
  for (int mf = 0; mf < 2; ++mf){
    const int fb = w * 32 + mf * 16 + g * 4;
    const float4 cb = *(const float4*)&bias_s[256 + fb];
    const float4 cw = *(const float4*)&bias_s[512 + fb];
    #pragma unroll
    for (int nf = 0; nf < 4; ++nf){
      cp4[nf] += siluf(acc[mf][nf][0] + cb.x) * cw.x;
      cp4[nf] += siluf(acc[mf][nf][1] + cb.y) * cw.y;
      cp4[nf] += siluf(acc[mf][nf][2] + cb.z) * cw.z;
      cp4[nf] += siluf(acc[mf][nf][3] + cb.w) * cw.w;
    }
  }
  #pragma unroll
  for (int nf = 0; nf < 4; ++nf){
    float v = cp4[nf];
    v += __shfl_xor(v, 16, 64);
    v += __shfl_xor(v, 32, 64);
    if (g == 0) cpart[w][nf * 16 + li] = v;
  }
  __syncthreads();

  // ---- cacc: segmented suffix-reduce across the 64 sorted edges, head lanes atomic
  if (tid < 64){
    float c = cpart[0][tid] + cpart[1][tid] + cpart[2][tid] + cpart[3][tid]
            + cpart[4][tid] + cpart[5][tid] + cpart[6][tid] + cpart[7][tid];
    float4 d = dif[tid];
    const int myrow = rows_s[tid];
    float vx = d.x * c, vy = d.y * c, vz = d.z * c;
    #pragma unroll
    for (int dd = 1; dd < 64; dd <<= 1){
      const int rr = __shfl_down(myrow, dd, 64);
      const bool ok = ((tid + dd) < 64) && (rr == myrow);
      float tx = __shfl_down(vx, dd, 64);
      float ty = __shfl_down(vy, dd, 64);
      float tz = __shfl_down(vz, dd, 64);
      if (ok){ vx += tx; vy += ty; vz += tz; }
    }
    if (tid == 0 || rows_s[tid - 1] != myrow){
      atomicAdd(cacc + (size_t)myrow * 4 + 0, vx);
      atomicAdd(cacc + (size_t)myrow * 4 + 1, vy);
      atomicAdd(cacc + (size_t)myrow * 4 + 2, vz);
    }
  }

  // ---- fallback path only: agg via segmented suffix-reduce + atomics
  if (!STREAM){
    #pragma unroll
    for (int nf = 0; nf < 4; ++nf){
      const int myrow = rows_s[nf * 16 + li];
      const bool head = (li == 0) || (rows_s[nf * 16 + li - 1] != myrow);
      float v[8];
      #pragma unroll
      for (int mf = 0; mf < 2; ++mf)
        #pragma unroll
        for (int r = 0; r < 4; ++r) v[mf * 4 + r] = bf2f((u16)(pm2[mf][nf] >> (16 * r)));
      #pragma unroll
      for (int d = 1; d < 16; d <<= 1){
        const int rr = __shfl_down(myrow, d, 16);
        const bool ok = ((li + d) < 16) && (rr == myrow);
        #pragma unroll
        for (int j = 0; j < 8; ++j){
          const float vv = __shfl_down(v[j], d, 16);
          if (ok) v[j] += vv;
        }
      }
      if (head){
        #pragma unroll
        for (int mf = 0; mf < 2; ++mf){
          float* ag = agg + (size_t)myrow * HH + w * 32 + mf * 16 + g * 4;
          atomicAdd(ag + 0, v[mf * 4 + 0]);
          atomicAdd(ag + 1, v[mf * 4 + 1]);
          atomicAdd(ag + 2, v[mf * 4 + 2]);
          atomicAdd(ag + 3, v[mf * 4 + 3]);
        }
      }
    }
  }
}

// ---------------- node kernel (+ fused next-layer pab): h += MLP([h, agg]) ----------------
template<bool EMIT_PAB>
__global__ __launch_bounds__(256) void node_pab_kernel(
    float* __restrict__ h, u16* __restrict__ hb, const u16* __restrict__ agg_bf,
    const u16* __restrict__ pw1, const u16* __restrict__ pw2,
    const float* __restrict__ b1, const float* __restrict__ b2,
    const u16* __restrict__ pw1n, const float* __restrict__ b1n,
    float* __restrict__ Pa, float* __restrict__ Pb){
  __shared__ ulonglong2 mt2[2048];
  __shared__ float bias_s[512];
  const int tid = threadIdx.x;
  const int w = tid >> 6, l = tid & 63, g = l >> 4, li = l & 15;
  const int nb = blockIdx.x * 64;
  for (int i = tid; i < 512; i += 256) bias_s[i] = (i < 256) ? b1[i] : b2[i - 256];
  __syncthreads();

  const u16* hp[4]; const u16* ap[4];
  int pbase[4], pm4[4];
  #pragma unroll
  for (int nf = 0; nf < 4; ++nf){
    int n = nb + nf * 16 + li; if (n >= NN) n = NN - 1;
    hp[nf] = hb     + (size_t)n * HH + g * 4;
    ap[nf] = agg_bf + (size_t)n * HH + g * 4;
    int e = nf * 16 + li;
    pbase[nf] = e * 32 + (g ^ (e & 3));
    pm4[nf] = e & 4;
  }
  f4v acc[4][4];
  #pragma unroll
  for (int a = 0; a < 4; ++a)
    #pragma unroll
    for (int b = 0; b < 4; ++b) acc[a][b] = (f4v){0.f,0.f,0.f,0.f};

  const u16* pw1b = pw1 + ((size_t)(w * 4) * 64 + l) * 8;
  #pragma unroll 4
  for (int kb = 0; kb < 8; ++kb){
    s8v A[4];
    #pragma unroll
    for (int mf = 0; mf < 4; ++mf) A[mf] = *(const s8v*)(pw1b + (size_t)kb * 8192 + mf * 512);
    #pragma unroll
    for (int nf = 0; nf < 4; ++nf){
      BU bu;
      bu.d[0] = *(const u64*)(hp[nf] + kb * 32);
      bu.d[1] = *(const u64*)(hp[nf] + kb * 32 + 16);
      #pragma unroll
      for (int mf = 0; mf < 4; ++mf)
        acc[mf][nf] = __builtin_amdgcn_mfma_f32_16x16x32_bf16(A[mf], bu.v, acc[mf][nf], 0, 0, 0);
    }
  }
  #pragma unroll 4
  for (int kb = 8; kb < 16; ++kb){
    s8v A[4];
    #pragma unroll
    for (int mf = 0; mf < 4; ++mf) A[mf] = *(const s8v*)(pw1b + (size_t)kb * 8192 + mf * 512);
    #pragma unroll
    for (int nf = 0; nf < 4; ++nf){
      BU bu;
      bu.d[0] = *(const u64*)(ap[nf] + (kb - 8) * 32);
      bu.d[1] = *(const u64*)(ap[nf] + (kb - 8) * 32 + 16);
      #pragma unroll
      for (int mf = 0; mf < 4; ++mf)
        acc[mf][nf] = __builtin_amdgcn_mfma_f32_16x16x32_bf16(A[mf], bu.v, acc[mf][nf], 0, 0, 0);
    }
  }
  // n1 tile (b128 pairs)
  #pragma unroll
  for (int nf = 0; nf < 4; ++nf){
    u64 p01[4];
    #pragma unroll
    for (int mf = 0; mf < 4; ++mf){
      const int fb = w * 64 + mf * 16 + g * 4;
      const float4 bb = *(const float4*)&bias_s[fb];
      p01[mf] = pack4bf(siluf(acc[mf][nf][0] + bb.x), siluf(acc[mf][nf][1] + bb.y),
                        siluf(acc[mf][nf][2] + bb.z), siluf(acc[mf][nf][3] + bb.w));
    }
    ulonglong2 t0; t0.x = p01[0]; t0.y = p01[1];
    ulonglong2 t1; t1.x = p01[2]; t1.y = p01[3];
    mt2[pbase[nf] + ((8 * w)     ^ pm4[nf])] = t0;
    mt2[pbase[nf] + ((8 * w + 4) ^ pm4[nf])] = t1;
  }
  __syncthreads();

  #pragma unroll
  for (int a = 0; a < 4; ++a)
    #pragma unroll
    for (int b = 0; b < 4; ++b) acc[a][b] = (f4v){0.f,0.f,0.f,0.f};
  const u16* pw2b = pw2 + ((size_t)(w * 4) * 64 + l) * 8;
  #pragma unroll 4
  for (int kb = 0; kb < 8; ++kb){
    s8v A[4];
    #pragma unroll
    for (int mf = 0; mf < 4; ++mf) A[mf] = *(const s8v*)(pw2b + (size_t)kb * 8192 + mf * 512);
    #pragma unroll
    for (int nf = 0; nf < 4; ++nf){
      ulonglong2 pr = mt2[pbase[nf] + ((4 * kb) ^ pm4[nf])];
      BU bu; bu.d[0] = pr.x; bu.d[1] = pr.y;
      #pragma unroll
      for (int mf = 0; mf < 4; ++mf)
        acc[mf][nf] = __builtin_amdgcn_mfma_f32_16x16x32_bf16(A[mf], bu.v, acc[mf][nf], 0, 0, 0);
    }
  }
  __syncthreads();                    // done reading n1 tile
  u64 pm[4][4];
  #pragma unroll
  for (int mf = 0; mf < 4; ++mf){
    const int fb = w * 64 + mf * 16 + g * 4;
    const float4 bb = *(const float4*)&bias_s[256 + fb];
    #pragma unroll
    for (int nf = 0; nf < 4; ++nf){
      int n = nb + nf * 16 + li;
      int nc = (n >= NN) ? NN - 1 : n;
      float4 hv = *(float4*)(h + (size_t)nc * HH + fb);
      float o0 = hv.x + acc[mf][nf][0] + bb.x;
      float o1 = hv.y + acc[mf][nf][1] + bb.y;
      float o2 = hv.z + acc[mf][nf][2] + bb.z;
      float o3 = hv.w + acc[mf][nf][3] + bb.w;
      pm[mf][nf] = pack4bf(o0, o1, o2, o3);
      if (n < NN){
        *(float4*)(h + (size_t)n * HH + fb) = make_float4(o0, o1, o2, o3);
        *(u64*)(hb + (size_t)n * HH + fb) = pm[mf][nf];
      }
    }
  }
  if (EMIT_PAB){
    // h_new tile for next-layer Pa/Pb
    #pragma unroll
    for (int nf = 0; nf < 4; ++nf){
      ulonglong2 t0; t0.x = pm[0][nf]; t0.y = pm[1][nf];
      ulonglong2 t1; t1.x = pm[2][nf]; t1.y = pm[3][nf];
      mt2[pbase[nf] + ((8 * w)     ^ pm4[nf])] = t0;
      mt2[pbase[nf] + ((8 * w + 4) ^ pm4[nf])] = t1;
    }
    __syncthreads();
    const u16* pwn = pw1n + ((size_t)(w * 4) * 64 + l) * 8;
    #pragma unroll
    for (int pass = 0; pass < 2; ++pass){
      #pragma unroll
      for (int a = 0; a < 4; ++a)
        #pragma unroll
        for (int b = 0; b < 4; ++b) acc[a][b] = (f4v){0.f,0.f,0.f,0.f};
      const u16* pwp = pwn + (size_t)(pass * 8) * 8192;
      #pragma unroll 4
      for (int kb = 0; kb < 8; ++kb){
        s8v A[4];
        #pragma unroll
        for (int mf = 0; mf < 4; ++mf) A[mf] = *(const s8v*)(pwp + (size_t)kb * 8192 + mf * 512);
        #pragma unroll
        for (int nf = 0; nf < 4; ++nf){
          ulonglong2 pr = mt2[pbase[nf] + ((4 * kb) ^ pm4[nf])];
          BU bu; bu.d[0] = pr.x; bu.d[1] = pr.y;
          #pragma unroll
          for (int mf = 0; mf < 4; ++mf)
            acc[mf][nf] = __builtin_amdgcn_mfma_f32_16x16x32_bf16(A[mf], bu.v, acc[mf][nf], 0, 0, 0);
        }
      }
      float* dst = pass ? Pb : Pa;
      #pragma unroll
      for (int mf = 0; mf < 4; ++mf){
        const int fb = w * 64 + mf * 16 + g * 4;
        float c0 = 0.f, c1 = 0.f, c2 = 0.f, c3 = 0.f;
        if (!pass){ c0 = b1n[fb]; c1 = b1n[fb+1]; c2 = b1n[fb+2]; c3 = b1n[fb+3]; }
        #pragma unroll
        for (int nf = 0; nf < 4; ++nf){
          int n = nb + nf * 16 + li;
          if (n < NN)
            *(float4*)(dst + (size_t)n * HH + fb) =
              make_float4(acc[mf][nf][0] + c0, acc[mf][nf][1] + c1,
                          acc[mf][nf][2] + c2, acc[mf][nf][3] + c3);
        }
      }
    }
  }
}

// ---------------- resblock + head ----------------
__global__ __launch_bounds__(256) void final_kernel(
    const float* __restrict__ z, const float* __restrict__ rw1, const float* __restrict__ rb1,
    const float* __restrict__ rw2, const float* __restrict__ rb2,
    const float* __restrict__ hw, const float* __restrict__ hbs, float* __restrict__ out){
  __shared__ float zr[272], t1[256], t2[272];
  const int b = blockIdx.x, tid = threadIdx.x;
  for (int i = tid; i < 272; i += 256) zr[i] = z[(size_t)b * 272 + i];
  __syncthreads();
  {
    float a = rb1[tid];
    for (int k = 0; k < 272; ++k) a += zr[k] * rw1[(size_t)k * 256 + tid];
    t1[tid] = siluf(a);
  }
  __syncthreads();
  for (int i = tid; i < 272; i += 256){
    float a = rb2[i] + zr[i];
    for (int k = 0; k < 256; ++k) a += t1[k] * rw2[(size_t)k * 272 + i];
    t2[i] = a;
  }
  __syncthreads();
  for (int p = tid; p < 2000; p += 256){
    float a = hbs[p];
    for (int k = 0; k < 272; ++k) a += t2[k] * hw[(size_t)k * 2000 + p];
    out[(size_t)b * 2000 + p] = a;
  }
}

extern "C" void kernel_launch(void* const* d_in, const int* in_sizes, int n_in,
                              void* d_out, int out_size, void* d_ws, size_t ws_size,
                              hipStream_t stream){
  const float* x        = (const float*)d_in[0];
  const float* pos      = (const float*)d_in[1];
  const float* eattr    = (const float*)d_in[2];
  const float* fragl    = (const float*)d_in[3];
  const float* addf     = (const float*)d_in[4];
  const int*   ei       = (const int*)d_in[5];
  const int*   batch    = (const int*)d_in[6];
  const float* emb_in_w = (const float*)d_in[7];
  const float* emb_in_b = (const float*)d_in[8];
  const float* edge_w1  = (const float*)d_in[9];
  const float* edge_b1  = (const float*)d_in[10];
  const float* edge_w2  = (const float*)d_in[11];
  const float* edge_b2  = (const float*)d_in[12];
  const float* node_w1  = (const float*)d_in[13];
  const float* node_b1  = (const float*)d_in[14];
  const float* node_w2  = (const float*)d_in[15];
  const float* node_b2  = (const float*)d_in[16];
  const float* coord_w1 = (const float*)d_in[17];
  const float* coord_b1 = (const float*)d_in[18];
  const float* coord_w2 = (const float*)d_in[19];
  const float* emb_out_w= (const float*)d_in[20];
  const float* emb_out_b= (const float*)d_in[21];
  const float* res_w1   = (const float*)d_in[22];
  const float* res_b1   = (const float*)d_in[23];
  const float* res_w2   = (const float*)d_in[24];
  const float* res_b2   = (const float*)d_in[25];
  const float* head_w   = (const float*)d_in[26];
  const float* head_b   = (const float*)d_in[27];

  char* ws = (char*)d_ws;
  size_t off = 0;
  auto alloc = [&](size_t bytes) -> void* {
    void* p = ws + off;
    off += (bytes + 255) & ~(size_t)255;
    return p;
  };
  float*  h      = (float*)alloc((size_t)NN * HH * 4);
  float*  agg    = (float*)alloc((size_t)NN * HH * 4);
  u16*    agg_bf = (u16*)  alloc((size_t)NN * HH * 2);
  u16*    hb     = (u16*)  alloc((size_t)NN * HH * 2);
  float*  Pa     = (float*)alloc((size_t)NN * HH * 4);
  float*  Pb     = (float*)alloc((size_t)NN * HH * 4);
  float*  ho     = (float*)alloc((size_t)NN * HH * 4);
  float4* coordb = (float4*)alloc((size_t)NN * 16);
  float*  cacc   = (float*)alloc((size_t)NN * 16);
  float*  z      = (float*)alloc((size_t)BB * 272 * 4);
  u16*    packed = (u16*)  alloc((size_t)7680 * 256 * 2);
  int*    icnt   = (int*)  alloc((size_t)NN * 4);
  int*    iscan  = (int*)  alloc((size_t)NN * 4);
  int*    rstart = (int*)  alloc((size_t)NN * 4);
  int*    cursor = (int*)  alloc((size_t)NN * 4);
  int*    bsum   = (int*)  alloc((size_t)128 * 4);
  int*    bstart = (int*)  alloc((size_t)(BB + 1) * 4);
  int*    seid   = (int*)  alloc((size_t)EE * 4);
  int*    srow   = (int*)  alloc((size_t)EE * 4);
  int*    scol   = (int*)  alloc((size_t)EE * 4);
  const size_t base_off = off;
  u64*    m2g    = (u64*)  alloc((size_t)EE * HH * 2);   // 164 MB m2 stream buffer
  const bool use_stream = (off <= ws_size);
  if (base_off > ws_size) return;

  u16* pk_embin  = packed;
  u16* pk_embout = packed + 32768 + (size_t)4 * 466944;
  auto pk_ew1 = [&](int l){ return packed + 32768 + (size_t)l * 466944; };
  auto pk_ew2 = [&](int l){ return pk_ew1(l) + 139264; };
  auto pk_cw1 = [&](int l){ return pk_ew1(l) + 204800; };
  auto pk_nw1 = [&](int l){ return pk_ew1(l) + 270336; };
  auto pk_nw2 = [&](int l){ return pk_ew1(l) + 401408; };

  pack_kernel<<<16, 256, 0, stream>>>(emb_in_w, pk_embin, 128, 4);
  for (int l = 0; l < 4; ++l){
    pack_kernel<<<68, 256, 0, stream>>>(edge_w1 + (size_t)l * 529 * 256, pk_ew1(l), 529, 17);
    pack_kernel<<<32, 256, 0, stream>>>(edge_w2 + (size_t)l * 65536,     pk_ew2(l), 256, 8);
    pack_kernel<<<32, 256, 0, stream>>>(coord_w1 + (size_t)l * 65536,    pk_cw1(l), 256, 8);
    pack_kernel<<<64, 256, 0, stream>>>(node_w1 + (size_t)l * 131072,    pk_nw1(l), 512, 16);
    pack_kernel<<<32, 256, 0, stream>>>(node_w2 + (size_t)l * 65536,     pk_nw2(l), 256, 8);
  }
  pack_kernel<<<32, 256, 0, stream>>>(emb_out_w, pk_embout, 256, 8);

  // ---- one-time edge sort by row + per-graph ranges
  const int NB = (NN + 255) / 256;   // 79
  hipMemsetAsync(icnt,   0, (size_t)NN * 4, stream);
  hipMemsetAsync(cursor, 0, (size_t)NN * 4, stream);
  icnt_kernel<<<(EE + 255) / 256, 256, 0, stream>>>(ei, icnt);
  iscan_block<<<NB, 256, 0, stream>>>(icnt, iscan, bsum);
  iscan_top<<<1, 64, 0, stream>>>(bsum, NB);
  iscan_fix<<<NB, 256, 0, stream>>>(icnt, iscan, bsum, rstart);
  scatter_kernel<<<(EE + 255) / 256, 256, 0, stream>>>(ei, rstart, cursor, seid, srow, scol);
  bstart_kernel<<<NB, 256, 0, stream>>>(batch, bstart);

  coord_init_kernel<<<79, 256, 0, stream>>>(pos, coordb);
  emb_in_kernel<<<313, 256, 0, stream>>>(x, pk_embin, emb_in_b, h, hb,
                                         pk_ew1(0), edge_b1, Pa, Pb);

  for (int l = 0; l < 4; ++l){
    hipMemsetAsync(cacc, 0, (size_t)NN * 16, stream);
    if (use_stream){
      edge_kernel<true><<<5000, 512, 0, stream>>>(Pa, Pb, coordb, srow, scol, seid, eattr,
          pk_ew1(l), pk_ew2(l), pk_cw1(l),
          edge_b2 + l * 256, coord_b1 + l * 256, coord_w2 + l * 256,
          agg, cacc, m2g);
      agg_csr_kernel<<<NN, 256, 0, stream>>>((const u16*)m2g, rstart, icnt, agg_bf);
    } else {
      hipMemsetAsync(agg, 0, (size_t)NN * HH * 4, stream);
      edge_kernel<false><<<5000, 512, 0, stream>>>(Pa, Pb, coordb, srow, scol, seid, eattr,
          pk_ew1(l), pk_ew2(l), pk_cw1(l),
          edge_b2 + l * 256, coord_b1 + l * 256, coord_w2 + l * 256,
          agg, cacc, m2g);
      agg_conv_kernel<<<(NN * HH + 255) / 256, 256, 0, stream>>>(agg, agg_bf);
    }
    coord_upd_kernel<<<79, 256, 0, stream>>>(coordb, cacc, icnt);
    if (l < 3)
      node_pab_kernel<true><<<313, 256, 0, stream>>>(h, hb, agg_bf, pk_nw1(l), pk_nw2(l),
          node_b1 + l * 256, node_b2 + l * 256,
          pk_ew1(l + 1), edge_b1 + (l + 1) * 256, Pa, Pb);
    else
      node_pab_kernel<false><<<313, 256, 0, stream>>>(h, hb, agg_bf, pk_nw1(l), pk_nw2(l),
          node_b1 + l * 256, node_b2 + l * 256,
          pk_ew1(0), edge_b1, Pa, Pb);
  }

  emb_out_kernel<<<313, 256, 0, stream>>>(hb, pk_embout, emb_out_b, ho);
  pool_csr_kernel<<<BB * 4, 64, 0, stream>>>(ho, bstart, fragl, addf, z);
  final_kernel<<<128, 256, 0, stream>>>(z, res_w1, res_b1, res_w2, res_b2, head_w, head_b,
                                        (float*)d_out);
}